// Round 3
// baseline (40760.529 us; speedup 1.0000x reference)
//
#include <hip/hip_runtime.h>
#include <hip/hip_bf16.h>
#include <hip/hip_cooperative_groups.h>

namespace cg = cooperative_groups;

namespace {

constexpr int kB  = 256;   // batch
constexpr int kP  = 256;   // proposals
constexpr int kT  = 32;    // words
constexpr int kNS = 31;    // steps = T-1
constexpr int kV  = 3433;  // vocab
constexpr int kH  = 512;   // hidden
constexpr int kE  = 300;   // embed
constexpr int kC  = 128;   // feat dim
constexpr int kG  = 1536;  // 3H

typedef __bf16 bf16x8 __attribute__((ext_vector_type(8)));
typedef float f32x4 __attribute__((ext_vector_type(4)));

__device__ __forceinline__ float fexp2(float x) {
  float r; asm("v_exp_f32 %0, %1" : "=v"(r) : "v"(x)); return r;
}
__device__ __forceinline__ float frcp(float x) {
  float r; asm("v_rcp_f32 %0, %1" : "=v"(r) : "v"(x)); return r;
}
__device__ __forceinline__ float ftanh(float x) {
  float e = fexp2(x * 2.8853900817779268f);   // e^(2x)
  return 1.0f - 2.0f * frcp(e + 1.0f);
}
__device__ __forceinline__ float fsigm(float x) {
  return frcp(1.0f + fexp2(x * -1.4426950408889634f));
}
__device__ __forceinline__ unsigned short f2bf(float f) {   // RNE bf16
  unsigned u = __float_as_uint(f);
  u += 0x7FFFu + ((u >> 16) & 1u);
  return (unsigned short)(u >> 16);
}
__device__ __forceinline__ float bf2f(unsigned short s) {
  return __uint_as_float((unsigned)s << 16);
}
__device__ __forceinline__ bf16x8 bload(const unsigned short* p) {
  union { uint4 u; bf16x8 v; } x;
  x.u = *(const uint4*)p;
  return x.v;
}

// ---------------- one-time weight transposes (W[r][k] -> Wt[k*R + r]) -------
__global__ void k_transpose(const float* s0, const float* s1, const float* s2,
                            const float* s3, const float* s4, const float* s5,
                            const float* s6, const float* s7,
                            float* d0, float* d1, float* d2, float* d3,
                            float* d4, float* d5, float* d6, float* d7) {
  const float* src; float* dst; int R, Cd;
  switch (blockIdx.y) {
    case 0:  src = s0; dst = d0; R = 128;  Cd = 300; break;  // W_td3
    case 1:  src = s1; dst = d1; R = 128;  Cd = 512; break;  // W_td1
    case 2:  src = s2; dst = d2; R = 128;  Cd = 128; break;  // W_td
    case 3:  src = s3; dst = d3; R = 128;  Cd = 128; break;  // W_l1
    case 4:  src = s4; dst = d4; R = 128;  Cd = 512; break;  // W_l2
    case 5:  src = s5; dst = d5; R = 128;  Cd = 128; break;  // W_l
    case 6:  src = s6; dst = d6; R = 1536; Cd = 128; break;  // W1_ih
    default: src = s7; dst = d7; R = 1536; Cd = 128; break;  // W2_ih
  }
  int n = R * Cd;
  for (int i = blockIdx.x * blockDim.x + threadIdx.x; i < n;
       i += gridDim.x * blockDim.x) {
    int k = i / R, r = i - k * R;
    dst[i] = src[r * Cd + k];    // dst[k*R + r]
  }
}

// ---------------- one-time weight hi/lo bf16 splits --------------------------
__global__ void k_split(const float* s0, const float* s1, const float* s2,
                        const float* s3, const float* s4,
                        unsigned short* h0, unsigned short* l0,
                        unsigned short* h1, unsigned short* l1,
                        unsigned short* h2, unsigned short* l2,
                        unsigned short* h3, unsigned short* l3,
                        unsigned short* h4, unsigned short* l4) {
  const float* s; unsigned short* h; unsigned short* l; int n;
  switch (blockIdx.y) {
    case 0:  s = s0; h = h0; l = l0; n = kG * kH; break;   // W1_hh
    case 1:  s = s1; h = h1; l = l1; n = kG * kH; break;   // W2_hh
    case 2:  s = s2; h = h2; l = l2; n = kV * kH; break;   // W_cls
    case 3:  s = s3; h = h3; l = l3; n = kH * kH; break;   // W_hidd
    default: s = s4; h = h4; l = l4; n = kH * kC; break;   // W_feat
  }
  for (int i = blockIdx.x * blockDim.x + threadIdx.x; i < n;
       i += gridDim.x * blockDim.x) {
    float v = s[i];
    unsigned short hb = f2bf(v);
    h[i] = hb;
    l[i] = f2bf(v - bf2f(hb));
  }
}

// ---------------- init: td = t_feat @ W_td2^T ; zero h states ----------------
__global__ void k_init(const float* __restrict__ t_feat,
                       const float* __restrict__ W_td2,
                       float* __restrict__ td, float* __restrict__ h1,
                       float* __restrict__ h2,
                       unsigned short* __restrict__ h1h,
                       unsigned short* __restrict__ h1l,
                       unsigned short* __restrict__ h2h,
                       unsigned short* __restrict__ h2l) {
  int tid = blockIdx.x * 256 + threadIdx.x;  // 32768 threads
  int b = tid >> 7, c = tid & 127;
  const float* tf = t_feat + b * kC;
  const float* w  = W_td2 + c * kC;
  float acc = 0.f;
  for (int k = 0; k < kC; ++k) acc = fmaf(tf[k], w[k], acc);
  td[tid] = acc;
  for (int i = tid; i < kB * kH; i += (1 << 15)) {
    h1[i] = 0.f; h2[i] = 0.f;
    h1h[i] = 0; h1l[i] = 0; h2h[i] = 0; h2l[i] = 0;
  }
}

// ---------------- split-bf16 MFMA 128x128 tile (3-term) ----------------------
// C[m,n] = sum_{k in [kbeg,kend)} A[m][k]*B[n][k]; A,B hi/lo bf16 [rows][K].
// Uses waves 0..3 of the block (call with tid<256 guard if blockDim>256).
__device__ __forceinline__ void mm_split_tile(
    const unsigned short* __restrict__ Ah, const unsigned short* __restrict__ Al,
    const unsigned short* __restrict__ Bh, const unsigned short* __restrict__ Bl,
    int m0, int n0, int K, int kbeg, int kend, int nMax, f32x4 acc[4][4]) {
  int lane = threadIdx.x & 63, wid = (threadIdx.x >> 6) & 3;
  int wm = (wid >> 1) * 64, wn = (wid & 1) * 64;
  int r16 = lane & 15, kq = lane >> 4;
  int arow[4], brow[4];
  #pragma unroll
  for (int i = 0; i < 4; ++i) {
    arow[i] = m0 + wm + i * 16 + r16;
    int br = n0 + wn + i * 16 + r16;
    brow[i] = br > nMax ? nMax : br;
  }
  for (int k0 = kbeg; k0 < kend; k0 += 32) {
    int kk = k0 + kq * 8;
    bf16x8 ah[4], al[4], bh[4], bl[4];
    #pragma unroll
    for (int i = 0; i < 4; ++i) {
      ah[i] = bload(Ah + (size_t)arow[i] * K + kk);
      al[i] = bload(Al + (size_t)arow[i] * K + kk);
      bh[i] = bload(Bh + (size_t)brow[i] * K + kk);
      bl[i] = bload(Bl + (size_t)brow[i] * K + kk);
    }
    #pragma unroll
    for (int i = 0; i < 4; ++i)
      #pragma unroll
      for (int j = 0; j < 4; ++j) {
        acc[i][j] = __builtin_amdgcn_mfma_f32_16x16x32_bf16(ah[i], bh[j], acc[i][j], 0, 0, 0);
        acc[i][j] = __builtin_amdgcn_mfma_f32_16x16x32_bf16(ah[i], bl[j], acc[i][j], 0, 0, 0);
        acc[i][j] = __builtin_amdgcn_mfma_f32_16x16x32_bf16(al[i], bh[j], acc[i][j], 0, 0, 0);
      }
  }
}

// ---------------- feat_proj = c_feats @ W_feat^T -> bf16 (MFMA) --------------
__global__ __launch_bounds__(256) void k_featproj(
    const float* __restrict__ A, const unsigned short* __restrict__ Wh,
    const unsigned short* __restrict__ Wl, unsigned short* __restrict__ out) {
  int lane = threadIdx.x & 63, wid = threadIdx.x >> 6;
  int wm = (wid >> 1) * 64, wn = (wid & 1) * 64;
  int r16 = lane & 15, kq = lane >> 4;
  int m0 = blockIdx.x * 128, n0 = blockIdx.y * 128;
  f32x4 acc[4][4];
  #pragma unroll
  for (int i = 0; i < 4; ++i)
    #pragma unroll
    for (int j = 0; j < 4; ++j) acc[i][j] = (f32x4){0.f, 0.f, 0.f, 0.f};
  for (int k0 = 0; k0 < kC; k0 += 32) {
    int kk = k0 + kq * 8;
    bf16x8 ah[4], al[4], bh[4], bl[4];
    #pragma unroll
    for (int i = 0; i < 4; ++i) {
      const float* pa = A + (size_t)(m0 + wm + i * 16 + r16) * kC + kk;
      float4 v0 = *(const float4*)pa;
      float4 v1 = *(const float4*)(pa + 4);
      float vv[8] = {v0.x, v0.y, v0.z, v0.w, v1.x, v1.y, v1.z, v1.w};
      union { unsigned short s[8]; bf16x8 v; } uh, ul;
      #pragma unroll
      for (int q = 0; q < 8; ++q) {
        unsigned short hb = f2bf(vv[q]);
        uh.s[q] = hb;
        ul.s[q] = f2bf(vv[q] - bf2f(hb));
      }
      ah[i] = uh.v; al[i] = ul.v;
      const unsigned short* pb = Wh + (size_t)(n0 + wn + i * 16 + r16) * kC + kk;
      const unsigned short* pl = Wl + (size_t)(n0 + wn + i * 16 + r16) * kC + kk;
      bh[i] = bload(pb); bl[i] = bload(pl);
    }
    #pragma unroll
    for (int i = 0; i < 4; ++i)
      #pragma unroll
      for (int j = 0; j < 4; ++j) {
        acc[i][j] = __builtin_amdgcn_mfma_f32_16x16x32_bf16(ah[i], bh[j], acc[i][j], 0, 0, 0);
        acc[i][j] = __builtin_amdgcn_mfma_f32_16x16x32_bf16(ah[i], bl[j], acc[i][j], 0, 0, 0);
        acc[i][j] = __builtin_amdgcn_mfma_f32_16x16x32_bf16(al[i], bh[j], acc[i][j], 0, 0, 0);
      }
  }
  #pragma unroll
  for (int i = 0; i < 4; ++i)
    #pragma unroll
    for (int j = 0; j < 4; ++j)
      #pragma unroll
      for (int r = 0; r < 4; ++r) {
        int m = m0 + wm + i * 16 + kq * 4 + r;
        int n = n0 + wn + j * 16 + r16;
        out[(size_t)m * kH + n] = f2bf(acc[i][j][r]);
      }
}

// ---------------- persistent cooperative loop kernel -------------------------
struct LoopParams {
  const float* word_embs;
  const float* td;
  const float* td3t; const float* td1t; const float* tdt;
  const float* iht1; const float* b1_ih;
  const unsigned short* w1hh_h; const unsigned short* w1hh_l;
  const unsigned short* w2hh_h; const unsigned short* w2hh_l;
  const float* b1_hh; const float* b2_hh;
  const unsigned short* whd_h; const unsigned short* whd_l;
  const float* W_att; const unsigned short* fp; const float* c_feats;
  const float* l1t; const float* l2t; const float* lt;
  const float* iht2; const float* b2_ih;
  float* h1; float* h2;
  unsigned short* h1h; unsigned short* h1l;
  unsigned short* h2h; unsigned short* h2l;
  float* sbuf; float* gh1; float* gh2;
  float* hqp;            // [4][kB][kH] k-split partials
  float* att;
  unsigned short* h2all_h; unsigned short* h2all_l;
  float* attn_out;
};

__global__ __launch_bounds__(512, 2) void k_loop(LoopParams P) {
  cg::grid_group grid = cg::this_grid();
  __shared__ float smem[5888];
  const int blk = blockIdx.x;
  const int tid = threadIdx.x;

  for (int t = 0; t < kNS; ++t) {
    // ============ Stage A: s-chain (blk 0..63) | gh1/gh2 MFMA (64..111) =====
    if (blk < 64) {
      float* xl    = smem;          // [4][300]
      float* h2lcl = smem + 1200;   // [4][512]
      float* tdl   = smem + 3248;   // [512]
      float* s0t   = smem + 3760;   // [512]
      int b0 = blk * 4;
      #pragma unroll
      for (int r = 0; r < 4; ++r) {
        const float* xs = P.word_embs + (size_t)(b0 + r) * (kT * kE) + (size_t)t * kE;
        for (int e = tid; e < kE; e += 512) xl[r * kE + e] = xs[e];
      }
      for (int i = tid; i < 2048; i += 512) h2lcl[i] = P.h2[(size_t)b0 * kH + i];
      tdl[tid] = P.td[(size_t)b0 * kC + tid];
      __syncthreads();
      {
        int r = tid >> 7, c = tid & 127;
        float acc = tdl[tid];
        const float* xr = xl + r * kE;
        const float* w3 = P.td3t + c;
        for (int e = 0; e < kE; ++e) acc = fmaf(xr[e], w3[(size_t)e * 128], acc);
        const float* hr = h2lcl + r * kH;
        const float* w1 = P.td1t + c;
        for (int k = 0; k < kH; ++k) acc = fmaf(hr[k], w1[(size_t)k * 128], acc);
        s0t[tid] = ftanh(acc);
      }
      __syncthreads();
      {
        int r = tid >> 7, c = tid & 127;
        float acc = 0.f;
        const float* sr = s0t + r * kC;
        const float* w = P.tdt + c;
        for (int k = 0; k < kC; ++k) acc = fmaf(sr[k], w[k * 128], acc);
        P.sbuf[(size_t)(b0 + r) * kC + c] = fmaxf(acc, 0.f);
      }
    } else if (blk < 112) {
      if (tid < 256) {
        int g = blk - 64;   // 0..47
        const unsigned short *Ah, *Al, *Wh, *Wl; const float* bias; float* out;
        if (g < 24) { Ah = P.h1h; Al = P.h1l; Wh = P.w1hh_h; Wl = P.w1hh_l;
                      bias = P.b1_hh; out = P.gh1; }
        else { g -= 24; Ah = P.h2h; Al = P.h2l; Wh = P.w2hh_h; Wl = P.w2hh_l;
               bias = P.b2_hh; out = P.gh2; }
        int m0 = (g / 12) * 128, n0 = (g % 12) * 128;
        f32x4 acc[4][4];
        #pragma unroll
        for (int i = 0; i < 4; ++i)
          #pragma unroll
          for (int j = 0; j < 4; ++j) acc[i][j] = (f32x4){0.f, 0.f, 0.f, 0.f};
        mm_split_tile(Ah, Al, Wh, Wl, m0, n0, kH, 0, kH, kG - 1, acc);
        int lane = tid & 63, wid = tid >> 6;
        int wm = (wid >> 1) * 64, wn = (wid & 1) * 64;
        int r16 = lane & 15, kq = lane >> 4;
        #pragma unroll
        for (int i = 0; i < 4; ++i)
          #pragma unroll
          for (int j = 0; j < 4; ++j)
            #pragma unroll
            for (int r = 0; r < 4; ++r) {
              int m = m0 + wm + i * 16 + kq * 4 + r;
              int n = n0 + wn + j * 16 + r16;
              out[(size_t)m * kG + n] = acc[i][j][r] + bias[n];
            }
      }
    }
    __threadfence();
    grid.sync();

    // ============ Stage B: GRU1 combine -> h1 (blk 0..127) ==================
    if (blk < 128) {
      int bt = blk >> 4, jt = blk & 15;
      int b0 = bt * 32, j0 = jt * 32;
      int tj = tid & 31, tb = tid >> 5;      // tb 0..15, 2 rows each
      int col = j0 + tj;
      int brow = b0 + tb * 2;
      float ar[2] = {}, az[2] = {}, an[2] = {};
      const float* srow = P.sbuf + (size_t)brow * kC;
      for (int kk = 0; kk < kC; kk += 4) {
        float4 s0 = *(const float4*)(srow + kk);
        float4 s1 = *(const float4*)(srow + kC + kk);
        float sv[2][4] = {{s0.x, s0.y, s0.z, s0.w}, {s1.x, s1.y, s1.z, s1.w}};
        #pragma unroll
        for (int q = 0; q < 4; ++q) {
          float wr = P.iht1[(size_t)(kk + q) * kG + col];
          float wz = P.iht1[(size_t)(kk + q) * kG + 512 + col];
          float wn = P.iht1[(size_t)(kk + q) * kG + 1024 + col];
          #pragma unroll
          for (int i = 0; i < 2; ++i) {
            ar[i] = fmaf(sv[i][q], wr, ar[i]);
            az[i] = fmaf(sv[i][q], wz, az[i]);
            an[i] = fmaf(sv[i][q], wn, an[i]);
          }
        }
      }
      float bir = P.b1_ih[col], biz = P.b1_ih[512 + col], bn = P.b1_ih[1024 + col];
      #pragma unroll
      for (int i = 0; i < 2; ++i) {
        int b = brow + i;
        float ghr = P.gh1[(size_t)b * kG + col];
        float ghz = P.gh1[(size_t)b * kG + 512 + col];
        float ghn = P.gh1[(size_t)b * kG + 1024 + col];
        float rr = fsigm(ar[i] + bir + ghr);
        float zz = fsigm(az[i] + biz + ghz);
        float nn = ftanh(an[i] + bn + rr * ghn);
        float ho = P.h1[(size_t)b * kH + col];
        float hn = (1.f - zz) * nn + zz * ho;
        P.h1[(size_t)b * kH + col] = hn;
        unsigned short hb = f2bf(hn);
        P.h1h[(size_t)b * kH + col] = hb;
        P.h1l[(size_t)b * kH + col] = f2bf(hn - bf2f(hb));
      }
    }
    __threadfence();
    grid.sync();

    // ============ Stage C: hq k-split partials (blk 0..31) ==================
    if (blk < 32) {
      if (tid < 256) {
        int mt = blk >> 4, nt = (blk >> 2) & 3, kc = blk & 3;
        int m0 = mt * 128, n0 = nt * 128;
        f32x4 acc[4][4];
        #pragma unroll
        for (int i = 0; i < 4; ++i)
          #pragma unroll
          for (int j = 0; j < 4; ++j) acc[i][j] = (f32x4){0.f, 0.f, 0.f, 0.f};
        mm_split_tile(P.h1h, P.h1l, P.whd_h, P.whd_l, m0, n0, kH,
                      kc * 128, kc * 128 + 128, kH - 1, acc);
        float* out = P.hqp + (size_t)kc * (kB * kH);
        int lane = tid & 63, wid = tid >> 6;
        int wm = (wid >> 1) * 64, wn = (wid & 1) * 64;
        int r16 = lane & 15, kq = lane >> 4;
        #pragma unroll
        for (int i = 0; i < 4; ++i)
          #pragma unroll
          for (int j = 0; j < 4; ++j)
            #pragma unroll
            for (int r = 0; r < 4; ++r) {
              int m = m0 + wm + i * 16 + kq * 4 + r;
              int n = n0 + wn + j * 16 + r16;
              out[(size_t)m * kH + n] = acc[i][j][r];
            }
      }
    }
    __threadfence();
    grid.sync();

    // ============ Stage D: attention (all 256 blocks, 512 threads) ==========
    {
      int b = blk;
      int lane = tid & 63, wv = tid >> 6;   // 8 waves
      float* scs  = smem;         // 256
      float* red  = smem + 256;   // 8
      float* red2 = smem + 264;   // 8
      float* part = smem + 272;   // [4][128]
      float hql[8] = {0.f, 0.f, 0.f, 0.f, 0.f, 0.f, 0.f, 0.f};
      float aw[8];
      #pragma unroll
      for (int kc = 0; kc < 4; ++kc) {
        const float* hp = P.hqp + (size_t)kc * (kB * kH) + (size_t)b * kH + lane * 8;
        float4 x0 = *(const float4*)hp;
        float4 x1 = *(const float4*)(hp + 4);
        hql[0] += x0.x; hql[1] += x0.y; hql[2] += x0.z; hql[3] += x0.w;
        hql[4] += x1.x; hql[5] += x1.y; hql[6] += x1.z; hql[7] += x1.w;
      }
      {
        float4 a0 = *(const float4*)(P.W_att + lane * 8);
        float4 a1 = *(const float4*)(P.W_att + lane * 8 + 4);
        aw[0] = a0.x; aw[1] = a0.y; aw[2] = a0.z; aw[3] = a0.w;
        aw[4] = a1.x; aw[5] = a1.y; aw[6] = a1.z; aw[7] = a1.w;
      }
      const unsigned short* fpb = P.fp + (size_t)b * kP * kH;
      for (int p = wv * 32; p < wv * 32 + 32; ++p) {
        uint4 rv = *(const uint4*)(fpb + (size_t)p * kH + lane * 8);
        union { uint4 v; unsigned short s[8]; } u; u.v = rv;
        float sc = 0.f;
        #pragma unroll
        for (int j = 0; j < 8; ++j) {
          float f = __uint_as_float((unsigned)u.s[j] << 16);
          sc += aw[j] * ftanh(f + hql[j]);
        }
        #pragma unroll
        for (int m = 32; m; m >>= 1) sc += __shfl_xor(sc, m, 64);
        if (lane == 0) scs[p] = sc;
      }
      __syncthreads();
      float sv = (tid < 256) ? scs[tid] : -1e30f;
      float mx = sv;
      #pragma unroll
      for (int m = 32; m; m >>= 1) mx = fmaxf(mx, __shfl_xor(mx, m, 64));
      if (lane == 0) red[wv] = mx;
      __syncthreads();
      float bm = red[0];
      #pragma unroll
      for (int i = 1; i < 8; ++i) bm = fmaxf(bm, red[i]);
      float ev = (tid < 256) ? fexp2((sv - bm) * 1.4426950408889634f) : 0.f;
      float sm = ev;
      #pragma unroll
      for (int m = 32; m; m >>= 1) sm += __shfl_xor(sm, m, 64);
      if (lane == 0) red2[wv] = sm;
      __syncthreads();
      float tot = red2[0] + red2[1] + red2[2] + red2[3] +
                  red2[4] + red2[5] + red2[6] + red2[7];
      float inv = frcp(tot);
      if (tid < 256) {
        float mk = ev * inv;
        scs[tid] = mk;
        P.attn_out[(size_t)b * kP * kNS + (size_t)tid * kNS + t] = mk;
      }
      __syncthreads();
      {
        int c = tid & 127, q = tid >> 7;   // q 0..3, 64 proposals each
        const float* cf = P.c_feats + ((size_t)b * kP + q * 64) * kC + c;
        float acc = 0.f;
        for (int p = 0; p < 64; ++p)
          acc = fmaf(scs[q * 64 + p], cf[(size_t)p * kC], acc);
        part[q * 128 + c] = acc;
      }
      __syncthreads();
      if (tid < 128)
        P.att[(size_t)b * kC + tid] =
            part[tid] + part[128 + tid] + part[256 + tid] + part[384 + tid];
    }
    __threadfence();
    grid.sync();

    // ============ Stage E: language chain + GRU2 (blk 0..127) ===============
    if (blk < 128) {
      float* attl   = smem;          // 256
      float* h1lcl  = smem + 256;    // 1024
      float* h2lcl  = smem + 1280;   // 1024
      float* ltl    = smem + 2304;   // 256
      float* ll     = smem + 2560;   // 256
      float* gxt    = smem + 2816;   // 3072
      int b0 = blk * 2;
      for (int i = tid; i < 256; i += 512) attl[i] = P.att[(size_t)b0 * 128 + i];
      for (int i = tid; i < 1024; i += 512) {
        h1lcl[i] = P.h1[(size_t)b0 * 512 + i];
        h2lcl[i] = P.h2[(size_t)b0 * 512 + i];
      }
      __syncthreads();
      if (tid < 256) {
        int r = tid >> 7, c = tid & 127;
        float acc = 0.f;
        const float* a = attl + r * 128;
        const float* w1 = P.l1t + c;
        for (int k = 0; k < 128; ++k) acc = fmaf(a[k], w1[k * 128], acc);
        const float* hr = h1lcl + r * 512;
        const float* w2 = P.l2t + c;
        for (int k = 0; k < 512; ++k) acc = fmaf(hr[k], w2[(size_t)k * 128], acc);
        ltl[tid] = ftanh(acc);
      }
      __syncthreads();
      if (tid < 256) {
        int r = tid >> 7, c = tid & 127;
        float acc = 0.f;
        const float* lr_ = ltl + r * 128;
        const float* w = P.lt + c;
        for (int k = 0; k < 128; ++k) acc = fmaf(lr_[k], w[k * 128], acc);
        ll[tid] = fmaxf(acc, 0.f);
      }
      __syncthreads();
      for (int idx = tid; idx < 3072; idx += 512) {
        int r = idx / 1536, jj = idx - r * 1536;
        float acc = P.b2_ih[jj];
        const float* lr_ = ll + r * 128;
        const float* w = P.iht2 + jj;
        for (int k = 0; k < 128; ++k) acc = fmaf(lr_[k], w[(size_t)k * kG], acc);
        gxt[idx] = acc;
      }
      __syncthreads();
      for (int idx = tid; idx < 1024; idx += 512) {
        int r = idx >> 9, jv = idx & 511;
        int b = b0 + r;
        float gr = gxt[r * kG + jv];
        float gz = gxt[r * kG + 512 + jv];
        float gn = gxt[r * kG + 1024 + jv];
        float ghr = P.gh2[(size_t)b * kG + jv];
        float ghz = P.gh2[(size_t)b * kG + 512 + jv];
        float ghn = P.gh2[(size_t)b * kG + 1024 + jv];
        float ho = h2lcl[r * 512 + jv];
        float rr = fsigm(gr + ghr);
        float zz = fsigm(gz + ghz);
        float nn = ftanh(gn + rr * ghn);
        float hn = (1.f - zz) * nn + zz * ho;
        P.h2[(size_t)b * kH + jv] = hn;
        unsigned short hb = f2bf(hn);
        unsigned short lb = f2bf(hn - bf2f(hb));
        P.h2h[(size_t)b * kH + jv] = hb;
        P.h2l[(size_t)b * kH + jv] = lb;
        size_t o = ((size_t)t * kB + b) * kH + jv;
        P.h2all_h[o] = hb;
        P.h2all_l[o] = lb;
      }
    }
    __threadfence();
    grid.sync();
  }
}

// ---------------- classifier: lang = h2_all @ W_cls^T + b_cls (MFMA) ---------
__global__ __launch_bounds__(256) void k_cls(
    const unsigned short* __restrict__ Ah, const unsigned short* __restrict__ Al,
    const unsigned short* __restrict__ Wh, const unsigned short* __restrict__ Wl,
    const float* __restrict__ bc, float* __restrict__ out) {
  int m0 = blockIdx.x * 128, n0 = blockIdx.y * 128;
  f32x4 acc[4][4];
  #pragma unroll
  for (int i = 0; i < 4; ++i)
    #pragma unroll
    for (int j = 0; j < 4; ++j) acc[i][j] = (f32x4){0.f, 0.f, 0.f, 0.f};
  mm_split_tile(Ah, Al, Wh, Wl, m0, n0, kH, 0, kH, kV - 1, acc);
  int lane = threadIdx.x & 63, wid = threadIdx.x >> 6;
  int wm = (wid >> 1) * 64, wn = (wid & 1) * 64;
  int r16 = lane & 15, kq = lane >> 4;
  #pragma unroll
  for (int i = 0; i < 4; ++i)
    #pragma unroll
    for (int j = 0; j < 4; ++j)
      #pragma unroll
      for (int r = 0; r < 4; ++r) {
        int m = m0 + wm + i * 16 + kq * 4 + r;
        int n = n0 + wn + j * 16 + r16;
        if (n < kV) {
          int tt = m >> 8, b = m & 255;
          out[(size_t)b * (kNS * kV) + (size_t)tt * kV + n] = acc[i][j][r] + bc[n];
        }
      }
}

}  // namespace

extern "C" void kernel_launch(void* const* d_in, const int* in_sizes, int n_in,
                              void* d_out, int out_size, void* d_ws,
                              size_t ws_size, hipStream_t stream) {
  (void)in_sizes; (void)n_in; (void)out_size; (void)ws_size;
  const float* word_embs = (const float*)d_in[0];
  const float* t_feat    = (const float*)d_in[1];
  const float* c_feats   = (const float*)d_in[2];
  const float* W_td1 = (const float*)d_in[4];
  const float* W_td2 = (const float*)d_in[5];
  const float* W_td3 = (const float*)d_in[6];
  const float* W_td  = (const float*)d_in[7];
  const float* W1_ih = (const float*)d_in[8];
  const float* W1_hh = (const float*)d_in[9];
  const float* b1_ih = (const float*)d_in[10];
  const float* b1_hh = (const float*)d_in[11];
  const float* W_feat = (const float*)d_in[12];
  const float* W_hidd = (const float*)d_in[13];
  const float* W_att  = (const float*)d_in[14];
  const float* W_l1 = (const float*)d_in[15];
  const float* W_l2 = (const float*)d_in[16];
  const float* W_l  = (const float*)d_in[17];
  const float* W2_ih = (const float*)d_in[18];
  const float* W2_hh = (const float*)d_in[19];
  const float* b2_ih = (const float*)d_in[20];
  const float* b2_hh = (const float*)d_in[21];
  const float* W_cls = (const float*)d_in[22];
  const float* b_cls = (const float*)d_in[23];

  float* lang = (float*)d_out;
  float* attn_out = lang + (size_t)kB * kNS * kV;
  // feat_proj (bf16, 64MB) lives in the lang_cap region of d_out — dead by
  // the time k_cls (the only writer of lang_cap) runs.
  unsigned short* fp = (unsigned short*)d_out;

  float* p = (float*)d_ws;
  float* h1 = p;      p += kB * kH;
  float* h2 = p;      p += kB * kH;
  float* td = p;      p += kB * kC;
  float* sbuf = p;    p += kB * kC;
  float* att = p;     p += kB * kC;
  float* gh1 = p;     p += (size_t)kB * kG;
  float* gh2 = p;     p += (size_t)kB * kG;
  float* hqp = p;     p += (size_t)4 * kB * kH;
  float* td3t = p;    p += kE * 128;
  float* td1t = p;    p += kH * 128;
  float* tdt  = p;    p += 128 * 128;
  float* l1t  = p;    p += 128 * 128;
  float* l2t  = p;    p += kH * 128;
  float* lt   = p;    p += 128 * 128;
  float* iht1 = p;    p += 128 * kG;
  float* iht2 = p;    p += 128 * kG;

  unsigned short* u = (unsigned short*)p;
  unsigned short* h1h = u;     u += kB * kH;
  unsigned short* h1l = u;     u += kB * kH;
  unsigned short* h2h = u;     u += kB * kH;
  unsigned short* h2l = u;     u += kB * kH;
  unsigned short* w1hh_h = u;  u += (size_t)kG * kH;
  unsigned short* w1hh_l = u;  u += (size_t)kG * kH;
  unsigned short* w2hh_h = u;  u += (size_t)kG * kH;
  unsigned short* w2hh_l = u;  u += (size_t)kG * kH;
  unsigned short* wc_h = u;    u += (size_t)kV * kH;
  unsigned short* wc_l = u;    u += (size_t)kV * kH;
  unsigned short* whd_h = u;   u += (size_t)kH * kH;
  unsigned short* whd_l = u;   u += (size_t)kH * kH;
  unsigned short* wf_h = u;    u += (size_t)kH * kC;
  unsigned short* wf_l = u;    u += (size_t)kH * kC;
  unsigned short* h2all_h = u; u += (size_t)kNS * kB * kH;
  unsigned short* h2all_l = u; u += (size_t)kNS * kB * kH;

  k_transpose<<<dim3(64, 8), 256, 0, stream>>>(
      W_td3, W_td1, W_td, W_l1, W_l2, W_l, W1_ih, W2_ih,
      td3t, td1t, tdt, l1t, l2t, lt, iht1, iht2);
  k_split<<<dim3(256, 5), 256, 0, stream>>>(
      W1_hh, W2_hh, W_cls, W_hidd, W_feat,
      w1hh_h, w1hh_l, w2hh_h, w2hh_l, wc_h, wc_l, whd_h, whd_l, wf_h, wf_l);
  k_init<<<128, 256, 0, stream>>>(t_feat, W_td2, td, h1, h2,
                                  h1h, h1l, h2h, h2l);
  k_featproj<<<dim3(512, 4), 256, 0, stream>>>(c_feats, wf_h, wf_l, fp);

  LoopParams P;
  P.word_embs = word_embs;
  P.td = td; P.td3t = td3t; P.td1t = td1t; P.tdt = tdt;
  P.iht1 = iht1; P.b1_ih = b1_ih;
  P.w1hh_h = w1hh_h; P.w1hh_l = w1hh_l; P.w2hh_h = w2hh_h; P.w2hh_l = w2hh_l;
  P.b1_hh = b1_hh; P.b2_hh = b2_hh;
  P.whd_h = whd_h; P.whd_l = whd_l;
  P.W_att = W_att; P.fp = fp; P.c_feats = c_feats;
  P.l1t = l1t; P.l2t = l2t; P.lt = lt;
  P.iht2 = iht2; P.b2_ih = b2_ih;
  P.h1 = h1; P.h2 = h2;
  P.h1h = h1h; P.h1l = h1l; P.h2h = h2h; P.h2l = h2l;
  P.sbuf = sbuf; P.gh1 = gh1; P.gh2 = gh2;
  P.hqp = hqp; P.att = att;
  P.h2all_h = h2all_h; P.h2all_l = h2all_l;
  P.attn_out = attn_out;
  void* args[] = {&P};
  hipLaunchCooperativeKernel((void*)k_loop, dim3(256), dim3(512), args, 0,
                             stream);

  k_cls<<<dim3(62, 27), 256, 0, stream>>>(h2all_h, h2all_l, wc_h, wc_l,
                                          b_cls, lang);
}

// Round 4
// 7104.015 us; speedup vs baseline: 5.7377x; 5.7377x over previous
//
#include <hip/hip_runtime.h>
#include <hip/hip_bf16.h>

namespace {

constexpr int kB  = 256;   // batch
constexpr int kP  = 256;   // proposals
constexpr int kT  = 32;    // words
constexpr int kNS = 31;    // steps = T-1
constexpr int kV  = 3433;  // vocab
constexpr int kH  = 512;   // hidden
constexpr int kE  = 300;   // embed
constexpr int kC  = 128;   // feat dim
constexpr int kG  = 1536;  // 3H

typedef __bf16 bf16x8 __attribute__((ext_vector_type(8)));
typedef float f32x4 __attribute__((ext_vector_type(4)));

__device__ __forceinline__ float fexp2(float x) {
  float r; asm("v_exp_f32 %0, %1" : "=v"(r) : "v"(x)); return r;
}
__device__ __forceinline__ float frcp(float x) {
  float r; asm("v_rcp_f32 %0, %1" : "=v"(r) : "v"(x)); return r;
}
__device__ __forceinline__ float ftanh(float x) {
  float e = fexp2(x * 2.8853900817779268f);   // e^(2x)
  return 1.0f - 2.0f * frcp(e + 1.0f);
}
__device__ __forceinline__ float fsigm(float x) {
  return frcp(1.0f + fexp2(x * -1.4426950408889634f));
}
__device__ __forceinline__ unsigned short f2bf(float f) {   // RNE bf16
  unsigned u = __float_as_uint(f);
  u += 0x7FFFu + ((u >> 16) & 1u);
  return (unsigned short)(u >> 16);
}
__device__ __forceinline__ float bf2f(unsigned short s) {
  return __uint_as_float((unsigned)s << 16);
}
__device__ __forceinline__ bf16x8 bload(const unsigned short* p) {
  union { uint4 u; bf16x8 v; } x;
  x.u = *(const uint4*)p;
  return x.v;
}

// ---------------- one-time weight transposes (W[r][k] -> Wt[k*R + r]) -------
__global__ void k_transpose(const float* s0, const float* s1, const float* s2,
                            const float* s3, const float* s4, const float* s5,
                            const float* s6, const float* s7, const float* s8,
                            float* d0, float* d1, float* d2, float* d3,
                            float* d4, float* d5, float* d6, float* d7,
                            float* d8) {
  const float* src; float* dst; int R, Cd;
  switch (blockIdx.y) {
    case 0:  src = s0; dst = d0; R = 128;  Cd = 300; break;  // W_td3
    case 1:  src = s1; dst = d1; R = 128;  Cd = 512; break;  // W_td1
    case 2:  src = s2; dst = d2; R = 128;  Cd = 128; break;  // W_td
    case 3:  src = s3; dst = d3; R = 128;  Cd = 128; break;  // W_l1
    case 4:  src = s4; dst = d4; R = 128;  Cd = 512; break;  // W_l2
    case 5:  src = s5; dst = d5; R = 128;  Cd = 128; break;  // W_l
    case 6:  src = s6; dst = d6; R = 1536; Cd = 128; break;  // W1_ih
    case 7:  src = s7; dst = d7; R = 1536; Cd = 128; break;  // W2_ih
    default: src = s8; dst = d8; R = 512;  Cd = 512; break;  // W_hidd
  }
  int n = R * Cd;
  for (int i = blockIdx.x * blockDim.x + threadIdx.x; i < n;
       i += gridDim.x * blockDim.x) {
    int k = i / R, r = i - k * R;
    dst[i] = src[r * Cd + k];    // dst[k*R + r]
  }
}

// ---------------- one-time weight hi/lo bf16 splits --------------------------
__global__ void k_split(const float* s0, const float* s1, const float* s2,
                        const float* s3,
                        unsigned short* h0, unsigned short* l0,
                        unsigned short* h1, unsigned short* l1,
                        unsigned short* h2, unsigned short* l2,
                        unsigned short* h3, unsigned short* l3) {
  const float* s; unsigned short* h; unsigned short* l; int n;
  switch (blockIdx.y) {
    case 0:  s = s0; h = h0; l = l0; n = kG * kH; break;   // W1_hh
    case 1:  s = s1; h = h1; l = l1; n = kG * kH; break;   // W2_hh
    case 2:  s = s2; h = h2; l = l2; n = kV * kH; break;   // W_cls
    default: s = s3; h = h3; l = l3; n = kH * kC; break;   // W_feat
  }
  for (int i = blockIdx.x * blockDim.x + threadIdx.x; i < n;
       i += gridDim.x * blockDim.x) {
    float v = s[i];
    unsigned short hb = f2bf(v);
    h[i] = hb;
    l[i] = f2bf(v - bf2f(hb));
  }
}

// ---------------- init: td = t_feat @ W_td2^T ; zero h states ----------------
__global__ void k_init(const float* __restrict__ t_feat,
                       const float* __restrict__ W_td2,
                       float* __restrict__ td, float* __restrict__ h1,
                       float* __restrict__ h2,
                       unsigned short* __restrict__ h1h,
                       unsigned short* __restrict__ h1l,
                       unsigned short* __restrict__ h2h,
                       unsigned short* __restrict__ h2l) {
  int tid = blockIdx.x * 256 + threadIdx.x;  // 32768 threads
  int b = tid >> 7, c = tid & 127;
  const float* tf = t_feat + b * kC;
  const float* w  = W_td2 + c * kC;
  float acc = 0.f;
  for (int k = 0; k < kC; ++k) acc = fmaf(tf[k], w[k], acc);
  td[tid] = acc;
  for (int i = tid; i < kB * kH; i += (1 << 15)) {
    h1[i] = 0.f; h2[i] = 0.f;
    h1h[i] = 0; h1l[i] = 0; h2h[i] = 0; h2l[i] = 0;
  }
}

// ---------------- split-bf16 MFMA 128x128 tile (3-term) ----------------------
__device__ __forceinline__ void mm_split_tile(
    const unsigned short* __restrict__ Ah, const unsigned short* __restrict__ Al,
    const unsigned short* __restrict__ Bh, const unsigned short* __restrict__ Bl,
    int m0, int n0, int K, int nMax, f32x4 acc[4][4]) {
  int lane = threadIdx.x & 63, wid = (threadIdx.x >> 6) & 3;
  int wm = (wid >> 1) * 64, wn = (wid & 1) * 64;
  int r16 = lane & 15, kq = lane >> 4;
  int arow[4], brow[4];
  #pragma unroll
  for (int i = 0; i < 4; ++i) {
    arow[i] = m0 + wm + i * 16 + r16;
    int br = n0 + wn + i * 16 + r16;
    brow[i] = br > nMax ? nMax : br;
  }
  for (int k0 = 0; k0 < K; k0 += 32) {
    int kk = k0 + kq * 8;
    bf16x8 ah[4], al[4], bh[4], bl[4];
    #pragma unroll
    for (int i = 0; i < 4; ++i) {
      ah[i] = bload(Ah + (size_t)arow[i] * K + kk);
      al[i] = bload(Al + (size_t)arow[i] * K + kk);
      bh[i] = bload(Bh + (size_t)brow[i] * K + kk);
      bl[i] = bload(Bl + (size_t)brow[i] * K + kk);
    }
    #pragma unroll
    for (int i = 0; i < 4; ++i)
      #pragma unroll
      for (int j = 0; j < 4; ++j) {
        acc[i][j] = __builtin_amdgcn_mfma_f32_16x16x32_bf16(ah[i], bh[j], acc[i][j], 0, 0, 0);
        acc[i][j] = __builtin_amdgcn_mfma_f32_16x16x32_bf16(ah[i], bl[j], acc[i][j], 0, 0, 0);
        acc[i][j] = __builtin_amdgcn_mfma_f32_16x16x32_bf16(al[i], bh[j], acc[i][j], 0, 0, 0);
      }
  }
}

// ---------------- feat_proj = c_feats @ W_feat^T -> bf16 (MFMA) --------------
__global__ __launch_bounds__(256) void k_featproj(
    const float* __restrict__ A, const unsigned short* __restrict__ Wh,
    const unsigned short* __restrict__ Wl, unsigned short* __restrict__ out) {
  int lane = threadIdx.x & 63, wid = threadIdx.x >> 6;
  int wm = (wid >> 1) * 64, wn = (wid & 1) * 64;
  int r16 = lane & 15, kq = lane >> 4;
  int m0 = blockIdx.x * 128, n0 = blockIdx.y * 128;
  f32x4 acc[4][4];
  #pragma unroll
  for (int i = 0; i < 4; ++i)
    #pragma unroll
    for (int j = 0; j < 4; ++j) acc[i][j] = (f32x4){0.f, 0.f, 0.f, 0.f};
  for (int k0 = 0; k0 < kC; k0 += 32) {
    int kk = k0 + kq * 8;
    bf16x8 ah[4], al[4], bh[4], bl[4];
    #pragma unroll
    for (int i = 0; i < 4; ++i) {
      const float* pa = A + (size_t)(m0 + wm + i * 16 + r16) * kC + kk;
      float4 v0 = *(const float4*)pa;
      float4 v1 = *(const float4*)(pa + 4);
      float vv[8] = {v0.x, v0.y, v0.z, v0.w, v1.x, v1.y, v1.z, v1.w};
      union { unsigned short s[8]; bf16x8 v; } uh, ul;
      #pragma unroll
      for (int q = 0; q < 8; ++q) {
        unsigned short hb = f2bf(vv[q]);
        uh.s[q] = hb;
        ul.s[q] = f2bf(vv[q] - bf2f(hb));
      }
      ah[i] = uh.v; al[i] = ul.v;
      const unsigned short* pb = Wh + (size_t)(n0 + wn + i * 16 + r16) * kC + kk;
      const unsigned short* pl = Wl + (size_t)(n0 + wn + i * 16 + r16) * kC + kk;
      bh[i] = bload(pb); bl[i] = bload(pl);
    }
    #pragma unroll
    for (int i = 0; i < 4; ++i)
      #pragma unroll
      for (int j = 0; j < 4; ++j) {
        acc[i][j] = __builtin_amdgcn_mfma_f32_16x16x32_bf16(ah[i], bh[j], acc[i][j], 0, 0, 0);
        acc[i][j] = __builtin_amdgcn_mfma_f32_16x16x32_bf16(ah[i], bl[j], acc[i][j], 0, 0, 0);
        acc[i][j] = __builtin_amdgcn_mfma_f32_16x16x32_bf16(al[i], bh[j], acc[i][j], 0, 0, 0);
      }
  }
  #pragma unroll
  for (int i = 0; i < 4; ++i)
    #pragma unroll
    for (int j = 0; j < 4; ++j)
      #pragma unroll
      for (int r = 0; r < 4; ++r) {
        int m = m0 + wm + i * 16 + kq * 4 + r;
        int n = n0 + wn + j * 16 + r16;
        out[(size_t)m * kH + n] = f2bf(acc[i][j][r]);
      }
}

// ---------------- step kernel 1: [s-chain + gx1 GEMV] || [gh1/gh2 MFMA] ------
__global__ __launch_bounds__(256) void k_step1(
    const float* __restrict__ word_embs, int t,
    const float* __restrict__ h2, const float* __restrict__ td,
    const float* __restrict__ td3t, const float* __restrict__ td1t,
    const float* __restrict__ tdt, const float* __restrict__ iht1,
    const float* __restrict__ b1_ih,
    const unsigned short* __restrict__ h1h, const unsigned short* __restrict__ h1l,
    const unsigned short* __restrict__ h2h, const unsigned short* __restrict__ h2l,
    const unsigned short* __restrict__ w1hh_h, const unsigned short* __restrict__ w1hh_l,
    const unsigned short* __restrict__ w2hh_h, const unsigned short* __restrict__ w2hh_l,
    const float* __restrict__ b1_hh, const float* __restrict__ b2_hh,
    float* __restrict__ gx1, float* __restrict__ gh1, float* __restrict__ gh2) {
  __shared__ float smem[4784];
  int blk = blockIdx.x, tid = threadIdx.x;
  if (blk < 64) {
    // s = relu(tanh(x@W_td3^T + h2@W_td1^T + td) @ W_td^T); gx1 = s@W1_ih^T+b
    float* xl   = smem;          // [4][300]
    float* h2l_ = smem + 1200;   // [4][512]
    float* tdl  = smem + 3248;   // [4][128]
    float* s1   = smem + 3760;   // [4][128]
    float* s2   = smem + 4272;   // [4][128]
    int b0 = blk * 4;
    #pragma unroll
    for (int r = 0; r < 4; ++r) {
      const float* xs = word_embs + (size_t)(b0 + r) * (kT * kE) + (size_t)t * kE;
      for (int e = tid; e < kE; e += 256) xl[r * kE + e] = xs[e];
    }
    for (int i = tid; i < 2048; i += 256) h2l_[i] = h2[(size_t)b0 * kH + i];
    for (int i = tid; i < 512; i += 256) tdl[i] = td[(size_t)b0 * kC + i];
    __syncthreads();
    #pragma unroll
    for (int q = 0; q < 2; ++q) {
      int idx = tid + q * 256;
      int r = idx >> 7, c = idx & 127;
      float acc = tdl[idx];
      const float* xr = xl + r * kE;
      const float* w3 = td3t + c;
      for (int e = 0; e < kE; ++e) acc = fmaf(xr[e], w3[(size_t)e * 128], acc);
      const float* hr = h2l_ + r * kH;
      const float* w1 = td1t + c;
      for (int k = 0; k < kH; ++k) acc = fmaf(hr[k], w1[(size_t)k * 128], acc);
      s1[idx] = ftanh(acc);
    }
    __syncthreads();
    #pragma unroll
    for (int q = 0; q < 2; ++q) {
      int idx = tid + q * 256;
      int r = idx >> 7, c = idx & 127;
      float acc = 0.f;
      const float* sr = s1 + r * kC;
      const float* w = tdt + c;
      for (int k = 0; k < kC; ++k) acc = fmaf(sr[k], w[(size_t)k * 128], acc);
      s2[idx] = fmaxf(acc, 0.f);
    }
    __syncthreads();
    // gx1[4][1536] = s2 @ iht1 + b1_ih  (weights streamed once, 4-row reuse)
    #pragma unroll
    for (int q = 0; q < 6; ++q) {
      int j = q * 256 + tid;
      float bj = b1_ih[j];
      float a0 = bj, a1 = bj, a2 = bj, a3 = bj;
      const float* w = iht1 + j;
      #pragma unroll 4
      for (int k = 0; k < kC; ++k) {
        float wv = w[(size_t)k * kG];
        a0 = fmaf(s2[k], wv, a0);
        a1 = fmaf(s2[128 + k], wv, a1);
        a2 = fmaf(s2[256 + k], wv, a2);
        a3 = fmaf(s2[384 + k], wv, a3);
      }
      gx1[(size_t)(b0 + 0) * kG + j] = a0;
      gx1[(size_t)(b0 + 1) * kG + j] = a1;
      gx1[(size_t)(b0 + 2) * kG + j] = a2;
      gx1[(size_t)(b0 + 3) * kG + j] = a3;
    }
  } else {
    // gh = h @ W_hh^T + b_hh  (256x1536, K=512) via split-bf16 MFMA
    int g = blk - 64;   // 0..47
    const unsigned short *Ah, *Al, *Wh, *Wl; const float* bias; float* out;
    if (g < 24) { Ah = h1h; Al = h1l; Wh = w1hh_h; Wl = w1hh_l;
                  bias = b1_hh; out = gh1; }
    else { g -= 24; Ah = h2h; Al = h2l; Wh = w2hh_h; Wl = w2hh_l;
           bias = b2_hh; out = gh2; }
    int m0 = (g / 12) * 128, n0 = (g % 12) * 128;
    f32x4 acc[4][4];
    #pragma unroll
    for (int i = 0; i < 4; ++i)
      #pragma unroll
      for (int j = 0; j < 4; ++j) acc[i][j] = (f32x4){0.f, 0.f, 0.f, 0.f};
    mm_split_tile(Ah, Al, Wh, Wl, m0, n0, kH, kG - 1, acc);
    int lane = tid & 63, wid = tid >> 6;
    int wm = (wid >> 1) * 64, wn = (wid & 1) * 64;
    int r16 = lane & 15, kq = lane >> 4;
    #pragma unroll
    for (int i = 0; i < 4; ++i)
      #pragma unroll
      for (int j = 0; j < 4; ++j)
        #pragma unroll
        for (int r = 0; r < 4; ++r) {
          int m = m0 + wm + i * 16 + kq * 4 + r;
          int n = n0 + wn + j * 16 + r16;
          out[(size_t)m * kG + n] = acc[i][j][r] + bias[n];
        }
  }
}

// ---------------- step kernel 2: row-local GRU1+hq+attn+lang+GRU2 ------------
// 128 blocks x 512 threads; block owns batch rows {2*blk, 2*blk+1}.
__global__ __launch_bounds__(512) void k_step2(
    const float* __restrict__ gx1, const float* __restrict__ gh1,
    const float* __restrict__ gh2,
    float* __restrict__ h1, float* __restrict__ h2,
    unsigned short* __restrict__ h1h, unsigned short* __restrict__ h1l,
    unsigned short* __restrict__ h2h, unsigned short* __restrict__ h2l,
    const float* __restrict__ whd_t, const float* __restrict__ W_att,
    const unsigned short* __restrict__ fp, const float* __restrict__ c_feats,
    const float* __restrict__ l1t, const float* __restrict__ l2t,
    const float* __restrict__ lt, const float* __restrict__ iht2,
    const float* __restrict__ b2_ih,
    unsigned short* __restrict__ h2all_h, unsigned short* __restrict__ h2all_l,
    float* __restrict__ attn_out, int t) {
  __shared__ float h1p[2 * 512];
  __shared__ float hqs[2 * 512];
  __shared__ float scs[2 * 256];
  __shared__ float red[8];
  __shared__ float red2[8];
  __shared__ float part[2 * 2 * 128];
  __shared__ float attl[2 * 128];
  __shared__ float lt1[2 * 128];
  __shared__ float llv[2 * 128];
  const int b0 = blockIdx.x * 2;
  const int tid = threadIdx.x;

  // ---- GRU1 combine -> h1' ----
  #pragma unroll
  for (int q = 0; q < 2; ++q) {
    int idx = tid + q * 512;
    int r = idx >> 9, c = idx & 511;
    int b = b0 + r;
    float gr = gx1[(size_t)b * kG + c];
    float gz = gx1[(size_t)b * kG + 512 + c];
    float gn = gx1[(size_t)b * kG + 1024 + c];
    float hr = gh1[(size_t)b * kG + c];
    float hz = gh1[(size_t)b * kG + 512 + c];
    float hnv = gh1[(size_t)b * kG + 1024 + c];
    float rr = fsigm(gr + hr);
    float zz = fsigm(gz + hz);
    float nn = ftanh(gn + rr * hnv);
    float ho = h1[(size_t)b * kH + c];
    float hn = (1.f - zz) * nn + zz * ho;
    h1[(size_t)b * kH + c] = hn;
    h1p[idx] = hn;
    unsigned short hb = f2bf(hn);
    h1h[(size_t)b * kH + c] = hb;
    h1l[(size_t)b * kH + c] = f2bf(hn - bf2f(hb));
  }
  __syncthreads();

  // ---- hq = h1' @ W_hidd^T (fp32 GEMV, weight streamed once, 2-row reuse) ----
  {
    int c = tid;
    float a0 = 0.f, a1 = 0.f;
    const float* w = whd_t + c;
    #pragma unroll 4
    for (int k = 0; k < kH; ++k) {
      float wv = w[(size_t)k * kH];
      a0 = fmaf(h1p[k], wv, a0);
      a1 = fmaf(h1p[512 + k], wv, a1);
    }
    hqs[c] = a0;
    hqs[512 + c] = a1;
  }
  __syncthreads();

  // ---- attention scores: half-block per row ----
  {
    int row = tid >> 8, rtid = tid & 255;
    int lane = rtid & 63, wv = rtid >> 6;
    int b = b0 + row;
    float hq8[8], aw[8];
    #pragma unroll
    for (int j = 0; j < 8; ++j) hq8[j] = hqs[row * 512 + lane * 8 + j];
    {
      float4 a0 = *(const float4*)(W_att + lane * 8);
      float4 a1 = *(const float4*)(W_att + lane * 8 + 4);
      aw[0] = a0.x; aw[1] = a0.y; aw[2] = a0.z; aw[3] = a0.w;
      aw[4] = a1.x; aw[5] = a1.y; aw[6] = a1.z; aw[7] = a1.w;
    }
    const unsigned short* fpb = fp + (size_t)b * kP * kH;
    for (int p = wv * 64; p < wv * 64 + 64; ++p) {
      uint4 rv = *(const uint4*)(fpb + (size_t)p * kH + lane * 8);
      union { uint4 v; unsigned short s[8]; } u; u.v = rv;
      float sc = 0.f;
      #pragma unroll
      for (int j = 0; j < 8; ++j) {
        float f = __uint_as_float((unsigned)u.s[j] << 16);
        sc += aw[j] * ftanh(f + hq8[j]);
      }
      #pragma unroll
      for (int m = 32; m; m >>= 1) sc += __shfl_xor(sc, m, 64);
      if (lane == 0) scs[row * 256 + p] = sc;
    }
  }
  __syncthreads();

  // ---- softmax over 256 proposals, per row ----
  {
    int row = tid >> 8, rtid = tid & 255;
    int lane = rtid & 63, wv = rtid >> 6;
    int b = b0 + row;
    float sv = scs[row * 256 + rtid];
    float mx = sv;
    #pragma unroll
    for (int m = 32; m; m >>= 1) mx = fmaxf(mx, __shfl_xor(mx, m, 64));
    if (lane == 0) red[row * 4 + wv] = mx;
    __syncthreads();
    float bm = fmaxf(fmaxf(red[row * 4], red[row * 4 + 1]),
                     fmaxf(red[row * 4 + 2], red[row * 4 + 3]));
    float ev = fexp2((sv - bm) * 1.4426950408889634f);
    float sm = ev;
    #pragma unroll
    for (int m = 32; m; m >>= 1) sm += __shfl_xor(sm, m, 64);
    if (lane == 0) red2[row * 4 + wv] = sm;
    __syncthreads();
    float tot = red2[row * 4] + red2[row * 4 + 1] +
                red2[row * 4 + 2] + red2[row * 4 + 3];
    float mk = ev * frcp(tot);
    scs[row * 256 + rtid] = mk;
    attn_out[((size_t)b * kP + rtid) * kNS + t] = mk;
  }
  __syncthreads();

  // ---- attended = mask @ c_feats ----
  {
    int row = tid >> 8, rtid = tid & 255;
    int c = rtid & 127, q = rtid >> 7;
    int b = b0 + row;
    const float* cf = c_feats + ((size_t)b * kP + q * 128) * kC + c;
    const float* ms = scs + row * 256 + q * 128;
    float acc = 0.f;
    for (int p = 0; p < 128; ++p) acc = fmaf(ms[p], cf[(size_t)p * kC], acc);
    part[(row * 2 + q) * 128 + c] = acc;
  }
  __syncthreads();
  if (tid < 256) {
    int row = tid >> 7, c = tid & 127;
    attl[row * 128 + c] =
        part[(row * 2) * 128 + c] + part[(row * 2 + 1) * 128 + c];
  }
  __syncthreads();

  // ---- language chain ----
  if (tid < 256) {
    int r = tid >> 7, c = tid & 127;
    float acc = 0.f;
    const float* a = attl + r * 128;
    const float* w1 = l1t + c;
    for (int k = 0; k < kC; ++k) acc = fmaf(a[k], w1[(size_t)k * 128], acc);
    const float* hr = h1p + r * 512;
    const float* w2 = l2t + c;
    for (int k = 0; k < kH; ++k) acc = fmaf(hr[k], w2[(size_t)k * 128], acc);
    lt1[tid] = ftanh(acc);
  }
  __syncthreads();
  if (tid < 256) {
    int r = tid >> 7, c = tid & 127;
    float acc = 0.f;
    const float* lr_ = lt1 + r * 128;
    const float* w = lt + c;
    for (int k = 0; k < kC; ++k) acc = fmaf(lr_[k], w[(size_t)k * 128], acc);
    llv[tid] = fmaxf(acc, 0.f);
  }
  __syncthreads();

  // ---- gx2 GEMV + GRU2 combine -> h2' ----
  {
    int c = tid;
    float b0v = b2_ih[c], b1v = b2_ih[512 + c], b2v = b2_ih[1024 + c];
    float a00 = b0v, a01 = b1v, a02 = b2v;
    float a10 = b0v, a11 = b1v, a12 = b2v;
    const float* w = iht2;
    #pragma unroll 4
    for (int k = 0; k < kC; ++k) {
      float w0 = w[(size_t)k * kG + c];
      float w1 = w[(size_t)k * kG + 512 + c];
      float w2 = w[(size_t)k * kG + 1024 + c];
      float l0 = llv[k], l1 = llv[128 + k];
      a00 = fmaf(l0, w0, a00); a01 = fmaf(l0, w1, a01); a02 = fmaf(l0, w2, a02);
      a10 = fmaf(l1, w0, a10); a11 = fmaf(l1, w1, a11); a12 = fmaf(l1, w2, a12);
    }
    #pragma unroll
    for (int r = 0; r < 2; ++r) {
      int b = b0 + r;
      float g0 = r ? a10 : a00, g1 = r ? a11 : a01, g2 = r ? a12 : a02;
      float ghr = gh2[(size_t)b * kG + c];
      float ghz = gh2[(size_t)b * kG + 512 + c];
      float ghn = gh2[(size_t)b * kG + 1024 + c];
      float rr = fsigm(g0 + ghr);
      float zz = fsigm(g1 + ghz);
      float nn = ftanh(g2 + rr * ghn);
      float ho = h2[(size_t)b * kH + c];
      float hn = (1.f - zz) * nn + zz * ho;
      h2[(size_t)b * kH + c] = hn;
      unsigned short hb = f2bf(hn);
      unsigned short lb = f2bf(hn - bf2f(hb));
      h2h[(size_t)b * kH + c] = hb;
      h2l[(size_t)b * kH + c] = lb;
      size_t o = ((size_t)t * kB + b) * kH + c;
      h2all_h[o] = hb;
      h2all_l[o] = lb;
    }
  }
}

// ---------------- classifier: lang = h2_all @ W_cls^T + b_cls (MFMA) ---------
__global__ __launch_bounds__(256) void k_cls(
    const unsigned short* __restrict__ Ah, const unsigned short* __restrict__ Al,
    const unsigned short* __restrict__ Wh, const unsigned short* __restrict__ Wl,
    const float* __restrict__ bc, float* __restrict__ out) {
  int m0 = blockIdx.x * 128, n0 = blockIdx.y * 128;
  f32x4 acc[4][4];
  #pragma unroll
  for (int i = 0; i < 4; ++i)
    #pragma unroll
    for (int j = 0; j < 4; ++j) acc[i][j] = (f32x4){0.f, 0.f, 0.f, 0.f};
  mm_split_tile(Ah, Al, Wh, Wl, m0, n0, kH, kV - 1, acc);
  int lane = threadIdx.x & 63, wid = threadIdx.x >> 6;
  int wm = (wid >> 1) * 64, wn = (wid & 1) * 64;
  int r16 = lane & 15, kq = lane >> 4;
  #pragma unroll
  for (int i = 0; i < 4; ++i)
    #pragma unroll
    for (int j = 0; j < 4; ++j)
      #pragma unroll
      for (int r = 0; r < 4; ++r) {
        int m = m0 + wm + i * 16 + kq * 4 + r;
        int n = n0 + wn + j * 16 + r16;
        if (n < kV) {
          int tt = m >> 8, b = m & 255;
          out[(size_t)b * (kNS * kV) + (size_t)tt * kV + n] = acc[i][j][r] + bc[n];
        }
      }
}

}  // namespace

extern "C" void kernel_launch(void* const* d_in, const int* in_sizes, int n_in,
                              void* d_out, int out_size, void* d_ws,
                              size_t ws_size, hipStream_t stream) {
  (void)in_sizes; (void)n_in; (void)out_size; (void)ws_size;
  const float* word_embs = (const float*)d_in[0];
  const float* t_feat    = (const float*)d_in[1];
  const float* c_feats   = (const float*)d_in[2];
  const float* W_td1 = (const float*)d_in[4];
  const float* W_td2 = (const float*)d_in[5];
  const float* W_td3 = (const float*)d_in[6];
  const float* W_td  = (const float*)d_in[7];
  const float* W1_ih = (const float*)d_in[8];
  const float* W1_hh = (const float*)d_in[9];
  const float* b1_ih = (const float*)d_in[10];
  const float* b1_hh = (const float*)d_in[11];
  const float* W_feat = (const float*)d_in[12];
  const float* W_hidd = (const float*)d_in[13];
  const float* W_att  = (const float*)d_in[14];
  const float* W_l1 = (const float*)d_in[15];
  const float* W_l2 = (const float*)d_in[16];
  const float* W_l  = (const float*)d_in[17];
  const float* W2_ih = (const float*)d_in[18];
  const float* W2_hh = (const float*)d_in[19];
  const float* b2_ih = (const float*)d_in[20];
  const float* b2_hh = (const float*)d_in[21];
  const float* W_cls = (const float*)d_in[22];
  const float* b_cls = (const float*)d_in[23];

  float* lang = (float*)d_out;
  float* attn_out = lang + (size_t)kB * kNS * kV;
  // feat_proj (bf16, 64MB) lives in the lang_cap region of d_out — dead by
  // the time k_cls (the only writer of lang_cap) runs.
  unsigned short* fp = (unsigned short*)d_out;

  float* p = (float*)d_ws;
  float* h1 = p;      p += kB * kH;
  float* h2 = p;      p += kB * kH;
  float* td = p;      p += kB * kC;
  float* gx1 = p;     p += (size_t)kB * kG;
  float* gh1 = p;     p += (size_t)kB * kG;
  float* gh2 = p;     p += (size_t)kB * kG;
  float* td3t = p;    p += kE * 128;
  float* td1t = p;    p += kH * 128;
  float* tdt  = p;    p += 128 * 128;
  float* l1t  = p;    p += 128 * 128;
  float* l2t  = p;    p += kH * 128;
  float* lt   = p;    p += 128 * 128;
  float* iht1 = p;    p += 128 * kG;
  float* iht2 = p;    p += 128 * kG;
  float* whd_t = p;   p += kH * kH;

  unsigned short* u = (unsigned short*)p;
  unsigned short* h1h = u;     u += kB * kH;
  unsigned short* h1l = u;     u += kB * kH;
  unsigned short* h2h = u;     u += kB * kH;
  unsigned short* h2l = u;     u += kB * kH;
  unsigned short* w1hh_h = u;  u += (size_t)kG * kH;
  unsigned short* w1hh_l = u;  u += (size_t)kG * kH;
  unsigned short* w2hh_h = u;  u += (size_t)kG * kH;
  unsigned short* w2hh_l = u;  u += (size_t)kG * kH;
  unsigned short* wc_h = u;    u += (size_t)kV * kH;
  unsigned short* wc_l = u;    u += (size_t)kV * kH;
  unsigned short* wf_h = u;    u += (size_t)kH * kC;
  unsigned short* wf_l = u;    u += (size_t)kH * kC;
  unsigned short* h2all_h = u; u += (size_t)kNS * kB * kH;
  unsigned short* h2all_l = u; u += (size_t)kNS * kB * kH;

  k_transpose<<<dim3(64, 9), 256, 0, stream>>>(
      W_td3, W_td1, W_td, W_l1, W_l2, W_l, W1_ih, W2_ih, W_hidd,
      td3t, td1t, tdt, l1t, l2t, lt, iht1, iht2, whd_t);
  k_split<<<dim3(256, 4), 256, 0, stream>>>(
      W1_hh, W2_hh, W_cls, W_feat,
      w1hh_h, w1hh_l, w2hh_h, w2hh_l, wc_h, wc_l, wf_h, wf_l);
  k_init<<<128, 256, 0, stream>>>(t_feat, W_td2, td, h1, h2,
                                  h1h, h1l, h2h, h2l);
  k_featproj<<<dim3(512, 4), 256, 0, stream>>>(c_feats, wf_h, wf_l, fp);

  for (int t = 0; t < kNS; ++t) {
    k_step1<<<112, 256, 0, stream>>>(word_embs, t, h2, td, td3t, td1t, tdt,
                                     iht1, b1_ih, h1h, h1l, h2h, h2l,
                                     w1hh_h, w1hh_l, w2hh_h, w2hh_l,
                                     b1_hh, b2_hh, gx1, gh1, gh2);
    k_step2<<<128, 512, 0, stream>>>(gx1, gh1, gh2, h1, h2,
                                     h1h, h1l, h2h, h2l, whd_t, W_att, fp,
                                     c_feats, l1t, l2t, lt, iht2, b2_ih,
                                     h2all_h, h2all_l, attn_out, t);
  }
  k_cls<<<dim3(62, 27), 256, 0, stream>>>(h2all_h, h2all_l, wc_h, wc_l,
                                          b_cls, lang);
}

// Round 5
// 5252.645 us; speedup vs baseline: 7.7600x; 1.3525x over previous
//
#include <hip/hip_runtime.h>
#include <hip/hip_bf16.h>

namespace {

constexpr int kB  = 256;   // batch
constexpr int kP  = 256;   // proposals
constexpr int kT  = 32;    // words
constexpr int kNS = 31;    // steps = T-1
constexpr int kV  = 3433;  // vocab
constexpr int kH  = 512;   // hidden
constexpr int kE  = 300;   // embed
constexpr int kC  = 128;   // feat dim
constexpr int kG  = 1536;  // 3H

typedef __bf16 bf16x8 __attribute__((ext_vector_type(8)));
typedef float f32x4 __attribute__((ext_vector_type(4)));

__device__ __forceinline__ float fexp2(float x) {
  float r; asm("v_exp_f32 %0, %1" : "=v"(r) : "v"(x)); return r;
}
__device__ __forceinline__ float frcp(float x) {
  float r; asm("v_rcp_f32 %0, %1" : "=v"(r) : "v"(x)); return r;
}
__device__ __forceinline__ float ftanh(float x) {
  float e = fexp2(x * 2.8853900817779268f);   // e^(2x)
  return 1.0f - 2.0f * frcp(e + 1.0f);
}
__device__ __forceinline__ float fsigm(float x) {
  return frcp(1.0f + fexp2(x * -1.4426950408889634f));
}
__device__ __forceinline__ unsigned short f2bf(float f) {   // RNE bf16
  unsigned u = __float_as_uint(f);
  u += 0x7FFFu + ((u >> 16) & 1u);
  return (unsigned short)(u >> 16);
}
__device__ __forceinline__ float bf2f(unsigned short s) {
  return __uint_as_float((unsigned)s << 16);
}
__device__ __forceinline__ bf16x8 bload(const unsigned short* p) {
  union { uint4 u; bf16x8 v; } x;
  x.u = *(const uint4*)p;
  return x.v;
}

// ---------------- one-time weight transposes (W[r][k] -> Wt[k*R + r]) -------
__global__ void k_transpose(const float* s0, const float* s1, const float* s2,
                            const float* s3, const float* s4, const float* s5,
                            const float* s6, const float* s7, const float* s8,
                            float* d0, float* d1, float* d2, float* d3,
                            float* d4, float* d5, float* d6, float* d7,
                            float* d8) {
  const float* src; float* dst; int R, Cd;
  switch (blockIdx.y) {
    case 0:  src = s0; dst = d0; R = 128;  Cd = 300; break;  // W_td3
    case 1:  src = s1; dst = d1; R = 128;  Cd = 512; break;  // W_td1
    case 2:  src = s2; dst = d2; R = 128;  Cd = 128; break;  // W_td
    case 3:  src = s3; dst = d3; R = 128;  Cd = 128; break;  // W_l1
    case 4:  src = s4; dst = d4; R = 128;  Cd = 512; break;  // W_l2
    case 5:  src = s5; dst = d5; R = 128;  Cd = 128; break;  // W_l
    case 6:  src = s6; dst = d6; R = 1536; Cd = 128; break;  // W1_ih
    case 7:  src = s7; dst = d7; R = 1536; Cd = 128; break;  // W2_ih
    default: src = s8; dst = d8; R = 512;  Cd = 512; break;  // W_hidd
  }
  int n = R * Cd;
  for (int i = blockIdx.x * blockDim.x + threadIdx.x; i < n;
       i += gridDim.x * blockDim.x) {
    int k = i / R, r = i - k * R;
    dst[i] = src[r * Cd + k];    // dst[k*R + r]
  }
}

// ---------------- bf16 copies of the K2-local transposed weights -------------
__global__ void k_tobf16(const float* s0, const float* s1, const float* s2,
                         const float* s3, const float* s4,
                         unsigned short* d0, unsigned short* d1,
                         unsigned short* d2, unsigned short* d3,
                         unsigned short* d4) {
  const float* s; unsigned short* d; int n;
  switch (blockIdx.y) {
    case 0:  s = s0; d = d0; n = kC * kC; break;   // l1t
    case 1:  s = s1; d = d1; n = kH * kC; break;   // l2t
    case 2:  s = s2; d = d2; n = kC * kC; break;   // lt
    case 3:  s = s3; d = d3; n = kC * kG; break;   // iht2
    default: s = s4; d = d4; n = kH * kH; break;   // whd_t
  }
  for (int i = blockIdx.x * blockDim.x + threadIdx.x; i < n;
       i += gridDim.x * blockDim.x)
    d[i] = f2bf(s[i]);
}

// ---------------- one-time weight hi/lo bf16 splits --------------------------
__global__ void k_split(const float* s0, const float* s1, const float* s2,
                        const float* s3,
                        unsigned short* h0, unsigned short* l0,
                        unsigned short* h1, unsigned short* l1,
                        unsigned short* h2, unsigned short* l2,
                        unsigned short* h3, unsigned short* l3) {
  const float* s; unsigned short* h; unsigned short* l; int n;
  switch (blockIdx.y) {
    case 0:  s = s0; h = h0; l = l0; n = kG * kH; break;   // W1_hh
    case 1:  s = s1; h = h1; l = l1; n = kG * kH; break;   // W2_hh
    case 2:  s = s2; h = h2; l = l2; n = kV * kH; break;   // W_cls
    default: s = s3; h = h3; l = l3; n = kH * kC; break;   // W_feat
  }
  for (int i = blockIdx.x * blockDim.x + threadIdx.x; i < n;
       i += gridDim.x * blockDim.x) {
    float v = s[i];
    unsigned short hb = f2bf(v);
    h[i] = hb;
    l[i] = f2bf(v - bf2f(hb));
  }
}

// ---------------- init: td = t_feat @ W_td2^T ; zero h states ----------------
__global__ void k_init(const float* __restrict__ t_feat,
                       const float* __restrict__ W_td2,
                       float* __restrict__ td, float* __restrict__ h1,
                       float* __restrict__ h2,
                       unsigned short* __restrict__ h1h,
                       unsigned short* __restrict__ h1l,
                       unsigned short* __restrict__ h2h,
                       unsigned short* __restrict__ h2l) {
  int tid = blockIdx.x * 256 + threadIdx.x;  // 32768 threads
  int b = tid >> 7, c = tid & 127;
  const float* tf = t_feat + b * kC;
  const float* w  = W_td2 + c * kC;
  float acc = 0.f;
  for (int k = 0; k < kC; ++k) acc = fmaf(tf[k], w[k], acc);
  td[tid] = acc;
  for (int i = tid; i < kB * kH; i += (1 << 15)) {
    h1[i] = 0.f; h2[i] = 0.f;
    h1h[i] = 0; h1l[i] = 0; h2h[i] = 0; h2l[i] = 0;
  }
}

// ---------------- split-bf16 MFMA 128x128 tile (3-term) ----------------------
__device__ __forceinline__ void mm_split_tile(
    const unsigned short* __restrict__ Ah, const unsigned short* __restrict__ Al,
    const unsigned short* __restrict__ Bh, const unsigned short* __restrict__ Bl,
    int m0, int n0, int K, int nMax, f32x4 acc[4][4]) {
  int lane = threadIdx.x & 63, wid = (threadIdx.x >> 6) & 3;
  int wm = (wid >> 1) * 64, wn = (wid & 1) * 64;
  int r16 = lane & 15, kq = lane >> 4;
  int arow[4], brow[4];
  #pragma unroll
  for (int i = 0; i < 4; ++i) {
    arow[i] = m0 + wm + i * 16 + r16;
    int br = n0 + wn + i * 16 + r16;
    brow[i] = br > nMax ? nMax : br;
  }
  for (int k0 = 0; k0 < K; k0 += 32) {
    int kk = k0 + kq * 8;
    bf16x8 ah[4], al[4], bh[4], bl[4];
    #pragma unroll
    for (int i = 0; i < 4; ++i) {
      ah[i] = bload(Ah + (size_t)arow[i] * K + kk);
      al[i] = bload(Al + (size_t)arow[i] * K + kk);
      bh[i] = bload(Bh + (size_t)brow[i] * K + kk);
      bl[i] = bload(Bl + (size_t)brow[i] * K + kk);
    }
    #pragma unroll
    for (int i = 0; i < 4; ++i)
      #pragma unroll
      for (int j = 0; j < 4; ++j) {
        acc[i][j] = __builtin_amdgcn_mfma_f32_16x16x32_bf16(ah[i], bh[j], acc[i][j], 0, 0, 0);
        acc[i][j] = __builtin_amdgcn_mfma_f32_16x16x32_bf16(ah[i], bl[j], acc[i][j], 0, 0, 0);
        acc[i][j] = __builtin_amdgcn_mfma_f32_16x16x32_bf16(al[i], bh[j], acc[i][j], 0, 0, 0);
      }
  }
}

// ---------------- feat_proj = c_feats @ W_feat^T -> bf16 (MFMA) --------------
__global__ __launch_bounds__(256) void k_featproj(
    const float* __restrict__ A, const unsigned short* __restrict__ Wh,
    const unsigned short* __restrict__ Wl, unsigned short* __restrict__ out) {
  int lane = threadIdx.x & 63, wid = threadIdx.x >> 6;
  int wm = (wid >> 1) * 64, wn = (wid & 1) * 64;
  int r16 = lane & 15, kq = lane >> 4;
  int m0 = blockIdx.x * 128, n0 = blockIdx.y * 128;
  f32x4 acc[4][4];
  #pragma unroll
  for (int i = 0; i < 4; ++i)
    #pragma unroll
    for (int j = 0; j < 4; ++j) acc[i][j] = (f32x4){0.f, 0.f, 0.f, 0.f};
  for (int k0 = 0; k0 < kC; k0 += 32) {
    int kk = k0 + kq * 8;
    bf16x8 ah[4], al[4], bh[4], bl[4];
    #pragma unroll
    for (int i = 0; i < 4; ++i) {
      const float* pa = A + (size_t)(m0 + wm + i * 16 + r16) * kC + kk;
      float4 v0 = *(const float4*)pa;
      float4 v1 = *(const float4*)(pa + 4);
      float vv[8] = {v0.x, v0.y, v0.z, v0.w, v1.x, v1.y, v1.z, v1.w};
      union { unsigned short s[8]; bf16x8 v; } uh, ul;
      #pragma unroll
      for (int q = 0; q < 8; ++q) {
        unsigned short hb = f2bf(vv[q]);
        uh.s[q] = hb;
        ul.s[q] = f2bf(vv[q] - bf2f(hb));
      }
      ah[i] = uh.v; al[i] = ul.v;
      const unsigned short* pb = Wh + (size_t)(n0 + wn + i * 16 + r16) * kC + kk;
      const unsigned short* pl = Wl + (size_t)(n0 + wn + i * 16 + r16) * kC + kk;
      bh[i] = bload(pb); bl[i] = bload(pl);
    }
    #pragma unroll
    for (int i = 0; i < 4; ++i)
      #pragma unroll
      for (int j = 0; j < 4; ++j) {
        acc[i][j] = __builtin_amdgcn_mfma_f32_16x16x32_bf16(ah[i], bh[j], acc[i][j], 0, 0, 0);
        acc[i][j] = __builtin_amdgcn_mfma_f32_16x16x32_bf16(ah[i], bl[j], acc[i][j], 0, 0, 0);
        acc[i][j] = __builtin_amdgcn_mfma_f32_16x16x32_bf16(al[i], bh[j], acc[i][j], 0, 0, 0);
      }
  }
  #pragma unroll
  for (int i = 0; i < 4; ++i)
    #pragma unroll
    for (int j = 0; j < 4; ++j)
      #pragma unroll
      for (int r = 0; r < 4; ++r) {
        int m = m0 + wm + i * 16 + kq * 4 + r;
        int n = n0 + wn + j * 16 + r16;
        out[(size_t)m * kH + n] = f2bf(acc[i][j][r]);
      }
}

// ---------------- step kernel 1: [s-chain + gx1 GEMV] || [gh1/gh2 MFMA] ------
__global__ __launch_bounds__(256) void k_step1(
    const float* __restrict__ word_embs, int t,
    const float* __restrict__ h2, const float* __restrict__ td,
    const float* __restrict__ td3t, const float* __restrict__ td1t,
    const float* __restrict__ tdt, const float* __restrict__ iht1,
    const float* __restrict__ b1_ih,
    const unsigned short* __restrict__ h1h, const unsigned short* __restrict__ h1l,
    const unsigned short* __restrict__ h2h, const unsigned short* __restrict__ h2l,
    const unsigned short* __restrict__ w1hh_h, const unsigned short* __restrict__ w1hh_l,
    const unsigned short* __restrict__ w2hh_h, const unsigned short* __restrict__ w2hh_l,
    const float* __restrict__ b1_hh, const float* __restrict__ b2_hh,
    float* __restrict__ gx1, float* __restrict__ gh1, float* __restrict__ gh2) {
  __shared__ float smem[4784];
  int blk = blockIdx.x, tid = threadIdx.x;
  if (blk < 64) {
    float* xl   = smem;          // [4][300]
    float* h2l_ = smem + 1200;   // [4][512]
    float* tdl  = smem + 3248;   // [4][128]
    float* s1   = smem + 3760;   // [4][128]
    float* s2   = smem + 4272;   // [4][128]
    int b0 = blk * 4;
    #pragma unroll
    for (int r = 0; r < 4; ++r) {
      const float* xs = word_embs + (size_t)(b0 + r) * (kT * kE) + (size_t)t * kE;
      for (int e = tid; e < kE; e += 256) xl[r * kE + e] = xs[e];
    }
    for (int i = tid; i < 2048; i += 256) h2l_[i] = h2[(size_t)b0 * kH + i];
    for (int i = tid; i < 512; i += 256) tdl[i] = td[(size_t)b0 * kC + i];
    __syncthreads();
    #pragma unroll
    for (int q = 0; q < 2; ++q) {
      int idx = tid + q * 256;
      int r = idx >> 7, c = idx & 127;
      float acc = tdl[idx];
      const float* xr = xl + r * kE;
      const float* w3 = td3t + c;
      for (int e = 0; e < kE; ++e) acc = fmaf(xr[e], w3[(size_t)e * 128], acc);
      const float* hr = h2l_ + r * kH;
      const float* w1 = td1t + c;
      for (int k = 0; k < kH; ++k) acc = fmaf(hr[k], w1[(size_t)k * 128], acc);
      s1[idx] = ftanh(acc);
    }
    __syncthreads();
    #pragma unroll
    for (int q = 0; q < 2; ++q) {
      int idx = tid + q * 256;
      int r = idx >> 7, c = idx & 127;
      float acc = 0.f;
      const float* sr = s1 + r * kC;
      const float* w = tdt + c;
      for (int k = 0; k < kC; ++k) acc = fmaf(sr[k], w[(size_t)k * 128], acc);
      s2[idx] = fmaxf(acc, 0.f);
    }
    __syncthreads();
    #pragma unroll
    for (int q = 0; q < 6; ++q) {
      int j = q * 256 + tid;
      float bj = b1_ih[j];
      float a0 = bj, a1 = bj, a2 = bj, a3 = bj;
      const float* w = iht1 + j;
      #pragma unroll 4
      for (int k = 0; k < kC; ++k) {
        float wv = w[(size_t)k * kG];
        a0 = fmaf(s2[k], wv, a0);
        a1 = fmaf(s2[128 + k], wv, a1);
        a2 = fmaf(s2[256 + k], wv, a2);
        a3 = fmaf(s2[384 + k], wv, a3);
      }
      gx1[(size_t)(b0 + 0) * kG + j] = a0;
      gx1[(size_t)(b0 + 1) * kG + j] = a1;
      gx1[(size_t)(b0 + 2) * kG + j] = a2;
      gx1[(size_t)(b0 + 3) * kG + j] = a3;
    }
  } else {
    int g = blk - 64;   // 0..47
    const unsigned short *Ah, *Al, *Wh, *Wl; const float* bias; float* out;
    if (g < 24) { Ah = h1h; Al = h1l; Wh = w1hh_h; Wl = w1hh_l;
                  bias = b1_hh; out = gh1; }
    else { g -= 24; Ah = h2h; Al = h2l; Wh = w2hh_h; Wl = w2hh_l;
           bias = b2_hh; out = gh2; }
    int m0 = (g / 12) * 128, n0 = (g % 12) * 128;
    f32x4 acc[4][4];
    #pragma unroll
    for (int i = 0; i < 4; ++i)
      #pragma unroll
      for (int j = 0; j < 4; ++j) acc[i][j] = (f32x4){0.f, 0.f, 0.f, 0.f};
    mm_split_tile(Ah, Al, Wh, Wl, m0, n0, kH, kG - 1, acc);
    int lane = tid & 63, wid = tid >> 6;
    int wm = (wid >> 1) * 64, wn = (wid & 1) * 64;
    int r16 = lane & 15, kq = lane >> 4;
    #pragma unroll
    for (int i = 0; i < 4; ++i)
      #pragma unroll
      for (int j = 0; j < 4; ++j)
        #pragma unroll
        for (int r = 0; r < 4; ++r) {
          int m = m0 + wm + i * 16 + kq * 4 + r;
          int n = n0 + wn + j * 16 + r16;
          out[(size_t)m * kG + n] = acc[i][j][r] + bias[n];
        }
  }
}

// ---------------- step kernel 2: one batch row per block ---------------------
// 256 blocks x 512 threads. GRU1 -> hq -> attention -> lang -> GRU2.
__global__ __launch_bounds__(512) void k_step2(
    const float* __restrict__ gx1, const float* __restrict__ gh1,
    const float* __restrict__ gh2,
    float* __restrict__ h1, float* __restrict__ h2,
    unsigned short* __restrict__ h1h, unsigned short* __restrict__ h1l,
    unsigned short* __restrict__ h2h, unsigned short* __restrict__ h2l,
    const unsigned short* __restrict__ whdbT, const float* __restrict__ W_att,
    const unsigned short* __restrict__ fp, const float* __restrict__ c_feats,
    const unsigned short* __restrict__ l1bt, const unsigned short* __restrict__ l2bt,
    const unsigned short* __restrict__ lbt, const unsigned short* __restrict__ iht2b,
    const float* __restrict__ b2_ih,
    unsigned short* __restrict__ h2all_h, unsigned short* __restrict__ h2all_l,
    float* __restrict__ mask_ws, int t) {
  __shared__ float h1p[512];
  __shared__ float hqs[512];
  __shared__ float scs[256];
  __shared__ float red[8];
  __shared__ float red2[8];
  __shared__ float part[4 * 128];
  __shared__ float attl[128];
  __shared__ float lt1[128];
  __shared__ float llv[128];
  const int b = blockIdx.x;
  const int tid = threadIdx.x;
  const int lane = tid & 63, wv = tid >> 6;   // 8 waves

  // ---- GRU1 combine -> h1' ----
  {
    int c = tid;
    float gr = gx1[(size_t)b * kG + c];
    float gz = gx1[(size_t)b * kG + 512 + c];
    float gn = gx1[(size_t)b * kG + 1024 + c];
    float hr = gh1[(size_t)b * kG + c];
    float hz = gh1[(size_t)b * kG + 512 + c];
    float hnv = gh1[(size_t)b * kG + 1024 + c];
    float rr = fsigm(gr + hr);
    float zz = fsigm(gz + hz);
    float nn = ftanh(gn + rr * hnv);
    float ho = h1[(size_t)b * kH + c];
    float hn = (1.f - zz) * nn + zz * ho;
    h1[(size_t)b * kH + c] = hn;
    h1p[c] = hn;
    unsigned short hb = f2bf(hn);
    h1h[(size_t)b * kH + c] = hb;
    h1l[(size_t)b * kH + c] = f2bf(hn - bf2f(hb));
  }
  __syncthreads();

  // ---- hq = h1' @ W_hidd^T (bf16 weights, fp32 activations) ----
  {
    int c = tid;
    const unsigned short* w = whdbT + c;
    float a0 = 0.f, a1 = 0.f, a2 = 0.f, a3 = 0.f;
    #pragma unroll 4
    for (int k = 0; k < kH; k += 4) {
      a0 = fmaf(bf2f(w[(size_t)(k + 0) * kH]), h1p[k + 0], a0);
      a1 = fmaf(bf2f(w[(size_t)(k + 1) * kH]), h1p[k + 1], a1);
      a2 = fmaf(bf2f(w[(size_t)(k + 2) * kH]), h1p[k + 2], a2);
      a3 = fmaf(bf2f(w[(size_t)(k + 3) * kH]), h1p[k + 3], a3);
    }
    hqs[c] = (a0 + a1) + (a2 + a3);
  }
  __syncthreads();

  // ---- attention scores: 8 waves x 32 proposals ----
  {
    float hq8[8], aw[8];
    #pragma unroll
    for (int j = 0; j < 8; ++j) hq8[j] = hqs[lane * 8 + j];
    {
      float4 a0 = *(const float4*)(W_att + lane * 8);
      float4 a1 = *(const float4*)(W_att + lane * 8 + 4);
      aw[0] = a0.x; aw[1] = a0.y; aw[2] = a0.z; aw[3] = a0.w;
      aw[4] = a1.x; aw[5] = a1.y; aw[6] = a1.z; aw[7] = a1.w;
    }
    const unsigned short* fpb = fp + (size_t)b * kP * kH;
    for (int p = wv * 32; p < wv * 32 + 32; ++p) {
      uint4 rv = *(const uint4*)(fpb + (size_t)p * kH + lane * 8);
      union { uint4 v; unsigned short s[8]; } u; u.v = rv;
      float sc = 0.f;
      #pragma unroll
      for (int j = 0; j < 8; ++j) {
        float f = __uint_as_float((unsigned)u.s[j] << 16);
        sc += aw[j] * ftanh(f + hq8[j]);
      }
      #pragma unroll
      for (int m = 32; m; m >>= 1) sc += __shfl_xor(sc, m, 64);
      if (lane == 0) scs[p] = sc;
    }
  }
  __syncthreads();

  // ---- softmax over 256 proposals ----
  {
    float sv = (tid < 256) ? scs[tid] : -1e30f;
    float mx = sv;
    #pragma unroll
    for (int m = 32; m; m >>= 1) mx = fmaxf(mx, __shfl_xor(mx, m, 64));
    if (lane == 0) red[wv] = mx;
    __syncthreads();
    float bm = red[0];
    #pragma unroll
    for (int i = 1; i < 8; ++i) bm = fmaxf(bm, red[i]);
    float ev = (tid < 256) ? fexp2((sv - bm) * 1.4426950408889634f) : 0.f;
    float sm = ev;
    #pragma unroll
    for (int m = 32; m; m >>= 1) sm += __shfl_xor(sm, m, 64);
    if (lane == 0) red2[wv] = sm;
    __syncthreads();
    float tot = red2[0] + red2[1] + red2[2] + red2[3] +
                red2[4] + red2[5] + red2[6] + red2[7];
    float inv = frcp(tot);
    if (tid < 256) {
      float mk = ev * inv;
      scs[tid] = mk;
      // coalesced mask staging: [t][b][p]
      mask_ws[(size_t)t * (kB * kP) + (size_t)b * kP + tid] = mk;
    }
  }
  __syncthreads();

  // ---- attended = mask @ c_feats (4-way proposal split) ----
  {
    int c = tid & 127, q = tid >> 7;   // q 0..3, 64 proposals each
    const float* cf = c_feats + ((size_t)b * kP + q * 64) * kC + c;
    const float* ms = scs + q * 64;
    float acc = 0.f;
    for (int p = 0; p < 64; ++p) acc = fmaf(ms[p], cf[(size_t)p * kC], acc);
    part[q * 128 + c] = acc;
  }
  __syncthreads();
  if (tid < 128)
    attl[tid] = (part[tid] + part[128 + tid]) + (part[256 + tid] + part[384 + tid]);
  __syncthreads();

  // ---- l1: lt1 = tanh(att@W_l1^T + h1'@W_l2^T), 4-way k-split ----
  {
    int c = tid & 127, q = tid >> 7;
    float s = 0.f;
    const unsigned short* w2 = l2bt + (size_t)(q * 128) * kC + c;
    const float* hk = h1p + q * 128;
    for (int k = 0; k < 128; ++k)
      s = fmaf(hk[k], bf2f(w2[(size_t)k * kC]), s);
    const unsigned short* w1 = l1bt + (size_t)(q * 32) * kC + c;
    const float* ak = attl + q * 32;
    for (int k = 0; k < 32; ++k)
      s = fmaf(ak[k], bf2f(w1[(size_t)k * kC]), s);
    part[q * 128 + c] = s;
  }
  __syncthreads();
  if (tid < 128)
    lt1[tid] = ftanh((part[tid] + part[128 + tid]) +
                     (part[256 + tid] + part[384 + tid]));
  __syncthreads();

  // ---- l = relu(lt1 @ W_l^T), 4-way k-split ----
  {
    int c = tid & 127, q = tid >> 7;
    float s = 0.f;
    const unsigned short* w = lbt + (size_t)(q * 32) * kC + c;
    const float* lk = lt1 + q * 32;
    for (int k = 0; k < 32; ++k)
      s = fmaf(lk[k], bf2f(w[(size_t)k * kC]), s);
    part[q * 128 + c] = s;
  }
  __syncthreads();
  if (tid < 128)
    llv[tid] = fmaxf((part[tid] + part[128 + tid]) +
                     (part[256 + tid] + part[384 + tid]), 0.f);
  __syncthreads();

  // ---- gx2 GEMV + GRU2 combine -> h2' ----
  {
    int c = tid;
    float a0 = b2_ih[c], a1 = b2_ih[512 + c], a2 = b2_ih[1024 + c];
    const unsigned short* w = iht2b;
    #pragma unroll 4
    for (int k = 0; k < kC; ++k) {
      float l = llv[k];
      a0 = fmaf(l, bf2f(w[(size_t)k * kG + c]), a0);
      a1 = fmaf(l, bf2f(w[(size_t)k * kG + 512 + c]), a1);
      a2 = fmaf(l, bf2f(w[(size_t)k * kG + 1024 + c]), a2);
    }
    float ghr = gh2[(size_t)b * kG + c];
    float ghz = gh2[(size_t)b * kG + 512 + c];
    float ghn = gh2[(size_t)b * kG + 1024 + c];
    float rr = fsigm(a0 + ghr);
    float zz = fsigm(a1 + ghz);
    float nn = ftanh(a2 + rr * ghn);
    float ho = h2[(size_t)b * kH + c];
    float hn = (1.f - zz) * nn + zz * ho;
    h2[(size_t)b * kH + c] = hn;
    unsigned short hb = f2bf(hn);
    unsigned short lb = f2bf(hn - bf2f(hb));
    h2h[(size_t)b * kH + c] = hb;
    h2l[(size_t)b * kH + c] = lb;
    size_t o = ((size_t)t * kB + b) * kH + c;
    h2all_h[o] = hb;
    h2all_l[o] = lb;
  }
}

// ---------------- mask transpose: [t][b][p] -> out[b][p][t] ------------------
__global__ __launch_bounds__(256) void k_atrans(
    const float* __restrict__ mws, float* __restrict__ attn_out) {
  int pair = blockIdx.x * 256 + threadIdx.x;   // 65536 (b,p) pairs
  #pragma unroll
  for (int t = 0; t < kNS; ++t)
    attn_out[(size_t)pair * kNS + t] = mws[(size_t)t * (kB * kP) + pair];
}

// ---------------- classifier: lang = h2_all @ W_cls^T + b_cls (MFMA) ---------
__global__ __launch_bounds__(256) void k_cls(
    const unsigned short* __restrict__ Ah, const unsigned short* __restrict__ Al,
    const unsigned short* __restrict__ Wh, const unsigned short* __restrict__ Wl,
    const float* __restrict__ bc, float* __restrict__ out) {
  int m0 = blockIdx.x * 128, n0 = blockIdx.y * 128;
  f32x4 acc[4][4];
  #pragma unroll
  for (int i = 0; i < 4; ++i)
    #pragma unroll
    for (int j = 0; j < 4; ++j) acc[i][j] = (f32x4){0.f, 0.f, 0.f, 0.f};
  mm_split_tile(Ah, Al, Wh, Wl, m0, n0, kH, kV - 1, acc);
  int lane = threadIdx.x & 63, wid = threadIdx.x >> 6;
  int wm = (wid >> 1) * 64, wn = (wid & 1) * 64;
  int r16 = lane & 15, kq = lane >> 4;
  #pragma unroll
  for (int i = 0; i < 4; ++i)
    #pragma unroll
    for (int j = 0; j < 4; ++j)
      #pragma unroll
      for (int r = 0; r < 4; ++r) {
        int m = m0 + wm + i * 16 + kq * 4 + r;
        int n = n0 + wn + j * 16 + r16;
        if (n < kV) {
          int tt = m >> 8, b = m & 255;
          out[(size_t)b * (kNS * kV) + (size_t)tt * kV + n] = acc[i][j][r] + bc[n];
        }
      }
}

}  // namespace

extern "C" void kernel_launch(void* const* d_in, const int* in_sizes, int n_in,
                              void* d_out, int out_size, void* d_ws,
                              size_t ws_size, hipStream_t stream) {
  (void)in_sizes; (void)n_in; (void)out_size; (void)ws_size;
  const float* word_embs = (const float*)d_in[0];
  const float* t_feat    = (const float*)d_in[1];
  const float* c_feats   = (const float*)d_in[2];
  const float* W_td1 = (const float*)d_in[4];
  const float* W_td2 = (const float*)d_in[5];
  const float* W_td3 = (const float*)d_in[6];
  const float* W_td  = (const float*)d_in[7];
  const float* W1_ih = (const float*)d_in[8];
  const float* W1_hh = (const float*)d_in[9];
  const float* b1_ih = (const float*)d_in[10];
  const float* b1_hh = (const float*)d_in[11];
  const float* W_feat = (const float*)d_in[12];
  const float* W_hidd = (const float*)d_in[13];
  const float* W_att  = (const float*)d_in[14];
  const float* W_l1 = (const float*)d_in[15];
  const float* W_l2 = (const float*)d_in[16];
  const float* W_l  = (const float*)d_in[17];
  const float* W2_ih = (const float*)d_in[18];
  const float* W2_hh = (const float*)d_in[19];
  const float* b2_ih = (const float*)d_in[20];
  const float* b2_hh = (const float*)d_in[21];
  const float* W_cls = (const float*)d_in[22];
  const float* b_cls = (const float*)d_in[23];

  float* lang = (float*)d_out;
  float* attn_out = lang + (size_t)kB * kNS * kV;
  // feat_proj (bf16, 64MB) lives in the lang_cap region of d_out — dead by
  // the time k_cls (the only writer of lang_cap) runs.
  unsigned short* fp = (unsigned short*)d_out;

  float* p = (float*)d_ws;
  float* h1 = p;      p += kB * kH;
  float* h2 = p;      p += kB * kH;
  float* td = p;      p += kB * kC;
  float* gx1 = p;     p += (size_t)kB * kG;
  float* gh1 = p;     p += (size_t)kB * kG;
  float* gh2 = p;     p += (size_t)kB * kG;
  float* mask_ws = p; p += (size_t)kNS * kB * kP;
  float* td3t = p;    p += kE * 128;
  float* td1t = p;    p += kH * 128;
  float* tdt  = p;    p += 128 * 128;
  float* l1t  = p;    p += 128 * 128;
  float* l2t  = p;    p += kH * 128;
  float* lt   = p;    p += 128 * 128;
  float* iht1 = p;    p += 128 * kG;
  float* iht2 = p;    p += 128 * kG;
  float* whd_t = p;   p += kH * kH;

  unsigned short* u = (unsigned short*)p;
  unsigned short* h1h = u;     u += kB * kH;
  unsigned short* h1l = u;     u += kB * kH;
  unsigned short* h2h = u;     u += kB * kH;
  unsigned short* h2l = u;     u += kB * kH;
  unsigned short* w1hh_h = u;  u += (size_t)kG * kH;
  unsigned short* w1hh_l = u;  u += (size_t)kG * kH;
  unsigned short* w2hh_h = u;  u += (size_t)kG * kH;
  unsigned short* w2hh_l = u;  u += (size_t)kG * kH;
  unsigned short* wc_h = u;    u += (size_t)kV * kH;
  unsigned short* wc_l = u;    u += (size_t)kV * kH;
  unsigned short* wf_h = u;    u += (size_t)kH * kC;
  unsigned short* wf_l = u;    u += (size_t)kH * kC;
  unsigned short* h2all_h = u; u += (size_t)kNS * kB * kH;
  unsigned short* h2all_l = u; u += (size_t)kNS * kB * kH;
  unsigned short* l1bt = u;    u += kC * kC;
  unsigned short* l2bt = u;    u += (size_t)kH * kC;
  unsigned short* lbt = u;     u += kC * kC;
  unsigned short* iht2b = u;   u += (size_t)kC * kG;
  unsigned short* whdbT = u;   u += (size_t)kH * kH;

  k_transpose<<<dim3(64, 9), 256, 0, stream>>>(
      W_td3, W_td1, W_td, W_l1, W_l2, W_l, W1_ih, W2_ih, W_hidd,
      td3t, td1t, tdt, l1t, l2t, lt, iht1, iht2, whd_t);
  k_tobf16<<<dim3(64, 5), 256, 0, stream>>>(
      l1t, l2t, lt, iht2, whd_t, l1bt, l2bt, lbt, iht2b, whdbT);
  k_split<<<dim3(256, 4), 256, 0, stream>>>(
      W1_hh, W2_hh, W_cls, W_feat,
      w1hh_h, w1hh_l, w2hh_h, w2hh_l, wc_h, wc_l, wf_h, wf_l);
  k_init<<<128, 256, 0, stream>>>(t_feat, W_td2, td, h1, h2,
                                  h1h, h1l, h2h, h2l);
  k_featproj<<<dim3(512, 4), 256, 0, stream>>>(c_feats, wf_h, wf_l, fp);

  for (int t = 0; t < kNS; ++t) {
    k_step1<<<112, 256, 0, stream>>>(word_embs, t, h2, td, td3t, td1t, tdt,
                                     iht1, b1_ih, h1h, h1l, h2h, h2l,
                                     w1hh_h, w1hh_l, w2hh_h, w2hh_l,
                                     b1_hh, b2_hh, gx1, gh1, gh2);
    k_step2<<<256, 512, 0, stream>>>(gx1, gh1, gh2, h1, h2,
                                     h1h, h1l, h2h, h2l, whdbT, W_att, fp,
                                     c_feats, l1bt, l2bt, lbt, iht2b, b2_ih,
                                     h2all_h, h2all_l, mask_ws, t);
  }
  k_atrans<<<256, 256, 0, stream>>>(mask_ws, attn_out);
  k_cls<<<dim3(62, 27), 256, 0, stream>>>(h2all_h, h2all_l, wc_h, wc_l,
                                          b_cls, lang);
}

// Round 6
// 3907.501 us; speedup vs baseline: 10.4314x; 1.3442x over previous
//
#include <hip/hip_runtime.h>
#include <hip/hip_bf16.h>

namespace {

constexpr int kB  = 256;   // batch
constexpr int kP  = 256;   // proposals
constexpr int kT  = 32;    // words
constexpr int kNS = 31;    // steps = T-1
constexpr int kV  = 3433;  // vocab
constexpr int kH  = 512;   // hidden
constexpr int kE  = 300;   // embed
constexpr int kC  = 128;   // feat dim
constexpr int kG  = 1536;  // 3H

typedef __bf16 bf16x8 __attribute__((ext_vector_type(8)));
typedef float f32x4 __attribute__((ext_vector_type(4)));

__device__ __forceinline__ float fexp2(float x) {
  float r; asm("v_exp_f32 %0, %1" : "=v"(r) : "v"(x)); return r;
}
__device__ __forceinline__ float frcp(float x) {
  float r; asm("v_rcp_f32 %0, %1" : "=v"(r) : "v"(x)); return r;
}
__device__ __forceinline__ float ftanh(float x) {
  float e = fexp2(x * 2.8853900817779268f);   // e^(2x)
  return 1.0f - 2.0f * frcp(e + 1.0f);
}
__device__ __forceinline__ float fsigm(float x) {
  return frcp(1.0f + fexp2(x * -1.4426950408889634f));
}
__device__ __forceinline__ unsigned short f2bf(float f) {   // RNE bf16
  unsigned u = __float_as_uint(f);
  u += 0x7FFFu + ((u >> 16) & 1u);
  return (unsigned short)(u >> 16);
}
__device__ __forceinline__ float bf2f(unsigned short s) {
  return __uint_as_float((unsigned)s << 16);
}
__device__ __forceinline__ bf16x8 bload(const unsigned short* p) {
  union { uint4 u; bf16x8 v; } x;
  x.u = *(const uint4*)p;
  return x.v;
}

// ---------------- one-time weight transposes (W[r][k] -> Wt[k*R + r]) -------
__global__ void k_transpose(const float* s0, const float* s1, const float* s2,
                            const float* s3, const float* s4, const float* s5,
                            const float* s6, const float* s7, const float* s8,
                            float* d0, float* d1, float* d2, float* d3,
                            float* d4, float* d5, float* d6, float* d7,
                            float* d8) {
  const float* src; float* dst; int R, Cd;
  switch (blockIdx.y) {
    case 0:  src = s0; dst = d0; R = 128;  Cd = 300; break;  // W_td3
    case 1:  src = s1; dst = d1; R = 128;  Cd = 512; break;  // W_td1
    case 2:  src = s2; dst = d2; R = 128;  Cd = 128; break;  // W_td
    case 3:  src = s3; dst = d3; R = 128;  Cd = 128; break;  // W_l1
    case 4:  src = s4; dst = d4; R = 128;  Cd = 512; break;  // W_l2
    case 5:  src = s5; dst = d5; R = 128;  Cd = 128; break;  // W_l
    case 6:  src = s6; dst = d6; R = 1536; Cd = 128; break;  // W1_ih
    case 7:  src = s7; dst = d7; R = 1536; Cd = 128; break;  // W2_ih
    default: src = s8; dst = d8; R = 512;  Cd = 512; break;  // W_hidd
  }
  int n = R * Cd;
  for (int i = blockIdx.x * blockDim.x + threadIdx.x; i < n;
       i += gridDim.x * blockDim.x) {
    int k = i / R, r = i - k * R;
    dst[i] = src[r * Cd + k];    // dst[k*R + r]
  }
}

// ---------------- bf16 copies of the loop-local transposed weights -----------
__global__ void k_tobf16(const float* s0, const float* s1, const float* s2,
                         const float* s3, const float* s4, const float* s5,
                         const float* s6, const float* s7,
                         unsigned short* d0, unsigned short* d1,
                         unsigned short* d2, unsigned short* d3,
                         unsigned short* d4, unsigned short* d5,
                         unsigned short* d6, unsigned short* d7) {
  const float* s; unsigned short* d; int n;
  switch (blockIdx.y) {
    case 0:  s = s0; d = d0; n = kC * kC; break;   // l1t
    case 1:  s = s1; d = d1; n = kH * kC; break;   // l2t
    case 2:  s = s2; d = d2; n = kC * kC; break;   // lt
    case 3:  s = s3; d = d3; n = kC * kG; break;   // iht2
    case 4:  s = s4; d = d4; n = kH * kH; break;   // whd_t
    case 5:  s = s5; d = d5; n = kH * kC; break;   // td1t
    case 6:  s = s6; d = d6; n = kC * kC; break;   // tdt
    default: s = s7; d = d7; n = kC * kG; break;   // iht1
  }
  for (int i = blockIdx.x * blockDim.x + threadIdx.x; i < n;
       i += gridDim.x * blockDim.x)
    d[i] = f2bf(s[i]);
}

// ---------------- one-time weight hi/lo bf16 splits --------------------------
__global__ void k_split(const float* s0, const float* s1, const float* s2,
                        const float* s3,
                        unsigned short* h0, unsigned short* l0,
                        unsigned short* h1, unsigned short* l1,
                        unsigned short* h2, unsigned short* l2,
                        unsigned short* h3, unsigned short* l3) {
  const float* s; unsigned short* h; unsigned short* l; int n;
  switch (blockIdx.y) {
    case 0:  s = s0; h = h0; l = l0; n = kG * kH; break;   // W1_hh
    case 1:  s = s1; h = h1; l = l1; n = kG * kH; break;   // W2_hh
    case 2:  s = s2; h = h2; l = l2; n = kV * kH; break;   // W_cls
    default: s = s3; h = h3; l = l3; n = kH * kC; break;   // W_feat
  }
  for (int i = blockIdx.x * blockDim.x + threadIdx.x; i < n;
       i += gridDim.x * blockDim.x) {
    float v = s[i];
    unsigned short hb = f2bf(v);
    h[i] = hb;
    l[i] = f2bf(v - bf2f(hb));
  }
}

// ---------------- init: td = t_feat @ W_td2^T ; zero h states ----------------
__global__ void k_init(const float* __restrict__ t_feat,
                       const float* __restrict__ W_td2,
                       float* __restrict__ td, float* __restrict__ h1,
                       float* __restrict__ h2,
                       unsigned short* __restrict__ h1h,
                       unsigned short* __restrict__ h1l,
                       unsigned short* __restrict__ h2h,
                       unsigned short* __restrict__ h2l) {
  int tid = blockIdx.x * 256 + threadIdx.x;  // 32768 threads
  int b = tid >> 7, c = tid & 127;
  const float* tf = t_feat + b * kC;
  const float* w  = W_td2 + c * kC;
  float acc = 0.f;
  for (int k = 0; k < kC; ++k) acc = fmaf(tf[k], w[k], acc);
  td[tid] = acc;
  for (int i = tid; i < kB * kH; i += (1 << 15)) {
    h1[i] = 0.f; h2[i] = 0.f;
    h1h[i] = 0; h1l[i] = 0; h2h[i] = 0; h2l[i] = 0;
  }
}

// ---------------- xw[t][b][:] = x_t @ W_td3^T + td  (all t, fp32 exact) ------
__global__ __launch_bounds__(256) void k_xw(
    const float* __restrict__ word_embs, const float* __restrict__ td3t,
    const float* __restrict__ td, float* __restrict__ xw) {
  __shared__ float xl[4 * 300];
  __shared__ float tdl[512];
  int t = blockIdx.y, b0 = blockIdx.x * 4, tid = threadIdx.x;
  #pragma unroll
  for (int r = 0; r < 4; ++r) {
    const float* xs = word_embs + (size_t)(b0 + r) * (kT * kE) + (size_t)t * kE;
    for (int e = tid; e < kE; e += 256) xl[r * kE + e] = xs[e];
  }
  for (int i = tid; i < 512; i += 256) tdl[i] = td[(size_t)b0 * kC + i];
  __syncthreads();
  #pragma unroll
  for (int q = 0; q < 2; ++q) {
    int idx = tid + q * 256;
    int r = idx >> 7, c = idx & 127;
    float acc = tdl[idx];
    const float* xr = xl + r * kE;
    const float* w3 = td3t + c;
    for (int e = 0; e < kE; ++e) acc = fmaf(xr[e], w3[(size_t)e * 128], acc);
    xw[((size_t)t * kB + b0 + r) * kC + idx % 128 + (r * 0)] = acc;
  }
}

// ---------------- prestep: s(0), gx1(0) from xw[0] (h2 = 0) ------------------
__global__ __launch_bounds__(256) void k_prestep(
    const float* __restrict__ xw, const unsigned short* __restrict__ tdbt,
    const unsigned short* __restrict__ iht1b, const float* __restrict__ b1_ih,
    float* __restrict__ gx1) {
  __shared__ float s1l[128];
  __shared__ float s2l[128];
  __shared__ float part[256];
  int b = blockIdx.x, tid = threadIdx.x;
  if (tid < 128) s1l[tid] = ftanh(xw[(size_t)b * kC + tid]);
  __syncthreads();
  {
    int c = tid & 127, g = tid >> 7;   // 2 k-groups of 64
    float s = 0.f;
    const unsigned short* w = tdbt + (size_t)(g * 64) * kC + c;
    for (int k = 0; k < 64; ++k)
      s = fmaf(s1l[g * 64 + k], bf2f(w[(size_t)k * kC]), s);
    part[g * 128 + c] = s;
  }
  __syncthreads();
  if (tid < 128) s2l[tid] = fmaxf(part[tid] + part[128 + tid], 0.f);
  __syncthreads();
  #pragma unroll
  for (int q = 0; q < 6; ++q) {
    int j = q * 256 + tid;
    float acc = b1_ih[j];
    const unsigned short* w = iht1b + j;
    for (int k = 0; k < kC; ++k)
      acc = fmaf(s2l[k], bf2f(w[(size_t)k * kG]), acc);
    gx1[(size_t)b * kG + j] = acc;
  }
}

// ---------------- split-bf16 MFMA 128x128 tile (3-term) ----------------------
__device__ __forceinline__ void mm_split_tile(
    const unsigned short* __restrict__ Ah, const unsigned short* __restrict__ Al,
    const unsigned short* __restrict__ Bh, const unsigned short* __restrict__ Bl,
    int m0, int n0, int K, int nMax, f32x4 acc[4][4]) {
  int lane = threadIdx.x & 63, wid = (threadIdx.x >> 6) & 3;
  int wm = (wid >> 1) * 64, wn = (wid & 1) * 64;
  int r16 = lane & 15, kq = lane >> 4;
  int arow[4], brow[4];
  #pragma unroll
  for (int i = 0; i < 4; ++i) {
    arow[i] = m0 + wm + i * 16 + r16;
    int br = n0 + wn + i * 16 + r16;
    brow[i] = br > nMax ? nMax : br;
  }
  for (int k0 = 0; k0 < K; k0 += 32) {
    int kk = k0 + kq * 8;
    bf16x8 ah[4], al[4], bh[4], bl[4];
    #pragma unroll
    for (int i = 0; i < 4; ++i) {
      ah[i] = bload(Ah + (size_t)arow[i] * K + kk);
      al[i] = bload(Al + (size_t)arow[i] * K + kk);
      bh[i] = bload(Bh + (size_t)brow[i] * K + kk);
      bl[i] = bload(Bl + (size_t)brow[i] * K + kk);
    }
    #pragma unroll
    for (int i = 0; i < 4; ++i)
      #pragma unroll
      for (int j = 0; j < 4; ++j) {
        acc[i][j] = __builtin_amdgcn_mfma_f32_16x16x32_bf16(ah[i], bh[j], acc[i][j], 0, 0, 0);
        acc[i][j] = __builtin_amdgcn_mfma_f32_16x16x32_bf16(ah[i], bl[j], acc[i][j], 0, 0, 0);
        acc[i][j] = __builtin_amdgcn_mfma_f32_16x16x32_bf16(al[i], bh[j], acc[i][j], 0, 0, 0);
      }
  }
}

// ---------------- feat_proj = c_feats @ W_feat^T -> bf16 (MFMA) --------------
__global__ __launch_bounds__(256) void k_featproj(
    const float* __restrict__ A, const unsigned short* __restrict__ Wh,
    const unsigned short* __restrict__ Wl, unsigned short* __restrict__ out) {
  int lane = threadIdx.x & 63, wid = threadIdx.x >> 6;
  int wm = (wid >> 1) * 64, wn = (wid & 1) * 64;
  int r16 = lane & 15, kq = lane >> 4;
  int m0 = blockIdx.x * 128, n0 = blockIdx.y * 128;
  f32x4 acc[4][4];
  #pragma unroll
  for (int i = 0; i < 4; ++i)
    #pragma unroll
    for (int j = 0; j < 4; ++j) acc[i][j] = (f32x4){0.f, 0.f, 0.f, 0.f};
  for (int k0 = 0; k0 < kC; k0 += 32) {
    int kk = k0 + kq * 8;
    bf16x8 ah[4], al[4], bh[4], bl[4];
    #pragma unroll
    for (int i = 0; i < 4; ++i) {
      const float* pa = A + (size_t)(m0 + wm + i * 16 + r16) * kC + kk;
      float4 v0 = *(const float4*)pa;
      float4 v1 = *(const float4*)(pa + 4);
      float vv[8] = {v0.x, v0.y, v0.z, v0.w, v1.x, v1.y, v1.z, v1.w};
      union { unsigned short s[8]; bf16x8 v; } uh, ul;
      #pragma unroll
      for (int q = 0; q < 8; ++q) {
        unsigned short hb = f2bf(vv[q]);
        uh.s[q] = hb;
        ul.s[q] = f2bf(vv[q] - bf2f(hb));
      }
      ah[i] = uh.v; al[i] = ul.v;
      const unsigned short* pb = Wh + (size_t)(n0 + wn + i * 16 + r16) * kC + kk;
      const unsigned short* pl = Wl + (size_t)(n0 + wn + i * 16 + r16) * kC + kk;
      bh[i] = bload(pb); bl[i] = bload(pl);
    }
    #pragma unroll
    for (int i = 0; i < 4; ++i)
      #pragma unroll
      for (int j = 0; j < 4; ++j) {
        acc[i][j] = __builtin_amdgcn_mfma_f32_16x16x32_bf16(ah[i], bh[j], acc[i][j], 0, 0, 0);
        acc[i][j] = __builtin_amdgcn_mfma_f32_16x16x32_bf16(ah[i], bl[j], acc[i][j], 0, 0, 0);
        acc[i][j] = __builtin_amdgcn_mfma_f32_16x16x32_bf16(al[i], bh[j], acc[i][j], 0, 0, 0);
      }
  }
  #pragma unroll
  for (int i = 0; i < 4; ++i)
    #pragma unroll
    for (int j = 0; j < 4; ++j)
      #pragma unroll
      for (int r = 0; r < 4; ++r) {
        int m = m0 + wm + i * 16 + kq * 4 + r;
        int n = n0 + wn + j * 16 + r16;
        out[(size_t)m * kH + n] = f2bf(acc[i][j][r]);
      }
}

// ---------------- per-step kernel 1: gh1/gh2 MFMA only (48 blocks) -----------
__global__ __launch_bounds__(256) void k_gh(
    const unsigned short* __restrict__ h1h, const unsigned short* __restrict__ h1l,
    const unsigned short* __restrict__ h2h, const unsigned short* __restrict__ h2l,
    const unsigned short* __restrict__ w1hh_h, const unsigned short* __restrict__ w1hh_l,
    const unsigned short* __restrict__ w2hh_h, const unsigned short* __restrict__ w2hh_l,
    const float* __restrict__ b1_hh, const float* __restrict__ b2_hh,
    float* __restrict__ gh1, float* __restrict__ gh2) {
  int g = blockIdx.x;   // 0..47
  const unsigned short *Ah, *Al, *Wh, *Wl; const float* bias; float* out;
  if (g < 24) { Ah = h1h; Al = h1l; Wh = w1hh_h; Wl = w1hh_l;
                bias = b1_hh; out = gh1; }
  else { g -= 24; Ah = h2h; Al = h2l; Wh = w2hh_h; Wl = w2hh_l;
         bias = b2_hh; out = gh2; }
  int m0 = (g / 12) * 128, n0 = (g % 12) * 128;
  f32x4 acc[4][4];
  #pragma unroll
  for (int i = 0; i < 4; ++i)
    #pragma unroll
    for (int j = 0; j < 4; ++j) acc[i][j] = (f32x4){0.f, 0.f, 0.f, 0.f};
  mm_split_tile(Ah, Al, Wh, Wl, m0, n0, kH, kG - 1, acc);
  int tid = threadIdx.x;
  int lane = tid & 63, wid = tid >> 6;
  int wm = (wid >> 1) * 64, wn = (wid & 1) * 64;
  int r16 = lane & 15, kq = lane >> 4;
  #pragma unroll
  for (int i = 0; i < 4; ++i)
    #pragma unroll
    for (int j = 0; j < 4; ++j)
      #pragma unroll
      for (int r = 0; r < 4; ++r) {
        int m = m0 + wm + i * 16 + kq * 4 + r;
        int n = n0 + wn + j * 16 + r16;
        out[(size_t)m * kG + n] = acc[i][j][r] + bias[n];
      }
}

// ---------------- per-step kernel 2: one batch row per block, 1024 threads ---
// GRU1 -> hq -> attn -> lang -> GRU2 -> [s(t+1), gx1(t+1)]
__global__ __launch_bounds__(1024, 4) void k_step2(
    float* __restrict__ gx1, const float* __restrict__ gh1,
    const float* __restrict__ gh2,
    float* __restrict__ h1, float* __restrict__ h2,
    unsigned short* __restrict__ h1h, unsigned short* __restrict__ h1l,
    unsigned short* __restrict__ h2h, unsigned short* __restrict__ h2l,
    const unsigned short* __restrict__ whdbT, const float* __restrict__ W_att,
    const unsigned short* __restrict__ fp, const float* __restrict__ c_feats,
    const unsigned short* __restrict__ l1bt, const unsigned short* __restrict__ l2bt,
    const unsigned short* __restrict__ lbt, const unsigned short* __restrict__ iht2b,
    const float* __restrict__ b2_ih,
    const unsigned short* __restrict__ td1bt, const unsigned short* __restrict__ tdbt,
    const unsigned short* __restrict__ iht1b, const float* __restrict__ b1_ih,
    const float* __restrict__ xw,
    unsigned short* __restrict__ h2all_h, unsigned short* __restrict__ h2all_l,
    float* __restrict__ mask_ws, int t) {
  __shared__ float h1p[512];
  __shared__ float h2p[512];
  __shared__ float hqs[512];
  __shared__ float scs[256];
  __shared__ float red[16];
  __shared__ float red2[16];
  __shared__ float part[1024];
  __shared__ float attl[128];
  __shared__ float lt1[128];
  __shared__ float llv[128];
  __shared__ float s1l[128];
  __shared__ float s2l[128];
  __shared__ float gx2l[1536];
  const int b = blockIdx.x;
  const int tid = threadIdx.x;
  const int lane = tid & 63, wv = tid >> 6;   // 16 waves

  // ---- A: GRU1 combine -> h1' ----
  if (tid < 512) {
    int c = tid;
    float gr = gx1[(size_t)b * kG + c];
    float gz = gx1[(size_t)b * kG + 512 + c];
    float gn = gx1[(size_t)b * kG + 1024 + c];
    float hr = gh1[(size_t)b * kG + c];
    float hz = gh1[(size_t)b * kG + 512 + c];
    float hnv = gh1[(size_t)b * kG + 1024 + c];
    float rr = fsigm(gr + hr);
    float zz = fsigm(gz + hz);
    float nn = ftanh(gn + rr * hnv);
    float ho = h1[(size_t)b * kH + c];
    float hn = (1.f - zz) * nn + zz * ho;
    h1[(size_t)b * kH + c] = hn;
    h1p[c] = hn;
    unsigned short hb = f2bf(hn);
    h1h[(size_t)b * kH + c] = hb;
    h1l[(size_t)b * kH + c] = f2bf(hn - bf2f(hb));
  }
  __syncthreads();

  // ---- B: hq = h1' @ W_hidd^T (bf16 weights), 2-way k-split ----
  {
    int c = tid & 511, kh = tid >> 9;
    const unsigned short* w = whdbT + (size_t)(kh * 256) * kH + c;
    const float* hk = h1p + kh * 256;
    float a0 = 0.f, a1 = 0.f, a2 = 0.f, a3 = 0.f;
    #pragma unroll 8
    for (int k = 0; k < 256; k += 4) {
      a0 = fmaf(bf2f(w[(size_t)(k + 0) * kH]), hk[k + 0], a0);
      a1 = fmaf(bf2f(w[(size_t)(k + 1) * kH]), hk[k + 1], a1);
      a2 = fmaf(bf2f(w[(size_t)(k + 2) * kH]), hk[k + 2], a2);
      a3 = fmaf(bf2f(w[(size_t)(k + 3) * kH]), hk[k + 3], a3);
    }
    part[tid] = (a0 + a1) + (a2 + a3);
  }
  __syncthreads();
  if (tid < 512) hqs[tid] = part[tid] + part[tid + 512];
  __syncthreads();

  // ---- C: attention scores, 16 waves x 16 proposals ----
  {
    float hq8[8], aw[8];
    #pragma unroll
    for (int j = 0; j < 8; ++j) hq8[j] = hqs[lane * 8 + j];
    {
      float4 a0 = *(const float4*)(W_att + lane * 8);
      float4 a1 = *(const float4*)(W_att + lane * 8 + 4);
      aw[0] = a0.x; aw[1] = a0.y; aw[2] = a0.z; aw[3] = a0.w;
      aw[4] = a1.x; aw[5] = a1.y; aw[6] = a1.z; aw[7] = a1.w;
    }
    const unsigned short* fpb = fp + (size_t)b * kP * kH;
    int p0 = wv * 16;
    uint4 rv = *(const uint4*)(fpb + (size_t)p0 * kH + lane * 8);
    for (int p = p0; p < p0 + 16; ++p) {
      union { uint4 v; unsigned short s[8]; } u; u.v = rv;
      if (p + 1 < p0 + 16)
        rv = *(const uint4*)(fpb + (size_t)(p + 1) * kH + lane * 8);
      float sc = 0.f;
      #pragma unroll
      for (int j = 0; j < 8; ++j) {
        float f = __uint_as_float((unsigned)u.s[j] << 16);
        sc += aw[j] * ftanh(f + hq8[j]);
      }
      #pragma unroll
      for (int m = 32; m; m >>= 1) sc += __shfl_xor(sc, m, 64);
      if (lane == 0) scs[p] = sc;
    }
  }
  __syncthreads();

  // ---- D: softmax over 256 proposals ----
  {
    float sv = (tid < 256) ? scs[tid] : -1e30f;
    float mx = sv;
    #pragma unroll
    for (int m = 32; m; m >>= 1) mx = fmaxf(mx, __shfl_xor(mx, m, 64));
    if (lane == 0) red[wv] = mx;
    __syncthreads();
    float bm = red[0];
    #pragma unroll
    for (int i = 1; i < 16; ++i) bm = fmaxf(bm, red[i]);
    float ev = (tid < 256) ? fexp2((sv - bm) * 1.4426950408889634f) : 0.f;
    float sm = ev;
    #pragma unroll
    for (int m = 32; m; m >>= 1) sm += __shfl_xor(sm, m, 64);
    if (lane == 0) red2[wv] = sm;
    __syncthreads();
    float tot = 0.f;
    #pragma unroll
    for (int i = 0; i < 16; ++i) tot += red2[i];
    if (tid < 256) {
      float mk = ev * frcp(tot);
      scs[tid] = mk;
      mask_ws[(size_t)t * (kB * kP) + (size_t)b * kP + tid] = mk;
    }
  }
  __syncthreads();

  // ---- E: attended = mask @ c_feats, 8 proposal-groups x 32 ----
  {
    int c = tid & 127, q = tid >> 7;
    const float* cf = c_feats + ((size_t)b * kP + q * 32) * kC + c;
    const float* ms = scs + q * 32;
    float acc = 0.f;
    for (int p = 0; p < 32; ++p) acc = fmaf(ms[p], cf[(size_t)p * kC], acc);
    part[q * 128 + c] = acc;
  }
  __syncthreads();
  if (tid < 128) {
    float s = 0.f;
    #pragma unroll
    for (int q = 0; q < 8; ++q) s += part[q * 128 + tid];
    attl[tid] = s;
  }
  __syncthreads();

  // ---- F: lt1 = tanh(att@W_l1^T + h1'@W_l2^T), 8 k-groups ----
  {
    int c = tid & 127, g = tid >> 7;
    float s = 0.f;
    const unsigned short* w2 = l2bt + (size_t)(g * 64) * kC + c;
    const float* hk = h1p + g * 64;
    for (int k = 0; k < 64; ++k)
      s = fmaf(hk[k], bf2f(w2[(size_t)k * kC]), s);
    if (g < 2) {
      const unsigned short* w1 = l1bt + (size_t)(g * 64) * kC + c;
      const float* ak = attl + g * 64;
      for (int k = 0; k < 64; ++k)
        s = fmaf(ak[k], bf2f(w1[(size_t)k * kC]), s);
    }
    part[g * 128 + c] = s;
  }
  __syncthreads();
  if (tid < 128) {
    float s = 0.f;
    #pragma unroll
    for (int q = 0; q < 8; ++q) s += part[q * 128 + tid];
    lt1[tid] = ftanh(s);
  }
  __syncthreads();

  // ---- G: l = relu(lt1 @ W_l^T), 8 k-groups x 16 ----
  {
    int c = tid & 127, g = tid >> 7;
    float s = 0.f;
    const unsigned short* w = lbt + (size_t)(g * 16) * kC + c;
    const float* lk = lt1 + g * 16;
    for (int k = 0; k < 16; ++k)
      s = fmaf(lk[k], bf2f(w[(size_t)k * kC]), s);
    part[g * 128 + c] = s;
  }
  __syncthreads();
  if (tid < 128) {
    float s = 0.f;
    #pragma unroll
    for (int q = 0; q < 8; ++q) s += part[q * 128 + tid];
    llv[tid] = fmaxf(s, 0.f);
  }
  __syncthreads();

  // ---- H: gx2 = l @ W2_ih^T + b2 ; GRU2 combine -> h2' ----
  {
    int j = tid;
    float acc = b2_ih[j];
    const unsigned short* w = iht2b + j;
    #pragma unroll 4
    for (int k = 0; k < kC; ++k) acc = fmaf(llv[k], bf2f(w[(size_t)k * kG]), acc);
    gx2l[j] = acc;
    if (tid < 512) {
      int j2 = 1024 + tid;
      float acc2 = b2_ih[j2];
      const unsigned short* w2 = iht2b + j2;
      #pragma unroll 4
      for (int k = 0; k < kC; ++k)
        acc2 = fmaf(llv[k], bf2f(w2[(size_t)k * kG]), acc2);
      gx2l[j2] = acc2;
    }
  }
  __syncthreads();
  if (tid < 512) {
    int c = tid;
    float ghr = gh2[(size_t)b * kG + c];
    float ghz = gh2[(size_t)b * kG + 512 + c];
    float ghn = gh2[(size_t)b * kG + 1024 + c];
    float rr = fsigm(gx2l[c] + ghr);
    float zz = fsigm(gx2l[512 + c] + ghz);
    float nn = ftanh(gx2l[1024 + c] + rr * ghn);
    float ho = h2[(size_t)b * kH + c];
    float hn = (1.f - zz) * nn + zz * ho;
    h2[(size_t)b * kH + c] = hn;
    h2p[c] = hn;
    unsigned short hb = f2bf(hn);
    unsigned short lb = f2bf(hn - bf2f(hb));
    h2h[(size_t)b * kH + c] = hb;
    h2l[(size_t)b * kH + c] = lb;
    size_t o = ((size_t)t * kB + b) * kH + c;
    h2all_h[o] = hb;
    h2all_l[o] = lb;
  }
  __syncthreads();

  // ---- I: next step's s-chain + gx1 (row-local, uses fresh h2') ----
  if (t + 1 < kNS) {
    // I1: v = xw[t+1] + h2' @ W_td1^T ; s1 = tanh(v)
    {
      int c = tid & 127, g = tid >> 7;
      float s = 0.f;
      const unsigned short* w = td1bt + (size_t)(g * 64) * kC + c;
      const float* hk = h2p + g * 64;
      for (int k = 0; k < 64; ++k)
        s = fmaf(hk[k], bf2f(w[(size_t)k * kC]), s);
      part[g * 128 + c] = s;
    }
    __syncthreads();
    if (tid < 128) {
      float s = xw[((size_t)(t + 1) * kB + b) * kC + tid];
      #pragma unroll
      for (int q = 0; q < 8; ++q) s += part[q * 128 + tid];
      s1l[tid] = ftanh(s);
    }
    __syncthreads();
    // I2: s2 = relu(s1 @ W_td^T)
    {
      int c = tid & 127, g = tid >> 7;
      float s = 0.f;
      const unsigned short* w = tdbt + (size_t)(g * 16) * kC + c;
      const float* sk = s1l + g * 16;
      for (int k = 0; k < 16; ++k)
        s = fmaf(sk[k], bf2f(w[(size_t)k * kC]), s);
      part[g * 128 + c] = s;
    }
    __syncthreads();
    if (tid < 128) {
      float s = 0.f;
      #pragma unroll
      for (int q = 0; q < 8; ++q) s += part[q * 128 + tid];
      s2l[tid] = fmaxf(s, 0.f);
    }
    __syncthreads();
    // I3: gx1(t+1) = s2 @ W1_ih^T + b1_ih
    {
      int j = tid;
      float acc = b1_ih[j];
      const unsigned short* w = iht1b + j;
      #pragma unroll 4
      for (int k = 0; k < kC; ++k)
        acc = fmaf(s2l[k], bf2f(w[(size_t)k * kG]), acc);
      gx1[(size_t)b * kG + j] = acc;
      if (tid < 512) {
        int j2 = 1024 + tid;
        float acc2 = b1_ih[j2];
        const unsigned short* w2 = iht1b + j2;
        #pragma unroll 4
        for (int k = 0; k < kC; ++k)
          acc2 = fmaf(s2l[k], bf2f(w2[(size_t)k * kG]), acc2);
        gx1[(size_t)b * kG + j2] = acc2;
      }
    }
  }
}

// ---------------- mask transpose: [t][b][p] -> out[b][p][t] ------------------
__global__ __launch_bounds__(256) void k_atrans(
    const float* __restrict__ mws, float* __restrict__ attn_out) {
  int pair = blockIdx.x * 256 + threadIdx.x;   // 65536 (b,p) pairs
  #pragma unroll
  for (int t = 0; t < kNS; ++t)
    attn_out[(size_t)pair * kNS + t] = mws[(size_t)t * (kB * kP) + pair];
}

// ---------------- classifier: lang = h2_all @ W_cls^T + b_cls (MFMA) ---------
__global__ __launch_bounds__(256) void k_cls(
    const unsigned short* __restrict__ Ah, const unsigned short* __restrict__ Al,
    const unsigned short* __restrict__ Wh, const unsigned short* __restrict__ Wl,
    const float* __restrict__ bc, float* __restrict__ out) {
  int m0 = blockIdx.x * 128, n0 = blockIdx.y * 128;
  f32x4 acc[4][4];
  #pragma unroll
  for (int i = 0; i < 4; ++i)
    #pragma unroll
    for (int j = 0; j < 4; ++j) acc[i][j] = (f32x4){0.f, 0.f, 0.f, 0.f};
  mm_split_tile(Ah, Al, Wh, Wl, m0, n0, kH, kV - 1, acc);
  int lane = threadIdx.x & 63, wid = threadIdx.x >> 6;
  int wm = (wid >> 1) * 64, wn = (wid & 1) * 64;
  int r16 = lane & 15, kq = lane >> 4;
  #pragma unroll
  for (int i = 0; i < 4; ++i)
    #pragma unroll
    for (int j = 0; j < 4; ++j)
      #pragma unroll
      for (int r = 0; r < 4; ++r) {
        int m = m0 + wm + i * 16 + kq * 4 + r;
        int n = n0 + wn + j * 16 + r16;
        if (n < kV) {
          int tt = m >> 8, b = m & 255;
          out[(size_t)b * (kNS * kV) + (size_t)tt * kV + n] = acc[i][j][r] + bc[n];
        }
      }
}

}  // namespace

extern "C" void kernel_launch(void* const* d_in, const int* in_sizes, int n_in,
                              void* d_out, int out_size, void* d_ws,
                              size_t ws_size, hipStream_t stream) {
  (void)in_sizes; (void)n_in; (void)out_size; (void)ws_size;
  const float* word_embs = (const float*)d_in[0];
  const float* t_feat    = (const float*)d_in[1];
  const float* c_feats   = (const float*)d_in[2];
  const float* W_td1 = (const float*)d_in[4];
  const float* W_td2 = (const float*)d_in[5];
  const float* W_td3 = (const float*)d_in[6];
  const float* W_td  = (const float*)d_in[7];
  const float* W1_ih = (const float*)d_in[8];
  const float* W1_hh = (const float*)d_in[9];
  const float* b1_ih = (const float*)d_in[10];
  const float* b1_hh = (const float*)d_in[11];
  const float* W_feat = (const float*)d_in[12];
  const float* W_hidd = (const float*)d_in[13];
  const float* W_att  = (const float*)d_in[14];
  const float* W_l1 = (const float*)d_in[15];
  const float* W_l2 = (const float*)d_in[16];
  const float* W_l  = (const float*)d_in[17];
  const float* W2_ih = (const float*)d_in[18];
  const float* W2_hh = (const float*)d_in[19];
  const float* b2_ih = (const float*)d_in[20];
  const float* b2_hh = (const float*)d_in[21];
  const float* W_cls = (const float*)d_in[22];
  const float* b_cls = (const float*)d_in[23];

  float* lang = (float*)d_out;
  float* attn_out = lang + (size_t)kB * kNS * kV;
  // feat_proj (bf16, 64MB) lives in the lang_cap region of d_out — dead by
  // the time k_cls (the only writer of lang_cap) runs.
  unsigned short* fp = (unsigned short*)d_out;

  float* p = (float*)d_ws;
  float* h1 = p;      p += kB * kH;
  float* h2 = p;      p += kB * kH;
  float* td = p;      p += kB * kC;
  float* gx1 = p;     p += (size_t)kB * kG;
  float* gh1 = p;     p += (size_t)kB * kG;
  float* gh2 = p;     p += (size_t)kB * kG;
  float* mask_ws = p; p += (size_t)kNS * kB * kP;
  float* xw = p;      p += (size_t)kNS * kB * kC;
  float* td3t = p;    p += kE * 128;
  float* td1t = p;    p += kH * 128;
  float* tdt  = p;    p += 128 * 128;
  float* l1t  = p;    p += 128 * 128;
  float* l2t  = p;    p += kH * 128;
  float* lt   = p;    p += 128 * 128;
  float* iht1 = p;    p += 128 * kG;
  float* iht2 = p;    p += 128 * kG;
  float* whd_t = p;   p += kH * kH;

  unsigned short* u = (unsigned short*)p;
  unsigned short* h1h = u;     u += kB * kH;
  unsigned short* h1l = u;     u += kB * kH;
  unsigned short* h2h = u;     u += kB * kH;
  unsigned short* h2l = u;     u += kB * kH;
  unsigned short* w1hh_h = u;  u += (size_t)kG * kH;
  unsigned short* w1hh_l = u;  u += (size_t)kG * kH;
  unsigned short* w2hh_h = u;  u += (size_t)kG * kH;
  unsigned short* w2hh_l = u;  u += (size_t)kG * kH;
  unsigned short* wc_h = u;    u += (size_t)kV * kH;
  unsigned short* wc_l = u;    u += (size_t)kV * kH;
  unsigned short* wf_h = u;    u += (size_t)kH * kC;
  unsigned short* wf_l = u;    u += (size_t)kH * kC;
  unsigned short* h2all_h = u; u += (size_t)kNS * kB * kH;
  unsigned short* h2all_l = u; u += (size_t)kNS * kB * kH;
  unsigned short* l1bt = u;    u += kC * kC;
  unsigned short* l2bt = u;    u += (size_t)kH * kC;
  unsigned short* lbt = u;     u += kC * kC;
  unsigned short* iht2b = u;   u += (size_t)kC * kG;
  unsigned short* whdbT = u;   u += (size_t)kH * kH;
  unsigned short* td1bt = u;   u += (size_t)kH * kC;
  unsigned short* tdbt = u;    u += kC * kC;
  unsigned short* iht1b = u;   u += (size_t)kC * kG;

  k_transpose<<<dim3(64, 9), 256, 0, stream>>>(
      W_td3, W_td1, W_td, W_l1, W_l2, W_l, W1_ih, W2_ih, W_hidd,
      td3t, td1t, tdt, l1t, l2t, lt, iht1, iht2, whd_t);
  k_tobf16<<<dim3(96, 8), 256, 0, stream>>>(
      l1t, l2t, lt, iht2, whd_t, td1t, tdt, iht1,
      l1bt, l2bt, lbt, iht2b, whdbT, td1bt, tdbt, iht1b);
  k_split<<<dim3(256, 4), 256, 0, stream>>>(
      W1_hh, W2_hh, W_cls, W_feat,
      w1hh_h, w1hh_l, w2hh_h, w2hh_l, wc_h, wc_l, wf_h, wf_l);
  k_init<<<128, 256, 0, stream>>>(t_feat, W_td2, td, h1, h2,
                                  h1h, h1l, h2h, h2l);
  k_featproj<<<dim3(512, 4), 256, 0, stream>>>(c_feats, wf_h, wf_l, fp);
  k_xw<<<dim3(64, kNS), 256, 0, stream>>>(word_embs, td3t, td, xw);
  k_prestep<<<256, 256, 0, stream>>>(xw, tdbt, iht1b, b1_ih, gx1);

  for (int t = 0; t < kNS; ++t) {
    k_gh<<<48, 256, 0, stream>>>(h1h, h1l, h2h, h2l,
                                 w1hh_h, w1hh_l, w2hh_h, w2hh_l,
                                 b1_hh, b2_hh, gh1, gh2);
    k_step2<<<256, 1024, 0, stream>>>(gx1, gh1, gh2, h1, h2,
                                      h1h, h1l, h2h, h2l, whdbT, W_att, fp,
                                      c_feats, l1bt, l2bt, lbt, iht2b, b2_ih,
                                      td1bt, tdbt, iht1b, b1_ih, xw,
                                      h2all_h, h2all_l, mask_ws, t);
  }
  k_atrans<<<256, 256, 0, stream>>>(mask_ws, attn_out);
  k_cls<<<dim3(62, 27), 256, 0, stream>>>(h2all_h, h2all_l, wc_h, wc_l,
                                          b_cls, lang);
}

// Round 7
// 2264.218 us; speedup vs baseline: 18.0020x; 1.7258x over previous
//
#include <hip/hip_runtime.h>
#include <hip/hip_bf16.h>

namespace {

constexpr int kB  = 256;   // batch
constexpr int kP  = 256;   // proposals
constexpr int kT  = 32;    // words
constexpr int kNS = 31;    // steps = T-1
constexpr int kV  = 3433;  // vocab
constexpr int kH  = 512;   // hidden
constexpr int kE  = 300;   // embed
constexpr int kC  = 128;   // feat dim
constexpr int kG  = 1536;  // 3H

typedef __bf16 bf16x8 __attribute__((ext_vector_type(8)));
typedef float f32x4 __attribute__((ext_vector_type(4)));

__device__ __forceinline__ float fexp2(float x) {
  float r; asm("v_exp_f32 %0, %1" : "=v"(r) : "v"(x)); return r;
}
__device__ __forceinline__ float frcp(float x) {
  float r; asm("v_rcp_f32 %0, %1" : "=v"(r) : "v"(x)); return r;
}
__device__ __forceinline__ float ftanh(float x) {
  float e = fexp2(x * 2.8853900817779268f);   // e^(2x)
  return 1.0f - 2.0f * frcp(e + 1.0f);
}
__device__ __forceinline__ float fsigm(float x) {
  return frcp(1.0f + fexp2(x * -1.4426950408889634f));
}
// Pade(7,6) tanh, clamped; err <1e-5 on [-3,3]; 1 trans op only.
__device__ __forceinline__ float ptanh(float x) {
  x = fminf(3.0f, fmaxf(-3.0f, x));
  float t = x * x;
  float num = x * fmaf(t, fmaf(t, 378.0f + t, 17325.0f), 135135.0f);
  float den = fmaf(t, fmaf(t, fmaf(t, 28.0f, 3150.0f), 62370.0f), 135135.0f);
  return num * frcp(den);
}
__device__ __forceinline__ unsigned short f2bf(float f) {   // RNE bf16
  unsigned u = __float_as_uint(f);
  u += 0x7FFFu + ((u >> 16) & 1u);
  return (unsigned short)(u >> 16);
}
__device__ __forceinline__ float bf2f(unsigned short s) {
  return __uint_as_float((unsigned)s << 16);
}
__device__ __forceinline__ bf16x8 bload(const unsigned short* p) {
  union { uint4 u; bf16x8 v; } x;
  x.u = *(const uint4*)p;
  return x.v;
}

// ---------------- one-time weight transposes (W[r][k] -> Wt[k*R + r]) -------
__global__ void k_transpose(const float* s0, const float* s1, const float* s2,
                            const float* s3, const float* s4, const float* s5,
                            const float* s6, const float* s7, const float* s8,
                            float* d0, float* d1, float* d2, float* d3,
                            float* d4, float* d5, float* d6, float* d7,
                            float* d8) {
  const float* src; float* dst; int R, Cd;
  switch (blockIdx.y) {
    case 0:  src = s0; dst = d0; R = 128;  Cd = 300; break;  // W_td3
    case 1:  src = s1; dst = d1; R = 128;  Cd = 512; break;  // W_td1
    case 2:  src = s2; dst = d2; R = 128;  Cd = 128; break;  // W_td
    case 3:  src = s3; dst = d3; R = 128;  Cd = 128; break;  // W_l1
    case 4:  src = s4; dst = d4; R = 128;  Cd = 512; break;  // W_l2
    case 5:  src = s5; dst = d5; R = 128;  Cd = 128; break;  // W_l
    case 6:  src = s6; dst = d6; R = 1536; Cd = 128; break;  // W1_ih
    case 7:  src = s7; dst = d7; R = 1536; Cd = 128; break;  // W2_ih
    default: src = s8; dst = d8; R = 512;  Cd = 512; break;  // W_hidd
  }
  int n = R * Cd;
  for (int i = blockIdx.x * blockDim.x + threadIdx.x; i < n;
       i += gridDim.x * blockDim.x) {
    int k = i / R, r = i - k * R;
    dst[i] = src[r * Cd + k];    // dst[k*R + r]
  }
}

// ---------------- bf16 copies of the loop-local transposed weights -----------
__global__ void k_tobf16(const float* s0, const float* s1, const float* s2,
                         const float* s3, const float* s4, const float* s5,
                         const float* s6, const float* s7,
                         unsigned short* d0, unsigned short* d1,
                         unsigned short* d2, unsigned short* d3,
                         unsigned short* d4, unsigned short* d5,
                         unsigned short* d6, unsigned short* d7) {
  const float* s; unsigned short* d; int n;
  switch (blockIdx.y) {
    case 0:  s = s0; d = d0; n = kC * kC; break;   // l1t
    case 1:  s = s1; d = d1; n = kH * kC; break;   // l2t
    case 2:  s = s2; d = d2; n = kC * kC; break;   // lt
    case 3:  s = s3; d = d3; n = kC * kG; break;   // iht2
    case 4:  s = s4; d = d4; n = kH * kH; break;   // whd_t
    case 5:  s = s5; d = d5; n = kH * kC; break;   // td1t
    case 6:  s = s6; d = d6; n = kC * kC; break;   // tdt
    default: s = s7; d = d7; n = kC * kG; break;   // iht1
  }
  for (int i = blockIdx.x * blockDim.x + threadIdx.x; i < n;
       i += gridDim.x * blockDim.x)
    d[i] = f2bf(s[i]);
}

// ---------------- one-time weight hi/lo bf16 splits --------------------------
__global__ void k_split(const float* s0, const float* s1, const float* s2,
                        const float* s3,
                        unsigned short* h0, unsigned short* l0,
                        unsigned short* h1, unsigned short* l1,
                        unsigned short* h2, unsigned short* l2,
                        unsigned short* h3, unsigned short* l3) {
  const float* s; unsigned short* h; unsigned short* l; int n;
  switch (blockIdx.y) {
    case 0:  s = s0; h = h0; l = l0; n = kG * kH; break;   // W1_hh
    case 1:  s = s1; h = h1; l = l1; n = kG * kH; break;   // W2_hh
    case 2:  s = s2; h = h2; l = l2; n = kV * kH; break;   // W_cls
    default: s = s3; h = h3; l = l3; n = kH * kC; break;   // W_feat
  }
  for (int i = blockIdx.x * blockDim.x + threadIdx.x; i < n;
       i += gridDim.x * blockDim.x) {
    float v = s[i];
    unsigned short hb = f2bf(v);
    h[i] = hb;
    l[i] = f2bf(v - bf2f(hb));
  }
}

// ---------------- init: td = t_feat @ W_td2^T ; zero h states ----------------
__global__ void k_init(const float* __restrict__ t_feat,
                       const float* __restrict__ W_td2,
                       float* __restrict__ td, float* __restrict__ h1,
                       float* __restrict__ h2,
                       unsigned short* __restrict__ h1h,
                       unsigned short* __restrict__ h1l,
                       unsigned short* __restrict__ h2h,
                       unsigned short* __restrict__ h2l) {
  int tid = blockIdx.x * 256 + threadIdx.x;  // 32768 threads
  int b = tid >> 7, c = tid & 127;
  const float* tf = t_feat + b * kC;
  const float* w  = W_td2 + c * kC;
  float acc = 0.f;
  for (int k = 0; k < kC; ++k) acc = fmaf(tf[k], w[k], acc);
  td[tid] = acc;
  for (int i = tid; i < kB * kH; i += (1 << 15)) {
    h1[i] = 0.f; h2[i] = 0.f;
    h1h[i] = 0; h1l[i] = 0; h2h[i] = 0; h2l[i] = 0;
  }
}

// ---------------- xw[t][b][:] = x_t @ W_td3^T + td ---------------------------
__global__ __launch_bounds__(256) void k_xw(
    const float* __restrict__ word_embs, const float* __restrict__ td3t,
    const float* __restrict__ td, float* __restrict__ xw) {
  __shared__ float xl[4 * 300];
  __shared__ float tdl[512];
  int t = blockIdx.y, b0 = blockIdx.x * 4, tid = threadIdx.x;
  #pragma unroll
  for (int r = 0; r < 4; ++r) {
    const float* xs = word_embs + (size_t)(b0 + r) * (kT * kE) + (size_t)t * kE;
    for (int e = tid; e < kE; e += 256) xl[r * kE + e] = xs[e];
  }
  for (int i = tid; i < 512; i += 256) tdl[i] = td[(size_t)b0 * kC + i];
  __syncthreads();
  #pragma unroll
  for (int q = 0; q < 2; ++q) {
    int idx = tid + q * 256;
    int r = idx >> 7, c = idx & 127;
    float acc = tdl[idx];
    const float* xr = xl + r * kE;
    const float* w3 = td3t + c;
    for (int e = 0; e < kE; ++e) acc = fmaf(xr[e], w3[(size_t)e * 128], acc);
    xw[((size_t)t * kB + b0 + r) * kC + c] = acc;
  }
}

// ---------------- prestep: s(0), gx1(0) from xw[0] (h2 = 0) ------------------
__global__ __launch_bounds__(256) void k_prestep(
    const float* __restrict__ xw, const unsigned short* __restrict__ tdbt,
    const unsigned short* __restrict__ iht1b, const float* __restrict__ b1_ih,
    float* __restrict__ gx1) {
  __shared__ float s1l[128];
  __shared__ float s2l[128];
  __shared__ float part[256];
  int b = blockIdx.x, tid = threadIdx.x;
  if (tid < 128) s1l[tid] = ftanh(xw[(size_t)b * kC + tid]);
  __syncthreads();
  {
    int c = tid & 127, g = tid >> 7;
    float s = 0.f;
    const unsigned short* w = tdbt + (size_t)(g * 64) * kC + c;
    for (int k = 0; k < 64; ++k)
      s = fmaf(s1l[g * 64 + k], bf2f(w[(size_t)k * kC]), s);
    part[g * 128 + c] = s;
  }
  __syncthreads();
  if (tid < 128) s2l[tid] = fmaxf(part[tid] + part[128 + tid], 0.f);
  __syncthreads();
  #pragma unroll
  for (int q = 0; q < 6; ++q) {
    int j = q * 256 + tid;
    float acc = b1_ih[j];
    const unsigned short* w = iht1b + j;
    for (int k = 0; k < kC; ++k)
      acc = fmaf(s2l[k], bf2f(w[(size_t)k * kG]), acc);
    gx1[(size_t)b * kG + j] = acc;
  }
}

// ---------------- LDS-staged split-bf16 MFMA 128x128 tile (3-term) -----------
// 256 threads. Stages Ah/Al/Bh/Bl 128x32 bf16 tiles in LDS per K-chunk.
__device__ __forceinline__ void mm_tile_lds(
    const unsigned short* __restrict__ Ah, const unsigned short* __restrict__ Al,
    const unsigned short* __restrict__ Bh, const unsigned short* __restrict__ Bl,
    int m0, int n0, int K, int nMax, f32x4 acc[4][4],
    unsigned short* sAh, unsigned short* sAl,
    unsigned short* sBh, unsigned short* sBl) {
  int tid = threadIdx.x;
  int lane = tid & 63, wid = tid >> 6;
  int wm = (wid >> 1) * 64, wn = (wid & 1) * 64;
  int r16 = lane & 15, kq = lane >> 4;
  int rA = tid >> 2, cA = (tid & 3) * 8;   // rows rA and rA+64, col-chunk cA
  int brow0 = n0 + rA;       if (brow0 > nMax) brow0 = nMax;
  int brow1 = n0 + rA + 64;  if (brow1 > nMax) brow1 = nMax;
  for (int k0 = 0; k0 < K; k0 += 32) {
    uint4 va0 = *(const uint4*)(Ah + (size_t)(m0 + rA) * K + k0 + cA);
    uint4 va1 = *(const uint4*)(Ah + (size_t)(m0 + rA + 64) * K + k0 + cA);
    uint4 vb0 = *(const uint4*)(Al + (size_t)(m0 + rA) * K + k0 + cA);
    uint4 vb1 = *(const uint4*)(Al + (size_t)(m0 + rA + 64) * K + k0 + cA);
    uint4 vc0 = *(const uint4*)(Bh + (size_t)brow0 * K + k0 + cA);
    uint4 vc1 = *(const uint4*)(Bh + (size_t)brow1 * K + k0 + cA);
    uint4 vd0 = *(const uint4*)(Bl + (size_t)brow0 * K + k0 + cA);
    uint4 vd1 = *(const uint4*)(Bl + (size_t)brow1 * K + k0 + cA);
    __syncthreads();   // previous chunk's reads complete
    *(uint4*)&sAh[rA * 32 + cA] = va0;
    *(uint4*)&sAh[(rA + 64) * 32 + cA] = va1;
    *(uint4*)&sAl[rA * 32 + cA] = vb0;
    *(uint4*)&sAl[(rA + 64) * 32 + cA] = vb1;
    *(uint4*)&sBh[rA * 32 + cA] = vc0;
    *(uint4*)&sBh[(rA + 64) * 32 + cA] = vc1;
    *(uint4*)&sBl[rA * 32 + cA] = vd0;
    *(uint4*)&sBl[(rA + 64) * 32 + cA] = vd1;
    __syncthreads();
    bf16x8 ah[4], al[4], bh[4], bl[4];
    #pragma unroll
    for (int i = 0; i < 4; ++i) {
      int ar = (wm + i * 16 + r16) * 32 + kq * 8;
      int br = (wn + i * 16 + r16) * 32 + kq * 8;
      ah[i] = *(const bf16x8*)&sAh[ar];
      al[i] = *(const bf16x8*)&sAl[ar];
      bh[i] = *(const bf16x8*)&sBh[br];
      bl[i] = *(const bf16x8*)&sBl[br];
    }
    #pragma unroll
    for (int i = 0; i < 4; ++i)
      #pragma unroll
      for (int j = 0; j < 4; ++j) {
        acc[i][j] = __builtin_amdgcn_mfma_f32_16x16x32_bf16(ah[i], bh[j], acc[i][j], 0, 0, 0);
        acc[i][j] = __builtin_amdgcn_mfma_f32_16x16x32_bf16(ah[i], bl[j], acc[i][j], 0, 0, 0);
        acc[i][j] = __builtin_amdgcn_mfma_f32_16x16x32_bf16(al[i], bh[j], acc[i][j], 0, 0, 0);
      }
  }
}

// ---------------- feat_proj = c_feats @ W_feat^T -> bf16 (MFMA) --------------
__global__ __launch_bounds__(256) void k_featproj(
    const float* __restrict__ A, const unsigned short* __restrict__ Wh,
    const unsigned short* __restrict__ Wl, unsigned short* __restrict__ out) {
  int lane = threadIdx.x & 63, wid = threadIdx.x >> 6;
  int wm = (wid >> 1) * 64, wn = (wid & 1) * 64;
  int r16 = lane & 15, kq = lane >> 4;
  int m0 = blockIdx.x * 128, n0 = blockIdx.y * 128;
  f32x4 acc[4][4];
  #pragma unroll
  for (int i = 0; i < 4; ++i)
    #pragma unroll
    for (int j = 0; j < 4; ++j) acc[i][j] = (f32x4){0.f, 0.f, 0.f, 0.f};
  for (int k0 = 0; k0 < kC; k0 += 32) {
    int kk = k0 + kq * 8;
    bf16x8 ah[4], al[4], bh[4], bl[4];
    #pragma unroll
    for (int i = 0; i < 4; ++i) {
      const float* pa = A + (size_t)(m0 + wm + i * 16 + r16) * kC + kk;
      float4 v0 = *(const float4*)pa;
      float4 v1 = *(const float4*)(pa + 4);
      float vv[8] = {v0.x, v0.y, v0.z, v0.w, v1.x, v1.y, v1.z, v1.w};
      union { unsigned short s[8]; bf16x8 v; } uh, ul;
      #pragma unroll
      for (int q = 0; q < 8; ++q) {
        unsigned short hb = f2bf(vv[q]);
        uh.s[q] = hb;
        ul.s[q] = f2bf(vv[q] - bf2f(hb));
      }
      ah[i] = uh.v; al[i] = ul.v;
      const unsigned short* pb = Wh + (size_t)(n0 + wn + i * 16 + r16) * kC + kk;
      const unsigned short* pl = Wl + (size_t)(n0 + wn + i * 16 + r16) * kC + kk;
      bh[i] = bload(pb); bl[i] = bload(pl);
    }
    #pragma unroll
    for (int i = 0; i < 4; ++i)
      #pragma unroll
      for (int j = 0; j < 4; ++j) {
        acc[i][j] = __builtin_amdgcn_mfma_f32_16x16x32_bf16(ah[i], bh[j], acc[i][j], 0, 0, 0);
        acc[i][j] = __builtin_amdgcn_mfma_f32_16x16x32_bf16(ah[i], bl[j], acc[i][j], 0, 0, 0);
        acc[i][j] = __builtin_amdgcn_mfma_f32_16x16x32_bf16(al[i], bh[j], acc[i][j], 0, 0, 0);
      }
  }
  #pragma unroll
  for (int i = 0; i < 4; ++i)
    #pragma unroll
    for (int j = 0; j < 4; ++j)
      #pragma unroll
      for (int r = 0; r < 4; ++r) {
        int m = m0 + wm + i * 16 + kq * 4 + r;
        int n = n0 + wn + j * 16 + r16;
        out[(size_t)m * kH + n] = f2bf(acc[i][j][r]);
      }
}

// ---------------- per-step kernel 1: gh1/gh2 MFMA (48 blocks, LDS-staged) ----
__global__ __launch_bounds__(256) void k_gh(
    const unsigned short* __restrict__ h1h, const unsigned short* __restrict__ h1l,
    const unsigned short* __restrict__ h2h, const unsigned short* __restrict__ h2l,
    const unsigned short* __restrict__ w1hh_h, const unsigned short* __restrict__ w1hh_l,
    const unsigned short* __restrict__ w2hh_h, const unsigned short* __restrict__ w2hh_l,
    const float* __restrict__ b1_hh, const float* __restrict__ b2_hh,
    float* __restrict__ gh1, float* __restrict__ gh2) {
  __shared__ __align__(16) unsigned short sAh[4096], sAl[4096], sBh[4096], sBl[4096];
  int g = blockIdx.x;   // 0..47
  const unsigned short *Ah, *Al, *Wh, *Wl; const float* bias; float* out;
  if (g < 24) { Ah = h1h; Al = h1l; Wh = w1hh_h; Wl = w1hh_l;
                bias = b1_hh; out = gh1; }
  else { g -= 24; Ah = h2h; Al = h2l; Wh = w2hh_h; Wl = w2hh_l;
         bias = b2_hh; out = gh2; }
  int m0 = (g / 12) * 128, n0 = (g % 12) * 128;
  f32x4 acc[4][4];
  #pragma unroll
  for (int i = 0; i < 4; ++i)
    #pragma unroll
    for (int j = 0; j < 4; ++j) acc[i][j] = (f32x4){0.f, 0.f, 0.f, 0.f};
  mm_tile_lds(Ah, Al, Wh, Wl, m0, n0, kH, kG - 1, acc, sAh, sAl, sBh, sBl);
  int tid = threadIdx.x;
  int lane = tid & 63, wid = tid >> 6;
  int wm = (wid >> 1) * 64, wn = (wid & 1) * 64;
  int r16 = lane & 15, kq = lane >> 4;
  #pragma unroll
  for (int i = 0; i < 4; ++i)
    #pragma unroll
    for (int j = 0; j < 4; ++j)
      #pragma unroll
      for (int r = 0; r < 4; ++r) {
        int m = m0 + wm + i * 16 + kq * 4 + r;
        int n = n0 + wn + j * 16 + r16;
        out[(size_t)m * kG + n] = acc[i][j][r] + bias[n];
      }
}

// ---------------- per-step kernel 2: one batch row per block, 1024 threads ---
__global__ __launch_bounds__(1024, 4) void k_step2(
    float* __restrict__ gx1, const float* __restrict__ gh1,
    const float* __restrict__ gh2,
    float* __restrict__ h1, float* __restrict__ h2,
    unsigned short* __restrict__ h1h, unsigned short* __restrict__ h1l,
    unsigned short* __restrict__ h2h, unsigned short* __restrict__ h2l,
    const unsigned short* __restrict__ whdbT, const float* __restrict__ W_att,
    const unsigned short* __restrict__ fp, const float* __restrict__ c_feats,
    const unsigned short* __restrict__ l1bt, const unsigned short* __restrict__ l2bt,
    const unsigned short* __restrict__ lbt, const unsigned short* __restrict__ iht2b,
    const float* __restrict__ b2_ih,
    const unsigned short* __restrict__ td1bt, const unsigned short* __restrict__ tdbt,
    const unsigned short* __restrict__ iht1b, const float* __restrict__ b1_ih,
    const float* __restrict__ xw,
    unsigned short* __restrict__ h2all_h, unsigned short* __restrict__ h2all_l,
    float* __restrict__ mask_ws, int t) {
  __shared__ float partbuf[8192];     // 32 KB, reused across phases
  __shared__ float h1p[512];
  __shared__ float h2p[512];
  __shared__ float hqs[512];
  __shared__ float scs[256];
  __shared__ float red[16];
  __shared__ float red2[16];
  __shared__ float attl[128];
  __shared__ float lt1[128];
  __shared__ float llv[128];
  __shared__ float s1l[128];
  __shared__ float s2l[128];
  __shared__ float gx2l[1536];
  const int b = blockIdx.x;
  const int tid = threadIdx.x;
  const int lane = tid & 63, wv = tid >> 6;   // 16 waves

  // ---- A: GRU1 combine -> h1' ----
  if (tid < 512) {
    int c = tid;
    float gr = gx1[(size_t)b * kG + c];
    float gz = gx1[(size_t)b * kG + 512 + c];
    float gn = gx1[(size_t)b * kG + 1024 + c];
    float hr = gh1[(size_t)b * kG + c];
    float hz = gh1[(size_t)b * kG + 512 + c];
    float hnv = gh1[(size_t)b * kG + 1024 + c];
    float rr = fsigm(gr + hr);
    float zz = fsigm(gz + hz);
    float nn = ftanh(gn + rr * hnv);
    float ho = h1[(size_t)b * kH + c];
    float hn = (1.f - zz) * nn + zz * ho;
    h1[(size_t)b * kH + c] = hn;
    h1p[c] = hn;
    unsigned short hb = f2bf(hn);
    h1h[(size_t)b * kH + c] = hb;
    h1l[(size_t)b * kH + c] = f2bf(hn - bf2f(hb));
  }
  __syncthreads();

  // ---- B: hq = h1' @ W_hidd^T. 64 col-groups(8) x 16 k-groups(32) ----
  {
    int cg = tid & 63, kg = tid >> 6;   // kg 0..15
    int c0 = cg * 8;
    const unsigned short* w = whdbT + (size_t)(kg * 32) * kH + c0;
    float acc[8] = {};
    #pragma unroll 4
    for (int k = 0; k < 32; ++k) {
      union { uint4 u; unsigned short s[8]; } wu;
      wu.u = *(const uint4*)(w + (size_t)k * kH);
      float h = h1p[kg * 32 + k];
      #pragma unroll
      for (int j = 0; j < 8; ++j) acc[j] = fmaf(h, bf2f(wu.s[j]), acc[j]);
    }
    float* pp = &partbuf[kg * 512 + c0];
    #pragma unroll
    for (int j = 0; j < 8; ++j) pp[j] = acc[j];
  }
  __syncthreads();
  if (tid < 512) {
    float s = 0.f;
    #pragma unroll
    for (int g = 0; g < 16; ++g) s += partbuf[g * 512 + tid];
    hqs[tid] = s;
  }
  __syncthreads();

  // ---- C: attention scores (Pade tanh), 16 waves x 16 proposals ----
  {
    float hq8[8], aw[8];
    #pragma unroll
    for (int j = 0; j < 8; ++j) hq8[j] = hqs[lane * 8 + j];
    {
      float4 a0 = *(const float4*)(W_att + lane * 8);
      float4 a1 = *(const float4*)(W_att + lane * 8 + 4);
      aw[0] = a0.x; aw[1] = a0.y; aw[2] = a0.z; aw[3] = a0.w;
      aw[4] = a1.x; aw[5] = a1.y; aw[6] = a1.z; aw[7] = a1.w;
    }
    const unsigned short* fpb = fp + (size_t)b * kP * kH;
    int p0 = wv * 16;
    uint4 rv = *(const uint4*)(fpb + (size_t)p0 * kH + lane * 8);
    for (int p = p0; p < p0 + 16; ++p) {
      union { uint4 v; unsigned short s[8]; } u; u.v = rv;
      if (p + 1 < p0 + 16)
        rv = *(const uint4*)(fpb + (size_t)(p + 1) * kH + lane * 8);
      float sc = 0.f;
      #pragma unroll
      for (int j = 0; j < 8; ++j) {
        float f = __uint_as_float((unsigned)u.s[j] << 16);
        sc += aw[j] * ptanh(f + hq8[j]);
      }
      #pragma unroll
      for (int m = 32; m; m >>= 1) sc += __shfl_xor(sc, m, 64);
      if (lane == 0) scs[p] = sc;
    }
  }
  __syncthreads();

  // ---- D: softmax over 256 proposals ----
  {
    float sv = (tid < 256) ? scs[tid] : -1e30f;
    float mx = sv;
    #pragma unroll
    for (int m = 32; m; m >>= 1) mx = fmaxf(mx, __shfl_xor(mx, m, 64));
    if (lane == 0) red[wv] = mx;
    __syncthreads();
    float bm = red[0];
    #pragma unroll
    for (int i = 1; i < 16; ++i) bm = fmaxf(bm, red[i]);
    float ev = (tid < 256) ? fexp2((sv - bm) * 1.4426950408889634f) : 0.f;
    float sm = ev;
    #pragma unroll
    for (int m = 32; m; m >>= 1) sm += __shfl_xor(sm, m, 64);
    if (lane == 0) red2[wv] = sm;
    __syncthreads();
    float tot = 0.f;
    #pragma unroll
    for (int i = 0; i < 16; ++i) tot += red2[i];
    if (tid < 256) {
      float mk = ev * frcp(tot);
      scs[tid] = mk;
      mask_ws[(size_t)t * (kB * kP) + (size_t)b * kP + tid] = mk;
    }
  }
  __syncthreads();

  // ---- E: attended = mask @ c_feats, 8 proposal-groups x 32 ----
  {
    int c = tid & 127, q = tid >> 7;
    const float* cf = c_feats + ((size_t)b * kP + q * 32) * kC + c;
    const float* ms = scs + q * 32;
    float acc = 0.f;
    for (int p = 0; p < 32; ++p) acc = fmaf(ms[p], cf[(size_t)p * kC], acc);
    partbuf[q * 128 + c] = acc;
  }
  __syncthreads();
  if (tid < 128) {
    float s = 0.f;
    #pragma unroll
    for (int q = 0; q < 8; ++q) s += partbuf[q * 128 + tid];
    attl[tid] = s;
  }
  __syncthreads();

  // ---- F: lt1 = tanh(att@W_l1^T + h1'@W_l2^T) ----
  // l2 part: threads 0..511 (16 cg x 32 kg, k=16); l1 part: 512..767 (16x16, k=8)
  {
    if (tid < 512) {
      int cg = tid & 15, kg = tid >> 4;
      int c0 = cg * 8;
      const unsigned short* w = l2bt + (size_t)(kg * 16) * kC + c0;
      float acc[8] = {};
      for (int k = 0; k < 16; ++k) {
        union { uint4 u; unsigned short s[8]; } wu;
        wu.u = *(const uint4*)(w + (size_t)k * kC);
        float h = h1p[kg * 16 + k];
        #pragma unroll
        for (int j = 0; j < 8; ++j) acc[j] = fmaf(h, bf2f(wu.s[j]), acc[j]);
      }
      float* pp = &partbuf[kg * 128 + c0];
      #pragma unroll
      for (int j = 0; j < 8; ++j) pp[j] = acc[j];
    } else if (tid < 768) {
      int tt = tid - 512;
      int cg = tt & 15, kg = tt >> 4;
      int c0 = cg * 8;
      const unsigned short* w = l1bt + (size_t)(kg * 8) * kC + c0;
      float acc[8] = {};
      for (int k = 0; k < 8; ++k) {
        union { uint4 u; unsigned short s[8]; } wu;
        wu.u = *(const uint4*)(w + (size_t)k * kC);
        float a = attl[kg * 8 + k];
        #pragma unroll
        for (int j = 0; j < 8; ++j) acc[j] = fmaf(a, bf2f(wu.s[j]), acc[j]);
      }
      float* pp = &partbuf[4096 + kg * 128 + c0];
      #pragma unroll
      for (int j = 0; j < 8; ++j) pp[j] = acc[j];
    }
  }
  __syncthreads();
  if (tid < 128) {
    float s = 0.f;
    #pragma unroll
    for (int g = 0; g < 32; ++g) s += partbuf[g * 128 + tid];
    #pragma unroll
    for (int g = 0; g < 16; ++g) s += partbuf[4096 + g * 128 + tid];
    lt1[tid] = ftanh(s);
  }
  __syncthreads();

  // ---- G: llv = relu(lt1 @ W_l^T), 16 cg x 16 kg (k=8) ----
  if (tid < 256) {
    int cg = tid & 15, kg = tid >> 4;
    int c0 = cg * 8;
    const unsigned short* w = lbt + (size_t)(kg * 8) * kC + c0;
    float acc[8] = {};
    for (int k = 0; k < 8; ++k) {
      union { uint4 u; unsigned short s[8]; } wu;
      wu.u = *(const uint4*)(w + (size_t)k * kC);
      float l = lt1[kg * 8 + k];
      #pragma unroll
      for (int j = 0; j < 8; ++j) acc[j] = fmaf(l, bf2f(wu.s[j]), acc[j]);
    }
    float* pp = &partbuf[kg * 128 + c0];
    #pragma unroll
    for (int j = 0; j < 8; ++j) pp[j] = acc[j];
  }
  __syncthreads();
  if (tid < 128) {
    float s = 0.f;
    #pragma unroll
    for (int g = 0; g < 16; ++g) s += partbuf[g * 128 + tid];
    llv[tid] = fmaxf(s, 0.f);
  }
  __syncthreads();

  // ---- H: gx2 = llv @ W2_ih^T + b2. 192 cg(8) x 4 kg(32) ----
  if (tid < 768) {
    int cg = tid % 192, kg = tid / 192;
    int c0 = cg * 8;
    const unsigned short* w = iht2b + (size_t)(kg * 32) * kG + c0;
    float acc[8] = {};
    #pragma unroll 4
    for (int k = 0; k < 32; ++k) {
      union { uint4 u; unsigned short s[8]; } wu;
      wu.u = *(const uint4*)(w + (size_t)k * kG);
      float l = llv[kg * 32 + k];
      #pragma unroll
      for (int j = 0; j < 8; ++j) acc[j] = fmaf(l, bf2f(wu.s[j]), acc[j]);
    }
    float* pp = &partbuf[kg * 1536 + c0];
    #pragma unroll
    for (int j = 0; j < 8; ++j) pp[j] = acc[j];
  }
  __syncthreads();
  for (int c = tid; c < kG; c += 1024) {
    float s = b2_ih[c];
    #pragma unroll
    for (int g = 0; g < 4; ++g) s += partbuf[g * 1536 + c];
    gx2l[c] = s;
  }
  __syncthreads();
  if (tid < 512) {
    int c = tid;
    float ghr = gh2[(size_t)b * kG + c];
    float ghz = gh2[(size_t)b * kG + 512 + c];
    float ghn = gh2[(size_t)b * kG + 1024 + c];
    float rr = fsigm(gx2l[c] + ghr);
    float zz = fsigm(gx2l[512 + c] + ghz);
    float nn = ftanh(gx2l[1024 + c] + rr * ghn);
    float ho = h2[(size_t)b * kH + c];
    float hn = (1.f - zz) * nn + zz * ho;
    h2[(size_t)b * kH + c] = hn;
    h2p[c] = hn;
    unsigned short hb = f2bf(hn);
    unsigned short lb = f2bf(hn - bf2f(hb));
    h2h[(size_t)b * kH + c] = hb;
    h2l[(size_t)b * kH + c] = lb;
    size_t o = ((size_t)t * kB + b) * kH + c;
    h2all_h[o] = hb;
    h2all_l[o] = lb;
  }
  __syncthreads();

  // ---- I: next step's s-chain + gx1 ----
  if (t + 1 < kNS) {
    // I1: s1 = tanh(xw[t+1] + h2'@W_td1^T), 16 cg x 32 kg (k=16)
    if (tid < 512) {
      int cg = tid & 15, kg = tid >> 4;
      int c0 = cg * 8;
      const unsigned short* w = td1bt + (size_t)(kg * 16) * kC + c0;
      float acc[8] = {};
      for (int k = 0; k < 16; ++k) {
        union { uint4 u; unsigned short s[8]; } wu;
        wu.u = *(const uint4*)(w + (size_t)k * kC);
        float h = h2p[kg * 16 + k];
        #pragma unroll
        for (int j = 0; j < 8; ++j) acc[j] = fmaf(h, bf2f(wu.s[j]), acc[j]);
      }
      float* pp = &partbuf[kg * 128 + c0];
      #pragma unroll
      for (int j = 0; j < 8; ++j) pp[j] = acc[j];
    }
    __syncthreads();
    if (tid < 128) {
      float s = xw[((size_t)(t + 1) * kB + b) * kC + tid];
      #pragma unroll
      for (int g = 0; g < 32; ++g) s += partbuf[g * 128 + tid];
      s1l[tid] = ftanh(s);
    }
    __syncthreads();
    // I2: s2 = relu(s1 @ W_td^T), 16 cg x 16 kg (k=8)
    if (tid < 256) {
      int cg = tid & 15, kg = tid >> 4;
      int c0 = cg * 8;
      const unsigned short* w = tdbt + (size_t)(kg * 8) * kC + c0;
      float acc[8] = {};
      for (int k = 0; k < 8; ++k) {
        union { uint4 u; unsigned short s[8]; } wu;
        wu.u = *(const uint4*)(w + (size_t)k * kC);
        float sv = s1l[kg * 8 + k];
        #pragma unroll
        for (int j = 0; j < 8; ++j) acc[j] = fmaf(sv, bf2f(wu.s[j]), acc[j]);
      }
      float* pp = &partbuf[kg * 128 + c0];
      #pragma unroll
      for (int j = 0; j < 8; ++j) pp[j] = acc[j];
    }
    __syncthreads();
    if (tid < 128) {
      float s = 0.f;
      #pragma unroll
      for (int g = 0; g < 16; ++g) s += partbuf[g * 128 + tid];
      s2l[tid] = fmaxf(s, 0.f);
    }
    __syncthreads();
    // I3: gx1(t+1) = s2 @ W1_ih^T + b1. 192 cg(8) x 4 kg(32)
    if (tid < 768) {
      int cg = tid % 192, kg = tid / 192;
      int c0 = cg * 8;
      const unsigned short* w = iht1b + (size_t)(kg * 32) * kG + c0;
      float acc[8] = {};
      #pragma unroll 4
      for (int k = 0; k < 32; ++k) {
        union { uint4 u; unsigned short s[8]; } wu;
        wu.u = *(const uint4*)(w + (size_t)k * kG);
        float sv = s2l[kg * 32 + k];
        #pragma unroll
        for (int j = 0; j < 8; ++j) acc[j] = fmaf(sv, bf2f(wu.s[j]), acc[j]);
      }
      float* pp = &partbuf[kg * 1536 + c0];
      #pragma unroll
      for (int j = 0; j < 8; ++j) pp[j] = acc[j];
    }
    __syncthreads();
    for (int c = tid; c < kG; c += 1024) {
      float s = b1_ih[c];
      #pragma unroll
      for (int g = 0; g < 4; ++g) s += partbuf[g * 1536 + c];
      gx1[(size_t)b * kG + c] = s;
    }
  }
}

// ---------------- mask transpose: [t][b][p] -> out[b][p][t] ------------------
__global__ __launch_bounds__(256) void k_atrans(
    const float* __restrict__ mws, float* __restrict__ attn_out) {
  int pair = blockIdx.x * 256 + threadIdx.x;   // 65536 (b,p) pairs
  #pragma unroll
  for (int t = 0; t < kNS; ++t)
    attn_out[(size_t)pair * kNS + t] = mws[(size_t)t * (kB * kP) + pair];
}

// ---------------- classifier: lang = h2_all @ W_cls^T + b_cls (MFMA, LDS) ----
__global__ __launch_bounds__(256) void k_cls(
    const unsigned short* __restrict__ Ah, const unsigned short* __restrict__ Al,
    const unsigned short* __restrict__ Wh, const unsigned short* __restrict__ Wl,
    const float* __restrict__ bc, float* __restrict__ out) {
  __shared__ __align__(16) unsigned short sAh[4096], sAl[4096], sBh[4096], sBl[4096];
  int m0 = blockIdx.x * 128, n0 = blockIdx.y * 128;
  f32x4 acc[4][4];
  #pragma unroll
  for (int i = 0; i < 4; ++i)
    #pragma unroll
    for (int j = 0; j < 4; ++j) acc[i][j] = (f32x4){0.f, 0.f, 0.f, 0.f};
  mm_tile_lds(Ah, Al, Wh, Wl, m0, n0, kH, kV - 1, acc, sAh, sAl, sBh, sBl);
  int lane = threadIdx.x & 63, wid = threadIdx.x >> 6;
  int wm = (wid >> 1) * 64, wn = (wid & 1) * 64;
  int r16 = lane & 15, kq = lane >> 4;
  #pragma unroll
  for (int i = 0; i < 4; ++i)
    #pragma unroll
    for (int j = 0; j < 4; ++j)
      #pragma unroll
      for (int r = 0; r < 4; ++r) {
        int m = m0 + wm + i * 16 + kq * 4 + r;
        int n = n0 + wn + j * 16 + r16;
        if (n < kV) {
          int tt = m >> 8, b = m & 255;
          out[(size_t)b * (kNS * kV) + (size_t)tt * kV + n] = acc[i][j][r] + bc[n];
        }
      }
}

}  // namespace

extern "C" void kernel_launch(void* const* d_in, const int* in_sizes, int n_in,
                              void* d_out, int out_size, void* d_ws,
                              size_t ws_size, hipStream_t stream) {
  (void)in_sizes; (void)n_in; (void)out_size; (void)ws_size;
  const float* word_embs = (const float*)d_in[0];
  const float* t_feat    = (const float*)d_in[1];
  const float* c_feats   = (const float*)d_in[2];
  const float* W_td1 = (const float*)d_in[4];
  const float* W_td2 = (const float*)d_in[5];
  const float* W_td3 = (const float*)d_in[6];
  const float* W_td  = (const float*)d_in[7];
  const float* W1_ih = (const float*)d_in[8];
  const float* W1_hh = (const float*)d_in[9];
  const float* b1_ih = (const float*)d_in[10];
  const float* b1_hh = (const float*)d_in[11];
  const float* W_feat = (const float*)d_in[12];
  const float* W_hidd = (const float*)d_in[13];
  const float* W_att  = (const float*)d_in[14];
  const float* W_l1 = (const float*)d_in[15];
  const float* W_l2 = (const float*)d_in[16];
  const float* W_l  = (const float*)d_in[17];
  const float* W2_ih = (const float*)d_in[18];
  const float* W2_hh = (const float*)d_in[19];
  const float* b2_ih = (const float*)d_in[20];
  const float* b2_hh = (const float*)d_in[21];
  const float* W_cls = (const float*)d_in[22];
  const float* b_cls = (const float*)d_in[23];

  float* lang = (float*)d_out;
  float* attn_out = lang + (size_t)kB * kNS * kV;
  // feat_proj (bf16, 64MB) lives in the lang_cap region of d_out — dead by
  // the time k_cls (the only writer of lang_cap) runs.
  unsigned short* fp = (unsigned short*)d_out;

  float* p = (float*)d_ws;
  float* h1 = p;      p += kB * kH;
  float* h2 = p;      p += kB * kH;
  float* td = p;      p += kB * kC;
  float* gx1 = p;     p += (size_t)kB * kG;
  float* gh1 = p;     p += (size_t)kB * kG;
  float* gh2 = p;     p += (size_t)kB * kG;
  float* mask_ws = p; p += (size_t)kNS * kB * kP;
  float* xw = p;      p += (size_t)kNS * kB * kC;
  float* td3t = p;    p += kE * 128;
  float* td1t = p;    p += kH * 128;
  float* tdt  = p;    p += 128 * 128;
  float* l1t  = p;    p += 128 * 128;
  float* l2t  = p;    p += kH * 128;
  float* lt   = p;    p += 128 * 128;
  float* iht1 = p;    p += 128 * kG;
  float* iht2 = p;    p += 128 * kG;
  float* whd_t = p;   p += kH * kH;

  unsigned short* u = (unsigned short*)p;
  unsigned short* h1h = u;     u += kB * kH;
  unsigned short* h1l = u;     u += kB * kH;
  unsigned short* h2h = u;     u += kB * kH;
  unsigned short* h2l = u;     u += kB * kH;
  unsigned short* w1hh_h = u;  u += (size_t)kG * kH;
  unsigned short* w1hh_l = u;  u += (size_t)kG * kH;
  unsigned short* w2hh_h = u;  u += (size_t)kG * kH;
  unsigned short* w2hh_l = u;  u += (size_t)kG * kH;
  unsigned short* wc_h = u;    u += (size_t)kV * kH;
  unsigned short* wc_l = u;    u += (size_t)kV * kH;
  unsigned short* wf_h = u;    u += (size_t)kH * kC;
  unsigned short* wf_l = u;    u += (size_t)kH * kC;
  unsigned short* h2all_h = u; u += (size_t)kNS * kB * kH;
  unsigned short* h2all_l = u; u += (size_t)kNS * kB * kH;
  unsigned short* l1bt = u;    u += kC * kC;
  unsigned short* l2bt = u;    u += (size_t)kH * kC;
  unsigned short* lbt = u;     u += kC * kC;
  unsigned short* iht2b = u;   u += (size_t)kC * kG;
  unsigned short* whdbT = u;   u += (size_t)kH * kH;
  unsigned short* td1bt = u;   u += (size_t)kH * kC;
  unsigned short* tdbt = u;    u += kC * kC;
  unsigned short* iht1b = u;   u += (size_t)kC * kG;

  k_transpose<<<dim3(64, 9), 256, 0, stream>>>(
      W_td3, W_td1, W_td, W_l1, W_l2, W_l, W1_ih, W2_ih, W_hidd,
      td3t, td1t, tdt, l1t, l2t, lt, iht1, iht2, whd_t);
  k_tobf16<<<dim3(96, 8), 256, 0, stream>>>(
      l1t, l2t, lt, iht2, whd_t, td1t, tdt, iht1,
      l1bt, l2bt, lbt, iht2b, whdbT, td1bt, tdbt, iht1b);
  k_split<<<dim3(256, 4), 256, 0, stream>>>(
      W1_hh, W2_hh, W_cls, W_feat,
      w1hh_h, w1hh_l, w2hh_h, w2hh_l, wc_h, wc_l, wf_h, wf_l);
  k_init<<<128, 256, 0, stream>>>(t_feat, W_td2, td, h1, h2,
                                  h1h, h1l, h2h, h2l);
  k_featproj<<<dim3(512, 4), 256, 0, stream>>>(c_feats, wf_h, wf_l, fp);
  k_xw<<<dim3(64, kNS), 256, 0, stream>>>(word_embs, td3t, td, xw);
  k_prestep<<<256, 256, 0, stream>>>(xw, tdbt, iht1b, b1_ih, gx1);

  for (int t = 0; t < kNS; ++t) {
    k_gh<<<48, 256, 0, stream>>>(h1h, h1l, h2h, h2l,
                                 w1hh_h, w1hh_l, w2hh_h, w2hh_l,
                                 b1_hh, b2_hh, gh1, gh2);
    k_step2<<<256, 1024, 0, stream>>>(gx1, gh1, gh2, h1, h2,
                                      h1h, h1l, h2h, h2l, whdbT, W_att, fp,
                                      c_feats, l1bt, l2bt, lbt, iht2b, b2_ih,
                                      td1bt, tdbt, iht1b, b1_ih, xw,
                                      h2all_h, h2all_l, mask_ws, t);
  }
  k_atrans<<<256, 256, 0, stream>>>(mask_ws, attn_out);
  k_cls<<<dim3(62, 27), 256, 0, stream>>>(h2all_h, h2all_l, wc_h, wc_l,
                                          b_cls, lang);
}

// Round 8
// 2227.646 us; speedup vs baseline: 18.2976x; 1.0164x over previous
//
#include <hip/hip_runtime.h>
#include <hip/hip_bf16.h>

namespace {

constexpr int kB  = 256;   // batch
constexpr int kP  = 256;   // proposals
constexpr int kT  = 32;    // words
constexpr int kNS = 31;    // steps = T-1
constexpr int kV  = 3433;  // vocab
constexpr int kH  = 512;   // hidden
constexpr int kE  = 300;   // embed
constexpr int kC  = 128;   // feat dim
constexpr int kG  = 1536;  // 3H
constexpr int kLdsStride = 40;   // shorts per LDS tile row (80B: 2-way max)

typedef __bf16 bf16x8 __attribute__((ext_vector_type(8)));
typedef float f32x4 __attribute__((ext_vector_type(4)));

__device__ __forceinline__ float fexp2(float x) {
  float r; asm("v_exp_f32 %0, %1" : "=v"(r) : "v"(x)); return r;
}
__device__ __forceinline__ float frcp(float x) {
  float r; asm("v_rcp_f32 %0, %1" : "=v"(r) : "v"(x)); return r;
}
__device__ __forceinline__ float ftanh(float x) {
  float e = fexp2(x * 2.8853900817779268f);   // e^(2x)
  return 1.0f - 2.0f * frcp(e + 1.0f);
}
__device__ __forceinline__ float fsigm(float x) {
  return frcp(1.0f + fexp2(x * -1.4426950408889634f));
}
__device__ __forceinline__ unsigned short f2bf(float f) {   // RNE bf16
  unsigned u = __float_as_uint(f);
  u += 0x7FFFu + ((u >> 16) & 1u);
  return (unsigned short)(u >> 16);
}
__device__ __forceinline__ float bf2f(unsigned short s) {
  return __uint_as_float((unsigned)s << 16);
}
__device__ __forceinline__ bf16x8 bload(const unsigned short* p) {
  union { uint4 u; bf16x8 v; } x;
  x.u = *(const uint4*)p;
  return x.v;
}

// ---------------- one-time weight transposes (W[r][k] -> Wt[k*R + r]) -------
__global__ void k_transpose(const float* s0, const float* s1, const float* s2,
                            const float* s3, const float* s4, const float* s5,
                            const float* s6, const float* s7, const float* s8,
                            float* d0, float* d1, float* d2, float* d3,
                            float* d4, float* d5, float* d6, float* d7,
                            float* d8) {
  const float* src; float* dst; int R, Cd;
  switch (blockIdx.y) {
    case 0:  src = s0; dst = d0; R = 128;  Cd = 300; break;  // W_td3
    case 1:  src = s1; dst = d1; R = 128;  Cd = 512; break;  // W_td1
    case 2:  src = s2; dst = d2; R = 128;  Cd = 128; break;  // W_td
    case 3:  src = s3; dst = d3; R = 128;  Cd = 128; break;  // W_l1
    case 4:  src = s4; dst = d4; R = 128;  Cd = 512; break;  // W_l2
    case 5:  src = s5; dst = d5; R = 128;  Cd = 128; break;  // W_l
    case 6:  src = s6; dst = d6; R = 1536; Cd = 128; break;  // W1_ih
    case 7:  src = s7; dst = d7; R = 1536; Cd = 128; break;  // W2_ih
    default: src = s8; dst = d8; R = 512;  Cd = 512; break;  // W_hidd
  }
  int n = R * Cd;
  for (int i = blockIdx.x * blockDim.x + threadIdx.x; i < n;
       i += gridDim.x * blockDim.x) {
    int k = i / R, r = i - k * R;
    dst[i] = src[r * Cd + k];    // dst[k*R + r]
  }
}

// ---------------- bf16 copies of the loop-local transposed weights -----------
__global__ void k_tobf16(const float* s0, const float* s1, const float* s2,
                         const float* s3, const float* s4, const float* s5,
                         const float* s6, const float* s7,
                         unsigned short* d0, unsigned short* d1,
                         unsigned short* d2, unsigned short* d3,
                         unsigned short* d4, unsigned short* d5,
                         unsigned short* d6, unsigned short* d7) {
  const float* s; unsigned short* d; int n;
  switch (blockIdx.y) {
    case 0:  s = s0; d = d0; n = kC * kC; break;   // l1t
    case 1:  s = s1; d = d1; n = kH * kC; break;   // l2t
    case 2:  s = s2; d = d2; n = kC * kC; break;   // lt
    case 3:  s = s3; d = d3; n = kC * kG; break;   // iht2
    case 4:  s = s4; d = d4; n = kH * kH; break;   // whd_t
    case 5:  s = s5; d = d5; n = kH * kC; break;   // td1t
    case 6:  s = s6; d = d6; n = kC * kC; break;   // tdt
    default: s = s7; d = d7; n = kC * kG; break;   // iht1
  }
  for (int i = blockIdx.x * blockDim.x + threadIdx.x; i < n;
       i += gridDim.x * blockDim.x)
    d[i] = f2bf(s[i]);
}

// ---------------- one-time weight hi/lo bf16 splits --------------------------
__global__ void k_split(const float* s0, const float* s1, const float* s2,
                        const float* s3,
                        unsigned short* h0, unsigned short* l0,
                        unsigned short* h1, unsigned short* l1,
                        unsigned short* h2, unsigned short* l2,
                        unsigned short* h3, unsigned short* l3) {
  const float* s; unsigned short* h; unsigned short* l; int n;
  switch (blockIdx.y) {
    case 0:  s = s0; h = h0; l = l0; n = kG * kH; break;   // W1_hh
    case 1:  s = s1; h = h1; l = l1; n = kG * kH; break;   // W2_hh
    case 2:  s = s2; h = h2; l = l2; n = kV * kH; break;   // W_cls
    default: s = s3; h = h3; l = l3; n = kH * kC; break;   // W_feat
  }
  for (int i = blockIdx.x * blockDim.x + threadIdx.x; i < n;
       i += gridDim.x * blockDim.x) {
    float v = s[i];
    unsigned short hb = f2bf(v);
    h[i] = hb;
    l[i] = f2bf(v - bf2f(hb));
  }
}

// ---------------- init: td = t_feat @ W_td2^T ; zero h states ----------------
__global__ void k_init(const float* __restrict__ t_feat,
                       const float* __restrict__ W_td2,
                       float* __restrict__ td, float* __restrict__ h1,
                       float* __restrict__ h2,
                       unsigned short* __restrict__ h1h,
                       unsigned short* __restrict__ h1l,
                       unsigned short* __restrict__ h2h,
                       unsigned short* __restrict__ h2l) {
  int tid = blockIdx.x * 256 + threadIdx.x;  // 32768 threads
  int b = tid >> 7, c = tid & 127;
  const float* tf = t_feat + b * kC;
  const float* w  = W_td2 + c * kC;
  float acc = 0.f;
  for (int k = 0; k < kC; ++k) acc = fmaf(tf[k], w[k], acc);
  td[tid] = acc;
  for (int i = tid; i < kB * kH; i += (1 << 15)) {
    h1[i] = 0.f; h2[i] = 0.f;
    h1h[i] = 0; h1l[i] = 0; h2h[i] = 0; h2l[i] = 0;
  }
}

// ---------------- xw[t][b][:] = x_t @ W_td3^T + td ---------------------------
__global__ __launch_bounds__(256) void k_xw(
    const float* __restrict__ word_embs, const float* __restrict__ td3t,
    const float* __restrict__ td, float* __restrict__ xw) {
  __shared__ float xl[4 * 300];
  __shared__ float tdl[512];
  int t = blockIdx.y, b0 = blockIdx.x * 4, tid = threadIdx.x;
  #pragma unroll
  for (int r = 0; r < 4; ++r) {
    const float* xs = word_embs + (size_t)(b0 + r) * (kT * kE) + (size_t)t * kE;
    for (int e = tid; e < kE; e += 256) xl[r * kE + e] = xs[e];
  }
  for (int i = tid; i < 512; i += 256) tdl[i] = td[(size_t)b0 * kC + i];
  __syncthreads();
  #pragma unroll
  for (int q = 0; q < 2; ++q) {
    int idx = tid + q * 256;
    int r = idx >> 7, c = idx & 127;
    float acc = tdl[idx];
    const float* xr = xl + r * kE;
    const float* w3 = td3t + c;
    for (int e = 0; e < kE; ++e) acc = fmaf(xr[e], w3[(size_t)e * 128], acc);
    xw[((size_t)t * kB + b0 + r) * kC + c] = acc;
  }
}

// ---------------- prestep: s(0), gx1(0) from xw[0] (h2 = 0) ------------------
__global__ __launch_bounds__(256) void k_prestep(
    const float* __restrict__ xw, const unsigned short* __restrict__ tdbt,
    const unsigned short* __restrict__ iht1b, const float* __restrict__ b1_ih,
    float* __restrict__ gx1) {
  __shared__ float s1l[128];
  __shared__ float s2l[128];
  __shared__ float part[256];
  int b = blockIdx.x, tid = threadIdx.x;
  if (tid < 128) s1l[tid] = ftanh(xw[(size_t)b * kC + tid]);
  __syncthreads();
  {
    int c = tid & 127, g = tid >> 7;
    float s = 0.f;
    const unsigned short* w = tdbt + (size_t)(g * 64) * kC + c;
    for (int k = 0; k < 64; ++k)
      s = fmaf(s1l[g * 64 + k], bf2f(w[(size_t)k * kC]), s);
    part[g * 128 + c] = s;
  }
  __syncthreads();
  if (tid < 128) s2l[tid] = fmaxf(part[tid] + part[128 + tid], 0.f);
  __syncthreads();
  #pragma unroll
  for (int q = 0; q < 6; ++q) {
    int j = q * 256 + tid;
    float acc = b1_ih[j];
    const unsigned short* w = iht1b + j;
    for (int k = 0; k < kC; ++k)
      acc = fmaf(s2l[k], bf2f(w[(size_t)k * kG]), acc);
    gx1[(size_t)b * kG + j] = acc;
  }
}

// ---------------- LDS-staged split-bf16 MFMA 128x128 tile (3-term) -----------
// 256 threads. Stages Ah/Al/Bh/Bl 128x32 bf16 tiles in LDS (stride 40 shorts:
// rows map to 8 distinct bank quads -> max 2-way conflict, which is free).
__device__ __forceinline__ void mm_tile_lds(
    const unsigned short* __restrict__ Ah, const unsigned short* __restrict__ Al,
    const unsigned short* __restrict__ Bh, const unsigned short* __restrict__ Bl,
    int m0, int n0, int K, int kbeg, int kend, int nMax, f32x4 acc[4][4],
    unsigned short* sAh, unsigned short* sAl,
    unsigned short* sBh, unsigned short* sBl) {
  int tid = threadIdx.x;
  int lane = tid & 63, wid = tid >> 6;
  int wm = (wid >> 1) * 64, wn = (wid & 1) * 64;
  int r16 = lane & 15, kq = lane >> 4;
  int rA = tid >> 2, cA = (tid & 3) * 8;   // rows rA and rA+64, col-chunk cA
  int brow0 = n0 + rA;       if (brow0 > nMax) brow0 = nMax;
  int brow1 = n0 + rA + 64;  if (brow1 > nMax) brow1 = nMax;
  for (int k0 = kbeg; k0 < kend; k0 += 32) {
    uint4 va0 = *(const uint4*)(Ah + (size_t)(m0 + rA) * K + k0 + cA);
    uint4 va1 = *(const uint4*)(Ah + (size_t)(m0 + rA + 64) * K + k0 + cA);
    uint4 vb0 = *(const uint4*)(Al + (size_t)(m0 + rA) * K + k0 + cA);
    uint4 vb1 = *(const uint4*)(Al + (size_t)(m0 + rA + 64) * K + k0 + cA);
    uint4 vc0 = *(const uint4*)(Bh + (size_t)brow0 * K + k0 + cA);
    uint4 vc1 = *(const uint4*)(Bh + (size_t)brow1 * K + k0 + cA);
    uint4 vd0 = *(const uint4*)(Bl + (size_t)brow0 * K + k0 + cA);
    uint4 vd1 = *(const uint4*)(Bl + (size_t)brow1 * K + k0 + cA);
    __syncthreads();   // previous chunk's reads complete
    *(uint4*)&sAh[rA * kLdsStride + cA] = va0;
    *(uint4*)&sAh[(rA + 64) * kLdsStride + cA] = va1;
    *(uint4*)&sAl[rA * kLdsStride + cA] = vb0;
    *(uint4*)&sAl[(rA + 64) * kLdsStride + cA] = vb1;
    *(uint4*)&sBh[rA * kLdsStride + cA] = vc0;
    *(uint4*)&sBh[(rA + 64) * kLdsStride + cA] = vc1;
    *(uint4*)&sBl[rA * kLdsStride + cA] = vd0;
    *(uint4*)&sBl[(rA + 64) * kLdsStride + cA] = vd1;
    __syncthreads();
    bf16x8 ah[4], al[4], bh[4], bl[4];
    #pragma unroll
    for (int i = 0; i < 4; ++i) {
      int ar = (wm + i * 16 + r16) * kLdsStride + kq * 8;
      int br = (wn + i * 16 + r16) * kLdsStride + kq * 8;
      ah[i] = *(const bf16x8*)&sAh[ar];
      al[i] = *(const bf16x8*)&sAl[ar];
      bh[i] = *(const bf16x8*)&sBh[br];
      bl[i] = *(const bf16x8*)&sBl[br];
    }
    #pragma unroll
    for (int i = 0; i < 4; ++i)
      #pragma unroll
      for (int j = 0; j < 4; ++j) {
        acc[i][j] = __builtin_amdgcn_mfma_f32_16x16x32_bf16(ah[i], bh[j], acc[i][j], 0, 0, 0);
        acc[i][j] = __builtin_amdgcn_mfma_f32_16x16x32_bf16(ah[i], bl[j], acc[i][j], 0, 0, 0);
        acc[i][j] = __builtin_amdgcn_mfma_f32_16x16x32_bf16(al[i], bh[j], acc[i][j], 0, 0, 0);
      }
  }
}

// ---------------- feat_proj = c_feats @ W_feat^T -> bf16 (MFMA) --------------
__global__ __launch_bounds__(256) void k_featproj(
    const float* __restrict__ A, const unsigned short* __restrict__ Wh,
    const unsigned short* __restrict__ Wl, unsigned short* __restrict__ out) {
  int lane = threadIdx.x & 63, wid = threadIdx.x >> 6;
  int wm = (wid >> 1) * 64, wn = (wid & 1) * 64;
  int r16 = lane & 15, kq = lane >> 4;
  int m0 = blockIdx.x * 128, n0 = blockIdx.y * 128;
  f32x4 acc[4][4];
  #pragma unroll
  for (int i = 0; i < 4; ++i)
    #pragma unroll
    for (int j = 0; j < 4; ++j) acc[i][j] = (f32x4){0.f, 0.f, 0.f, 0.f};
  for (int k0 = 0; k0 < kC; k0 += 32) {
    int kk = k0 + kq * 8;
    bf16x8 ah[4], al[4], bh[4], bl[4];
    #pragma unroll
    for (int i = 0; i < 4; ++i) {
      const float* pa = A + (size_t)(m0 + wm + i * 16 + r16) * kC + kk;
      float4 v0 = *(const float4*)pa;
      float4 v1 = *(const float4*)(pa + 4);
      float vv[8] = {v0.x, v0.y, v0.z, v0.w, v1.x, v1.y, v1.z, v1.w};
      union { unsigned short s[8]; bf16x8 v; } uh, ul;
      #pragma unroll
      for (int q = 0; q < 8; ++q) {
        unsigned short hb = f2bf(vv[q]);
        uh.s[q] = hb;
        ul.s[q] = f2bf(vv[q] - bf2f(hb));
      }
      ah[i] = uh.v; al[i] = ul.v;
      const unsigned short* pb = Wh + (size_t)(n0 + wn + i * 16 + r16) * kC + kk;
      const unsigned short* pl = Wl + (size_t)(n0 + wn + i * 16 + r16) * kC + kk;
      bh[i] = bload(pb); bl[i] = bload(pl);
    }
    #pragma unroll
    for (int i = 0; i < 4; ++i)
      #pragma unroll
      for (int j = 0; j < 4; ++j) {
        acc[i][j] = __builtin_amdgcn_mfma_f32_16x16x32_bf16(ah[i], bh[j], acc[i][j], 0, 0, 0);
        acc[i][j] = __builtin_amdgcn_mfma_f32_16x16x32_bf16(ah[i], bl[j], acc[i][j], 0, 0, 0);
        acc[i][j] = __builtin_amdgcn_mfma_f32_16x16x32_bf16(al[i], bh[j], acc[i][j], 0, 0, 0);
      }
  }
  #pragma unroll
  for (int i = 0; i < 4; ++i)
    #pragma unroll
    for (int j = 0; j < 4; ++j)
      #pragma unroll
      for (int r = 0; r < 4; ++r) {
        int m = m0 + wm + i * 16 + kq * 4 + r;
        int n = n0 + wn + j * 16 + r16;
        out[(size_t)m * kH + n] = f2bf(acc[i][j][r]);
      }
}

// ---------------- per-step kernel 1: gh1/gh2 MFMA, K-split x2 (96 blocks) ----
// Block g2: g = g2>>1 selects (gru, m-tile, n-tile); half = g2&1 selects
// K in [half*256, half*256+256). Output goes to partial buffer `half`;
// bias added only in half 0. step2 phases A/H sum both partials.
__global__ __launch_bounds__(256) void k_gh(
    const unsigned short* __restrict__ h1h, const unsigned short* __restrict__ h1l,
    const unsigned short* __restrict__ h2h, const unsigned short* __restrict__ h2l,
    const unsigned short* __restrict__ w1hh_h, const unsigned short* __restrict__ w1hh_l,
    const unsigned short* __restrict__ w2hh_h, const unsigned short* __restrict__ w2hh_l,
    const float* __restrict__ b1_hh, const float* __restrict__ b2_hh,
    float* __restrict__ gh1, float* __restrict__ gh2) {
  __shared__ __align__(16) unsigned short sAh[128 * kLdsStride];
  __shared__ __align__(16) unsigned short sAl[128 * kLdsStride];
  __shared__ __align__(16) unsigned short sBh[128 * kLdsStride];
  __shared__ __align__(16) unsigned short sBl[128 * kLdsStride];
  int g2 = blockIdx.x;          // 0..95
  int half = g2 & 1, g = g2 >> 1;   // g 0..47
  const unsigned short *Ah, *Al, *Wh, *Wl; const float* bias; float* out;
  if (g < 24) { Ah = h1h; Al = h1l; Wh = w1hh_h; Wl = w1hh_l;
                bias = b1_hh; out = gh1; }
  else { g -= 24; Ah = h2h; Al = h2l; Wh = w2hh_h; Wl = w2hh_l;
         bias = b2_hh; out = gh2; }
  out += (size_t)half * (kB * kG);
  int m0 = (g / 12) * 128, n0 = (g % 12) * 128;
  f32x4 acc[4][4];
  #pragma unroll
  for (int i = 0; i < 4; ++i)
    #pragma unroll
    for (int j = 0; j < 4; ++j) acc[i][j] = (f32x4){0.f, 0.f, 0.f, 0.f};
  mm_tile_lds(Ah, Al, Wh, Wl, m0, n0, kH, half * 256, half * 256 + 256,
              kG - 1, acc, sAh, sAl, sBh, sBl);
  int tid = threadIdx.x;
  int lane = tid & 63, wid = tid >> 6;
  int wm = (wid >> 1) * 64, wn = (wid & 1) * 64;
  int r16 = lane & 15, kq = lane >> 4;
  #pragma unroll
  for (int i = 0; i < 4; ++i)
    #pragma unroll
    for (int j = 0; j < 4; ++j)
      #pragma unroll
      for (int r = 0; r < 4; ++r) {
        int m = m0 + wm + i * 16 + kq * 4 + r;
        int n = n0 + wn + j * 16 + r16;
        float v = acc[i][j][r];
        if (half == 0) v += bias[n];
        out[(size_t)m * kG + n] = v;
      }
}

// ---------------- per-step kernel 2: one batch row per block, 1024 threads ---
__global__ __launch_bounds__(1024, 4) void k_step2(
    float* __restrict__ gx1, const float* __restrict__ gh1,
    const float* __restrict__ gh2,
    float* __restrict__ h1, float* __restrict__ h2,
    unsigned short* __restrict__ h1h, unsigned short* __restrict__ h1l,
    unsigned short* __restrict__ h2h, unsigned short* __restrict__ h2l,
    const unsigned short* __restrict__ whdbT, const float* __restrict__ W_att,
    const unsigned short* __restrict__ fp, const float* __restrict__ c_feats,
    const unsigned short* __restrict__ l1bt, const unsigned short* __restrict__ l2bt,
    const unsigned short* __restrict__ lbt, const unsigned short* __restrict__ iht2b,
    const float* __restrict__ b2_ih,
    const unsigned short* __restrict__ td1bt, const unsigned short* __restrict__ tdbt,
    const unsigned short* __restrict__ iht1b, const float* __restrict__ b1_ih,
    const float* __restrict__ xw,
    unsigned short* __restrict__ h2all_h, unsigned short* __restrict__ h2all_l,
    float* __restrict__ mask_ws, int t) {
  __shared__ float partbuf[8192];     // 32 KB, reused across phases
  __shared__ float h1p[512];
  __shared__ float h2p[512];
  __shared__ float hqs[512];
  __shared__ float scs[256];
  __shared__ float red[16];
  __shared__ float red2[16];
  __shared__ float attl[128];
  __shared__ float lt1[128];
  __shared__ float llv[128];
  __shared__ float s1l[128];
  __shared__ float s2l[128];
  __shared__ float gx2l[1536];
  const int b = blockIdx.x;
  const int tid = threadIdx.x;
  const int lane = tid & 63, wv = tid >> 6;   // 16 waves
  const size_t GPART = (size_t)kB * kG;       // gh k-split partial offset

  // ---- A: GRU1 combine -> h1' ----
  if (tid < 512) {
    int c = tid;
    float gr = gx1[(size_t)b * kG + c];
    float gz = gx1[(size_t)b * kG + 512 + c];
    float gn = gx1[(size_t)b * kG + 1024 + c];
    float hr = gh1[(size_t)b * kG + c] + gh1[GPART + (size_t)b * kG + c];
    float hz = gh1[(size_t)b * kG + 512 + c] + gh1[GPART + (size_t)b * kG + 512 + c];
    float hnv = gh1[(size_t)b * kG + 1024 + c] + gh1[GPART + (size_t)b * kG + 1024 + c];
    float rr = fsigm(gr + hr);
    float zz = fsigm(gz + hz);
    float nn = ftanh(gn + rr * hnv);
    float ho = h1[(size_t)b * kH + c];
    float hn = (1.f - zz) * nn + zz * ho;
    h1[(size_t)b * kH + c] = hn;
    h1p[c] = hn;
    unsigned short hb = f2bf(hn);
    h1h[(size_t)b * kH + c] = hb;
    h1l[(size_t)b * kH + c] = f2bf(hn - bf2f(hb));
  }
  __syncthreads();

  // ---- B: hq = h1' @ W_hidd^T. 64 col-groups(8) x 16 k-groups(32) ----
  {
    int cg = tid & 63, kg = tid >> 6;   // kg 0..15
    int c0 = cg * 8;
    const unsigned short* w = whdbT + (size_t)(kg * 32) * kH + c0;
    float acc[8] = {};
    #pragma unroll 4
    for (int k = 0; k < 32; ++k) {
      union { uint4 u; unsigned short s[8]; } wu;
      wu.u = *(const uint4*)(w + (size_t)k * kH);
      float h = h1p[kg * 32 + k];
      #pragma unroll
      for (int j = 0; j < 8; ++j) acc[j] = fmaf(h, bf2f(wu.s[j]), acc[j]);
    }
    float* pp = &partbuf[kg * 512 + c0];
    #pragma unroll
    for (int j = 0; j < 8; ++j) pp[j] = acc[j];
  }
  __syncthreads();
  if (tid < 512) {
    float s = 0.f;
    #pragma unroll
    for (int g = 0; g < 16; ++g) s += partbuf[g * 512 + tid];
    hqs[tid] = s;
  }
  __syncthreads();

  // ---- C: attention scores (exp-tanh), 16 waves x 16 proposals ----
  {
    float hq8[8], aw[8];
    #pragma unroll
    for (int j = 0; j < 8; ++j) hq8[j] = hqs[lane * 8 + j];
    {
      float4 a0 = *(const float4*)(W_att + lane * 8);
      float4 a1 = *(const float4*)(W_att + lane * 8 + 4);
      aw[0] = a0.x; aw[1] = a0.y; aw[2] = a0.z; aw[3] = a0.w;
      aw[4] = a1.x; aw[5] = a1.y; aw[6] = a1.z; aw[7] = a1.w;
    }
    const unsigned short* fpb = fp + (size_t)b * kP * kH;
    int p0 = wv * 16;
    uint4 rv = *(const uint4*)(fpb + (size_t)p0 * kH + lane * 8);
    for (int p = p0; p < p0 + 16; ++p) {
      union { uint4 v; unsigned short s[8]; } u; u.v = rv;
      if (p + 1 < p0 + 16)
        rv = *(const uint4*)(fpb + (size_t)(p + 1) * kH + lane * 8);
      float sc = 0.f;
      #pragma unroll
      for (int j = 0; j < 8; ++j) {
        float f = __uint_as_float((unsigned)u.s[j] << 16);
        sc += aw[j] * ftanh(f + hq8[j]);
      }
      #pragma unroll
      for (int m = 32; m; m >>= 1) sc += __shfl_xor(sc, m, 64);
      if (lane == 0) scs[p] = sc;
    }
  }
  __syncthreads();

  // ---- D: softmax over 256 proposals ----
  {
    float sv = (tid < 256) ? scs[tid] : -1e30f;
    float mx = sv;
    #pragma unroll
    for (int m = 32; m; m >>= 1) mx = fmaxf(mx, __shfl_xor(mx, m, 64));
    if (lane == 0) red[wv] = mx;
    __syncthreads();
    float bm = red[0];
    #pragma unroll
    for (int i = 1; i < 16; ++i) bm = fmaxf(bm, red[i]);
    float ev = (tid < 256) ? fexp2((sv - bm) * 1.4426950408889634f) : 0.f;
    float sm = ev;
    #pragma unroll
    for (int m = 32; m; m >>= 1) sm += __shfl_xor(sm, m, 64);
    if (lane == 0) red2[wv] = sm;
    __syncthreads();
    float tot = 0.f;
    #pragma unroll
    for (int i = 0; i < 16; ++i) tot += red2[i];
    if (tid < 256) {
      float mk = ev * frcp(tot);
      scs[tid] = mk;
      mask_ws[(size_t)t * (kB * kP) + (size_t)b * kP + tid] = mk;
    }
  }
  __syncthreads();

  // ---- E: attended = mask @ c_feats, 8 proposal-groups x 32 ----
  {
    int c = tid & 127, q = tid >> 7;
    const float* cf = c_feats + ((size_t)b * kP + q * 32) * kC + c;
    const float* ms = scs + q * 32;
    float acc = 0.f;
    for (int p = 0; p < 32; ++p) acc = fmaf(ms[p], cf[(size_t)p * kC], acc);
    partbuf[q * 128 + c] = acc;
  }
  __syncthreads();
  if (tid < 128) {
    float s = 0.f;
    #pragma unroll
    for (int q = 0; q < 8; ++q) s += partbuf[q * 128 + tid];
    attl[tid] = s;
  }
  __syncthreads();

  // ---- F: lt1 = tanh(att@W_l1^T + h1'@W_l2^T) ----
  {
    if (tid < 512) {
      int cg = tid & 15, kg = tid >> 4;
      int c0 = cg * 8;
      const unsigned short* w = l2bt + (size_t)(kg * 16) * kC + c0;
      float acc[8] = {};
      for (int k = 0; k < 16; ++k) {
        union { uint4 u; unsigned short s[8]; } wu;
        wu.u = *(const uint4*)(w + (size_t)k * kC);
        float h = h1p[kg * 16 + k];
        #pragma unroll
        for (int j = 0; j < 8; ++j) acc[j] = fmaf(h, bf2f(wu.s[j]), acc[j]);
      }
      float* pp = &partbuf[kg * 128 + c0];
      #pragma unroll
      for (int j = 0; j < 8; ++j) pp[j] = acc[j];
    } else if (tid < 768) {
      int tt = tid - 512;
      int cg = tt & 15, kg = tt >> 4;
      int c0 = cg * 8;
      const unsigned short* w = l1bt + (size_t)(kg * 8) * kC + c0;
      float acc[8] = {};
      for (int k = 0; k < 8; ++k) {
        union { uint4 u; unsigned short s[8]; } wu;
        wu.u = *(const uint4*)(w + (size_t)k * kC);
        float a = attl[kg * 8 + k];
        #pragma unroll
        for (int j = 0; j < 8; ++j) acc[j] = fmaf(a, bf2f(wu.s[j]), acc[j]);
      }
      float* pp = &partbuf[4096 + kg * 128 + c0];
      #pragma unroll
      for (int j = 0; j < 8; ++j) pp[j] = acc[j];
    }
  }
  __syncthreads();
  if (tid < 128) {
    float s = 0.f;
    #pragma unroll
    for (int g = 0; g < 32; ++g) s += partbuf[g * 128 + tid];
    #pragma unroll
    for (int g = 0; g < 16; ++g) s += partbuf[4096 + g * 128 + tid];
    lt1[tid] = ftanh(s);
  }
  __syncthreads();

  // ---- G: llv = relu(lt1 @ W_l^T), 16 cg x 16 kg (k=8) ----
  if (tid < 256) {
    int cg = tid & 15, kg = tid >> 4;
    int c0 = cg * 8;
    const unsigned short* w = lbt + (size_t)(kg * 8) * kC + c0;
    float acc[8] = {};
    for (int k = 0; k < 8; ++k) {
      union { uint4 u; unsigned short s[8]; } wu;
      wu.u = *(const uint4*)(w + (size_t)k * kC);
      float l = lt1[kg * 8 + k];
      #pragma unroll
      for (int j = 0; j < 8; ++j) acc[j] = fmaf(l, bf2f(wu.s[j]), acc[j]);
    }
    float* pp = &partbuf[kg * 128 + c0];
    #pragma unroll
    for (int j = 0; j < 8; ++j) pp[j] = acc[j];
  }
  __syncthreads();
  if (tid < 128) {
    float s = 0.f;
    #pragma unroll
    for (int g = 0; g < 16; ++g) s += partbuf[g * 128 + tid];
    llv[tid] = fmaxf(s, 0.f);
  }
  __syncthreads();

  // ---- H: gx2 = llv @ W2_ih^T + b2. 192 cg(8) x 4 kg(32) ----
  if (tid < 768) {
    int cg = tid % 192, kg = tid / 192;
    int c0 = cg * 8;
    const unsigned short* w = iht2b + (size_t)(kg * 32) * kG + c0;
    float acc[8] = {};
    #pragma unroll 4
    for (int k = 0; k < 32; ++k) {
      union { uint4 u; unsigned short s[8]; } wu;
      wu.u = *(const uint4*)(w + (size_t)k * kG);
      float l = llv[kg * 32 + k];
      #pragma unroll
      for (int j = 0; j < 8; ++j) acc[j] = fmaf(l, bf2f(wu.s[j]), acc[j]);
    }
    float* pp = &partbuf[kg * 1536 + c0];
    #pragma unroll
    for (int j = 0; j < 8; ++j) pp[j] = acc[j];
  }
  __syncthreads();
  for (int c = tid; c < kG; c += 1024) {
    float s = b2_ih[c];
    #pragma unroll
    for (int g = 0; g < 4; ++g) s += partbuf[g * 1536 + c];
    gx2l[c] = s;
  }
  __syncthreads();
  if (tid < 512) {
    int c = tid;
    float ghr = gh2[(size_t)b * kG + c] + gh2[GPART + (size_t)b * kG + c];
    float ghz = gh2[(size_t)b * kG + 512 + c] + gh2[GPART + (size_t)b * kG + 512 + c];
    float ghn = gh2[(size_t)b * kG + 1024 + c] + gh2[GPART + (size_t)b * kG + 1024 + c];
    float rr = fsigm(gx2l[c] + ghr);
    float zz = fsigm(gx2l[512 + c] + ghz);
    float nn = ftanh(gx2l[1024 + c] + rr * ghn);
    float ho = h2[(size_t)b * kH + c];
    float hn = (1.f - zz) * nn + zz * ho;
    h2[(size_t)b * kH + c] = hn;
    h2p[c] = hn;
    unsigned short hb = f2bf(hn);
    unsigned short lb = f2bf(hn - bf2f(hb));
    h2h[(size_t)b * kH + c] = hb;
    h2l[(size_t)b * kH + c] = lb;
    size_t o = ((size_t)t * kB + b) * kH + c;
    h2all_h[o] = hb;
    h2all_l[o] = lb;
  }
  __syncthreads();

  // ---- I: next step's s-chain + gx1 ----
  if (t + 1 < kNS) {
    // I1: s1 = tanh(xw[t+1] + h2'@W_td1^T), 16 cg x 32 kg (k=16)
    if (tid < 512) {
      int cg = tid & 15, kg = tid >> 4;
      int c0 = cg * 8;
      const unsigned short* w = td1bt + (size_t)(kg * 16) * kC + c0;
      float acc[8] = {};
      for (int k = 0; k < 16; ++k) {
        union { uint4 u; unsigned short s[8]; } wu;
        wu.u = *(const uint4*)(w + (size_t)k * kC);
        float h = h2p[kg * 16 + k];
        #pragma unroll
        for (int j = 0; j < 8; ++j) acc[j] = fmaf(h, bf2f(wu.s[j]), acc[j]);
      }
      float* pp = &partbuf[kg * 128 + c0];
      #pragma unroll
      for (int j = 0; j < 8; ++j) pp[j] = acc[j];
    }
    __syncthreads();
    if (tid < 128) {
      float s = xw[((size_t)(t + 1) * kB + b) * kC + tid];
      #pragma unroll
      for (int g = 0; g < 32; ++g) s += partbuf[g * 128 + tid];
      s1l[tid] = ftanh(s);
    }
    __syncthreads();
    // I2: s2 = relu(s1 @ W_td^T), 16 cg x 16 kg (k=8)
    if (tid < 256) {
      int cg = tid & 15, kg = tid >> 4;
      int c0 = cg * 8;
      const unsigned short* w = tdbt + (size_t)(kg * 8) * kC + c0;
      float acc[8] = {};
      for (int k = 0; k < 8; ++k) {
        union { uint4 u; unsigned short s[8]; } wu;
        wu.u = *(const uint4*)(w + (size_t)k * kC);
        float sv = s1l[kg * 8 + k];
        #pragma unroll
        for (int j = 0; j < 8; ++j) acc[j] = fmaf(sv, bf2f(wu.s[j]), acc[j]);
      }
      float* pp = &partbuf[kg * 128 + c0];
      #pragma unroll
      for (int j = 0; j < 8; ++j) pp[j] = acc[j];
    }
    __syncthreads();
    if (tid < 128) {
      float s = 0.f;
      #pragma unroll
      for (int g = 0; g < 16; ++g) s += partbuf[g * 128 + tid];
      s2l[tid] = fmaxf(s, 0.f);
    }
    __syncthreads();
    // I3: gx1(t+1) = s2 @ W1_ih^T + b1. 192 cg(8) x 4 kg(32)
    if (tid < 768) {
      int cg = tid % 192, kg = tid / 192;
      int c0 = cg * 8;
      const unsigned short* w = iht1b + (size_t)(kg * 32) * kG + c0;
      float acc[8] = {};
      #pragma unroll 4
      for (int k = 0; k < 32; ++k) {
        union { uint4 u; unsigned short s[8]; } wu;
        wu.u = *(const uint4*)(w + (size_t)k * kG);
        float sv = s2l[kg * 32 + k];
        #pragma unroll
        for (int j = 0; j < 8; ++j) acc[j] = fmaf(sv, bf2f(wu.s[j]), acc[j]);
      }
      float* pp = &partbuf[kg * 1536 + c0];
      #pragma unroll
      for (int j = 0; j < 8; ++j) pp[j] = acc[j];
    }
    __syncthreads();
    for (int c = tid; c < kG; c += 1024) {
      float s = b1_ih[c];
      #pragma unroll
      for (int g = 0; g < 4; ++g) s += partbuf[g * 1536 + c];
      gx1[(size_t)b * kG + c] = s;
    }
  }
}

// ---------------- mask transpose via LDS: [t][b][p] -> out[b][p][t] ----------
__global__ __launch_bounds__(256) void k_atrans(
    const float* __restrict__ mws, float* __restrict__ attn_out) {
  __shared__ float tile[256][33];   // +1 pad: bank = (pair+t)%32
  int pair0 = blockIdx.x * 256;     // 256 blocks cover 65536 (b,p) pairs
  int tid = threadIdx.x;
  #pragma unroll
  for (int t = 0; t < kNS; ++t)
    tile[tid][t] = mws[(size_t)t * (kB * kP) + pair0 + tid];
  __syncthreads();
  float* outb = attn_out + (size_t)pair0 * kNS;
  #pragma unroll
  for (int i = 0; i < kNS; ++i) {
    int g = i * 256 + tid;           // 0..7935 contiguous output floats
    int pr = g / 31, tt = g - pr * 31;
    outb[g] = tile[pr][tt];
  }
}

// ---------------- classifier: lang = h2_all @ W_cls^T + b_cls (MFMA, LDS) ----
__global__ __launch_bounds__(256) void k_cls(
    const unsigned short* __restrict__ Ah, const unsigned short* __restrict__ Al,
    const unsigned short* __restrict__ Wh, const unsigned short* __restrict__ Wl,
    const float* __restrict__ bc, float* __restrict__ out) {
  __shared__ __align__(16) unsigned short sAh[128 * kLdsStride];
  __shared__ __align__(16) unsigned short sAl[128 * kLdsStride];
  __shared__ __align__(16) unsigned short sBh[128 * kLdsStride];
  __shared__ __align__(16) unsigned short sBl[128 * kLdsStride];
  int m0 = blockIdx.x * 128, n0 = blockIdx.y * 128;
  f32x4 acc[4][4];
  #pragma unroll
  for (int i = 0; i < 4; ++i)
    #pragma unroll
    for (int j = 0; j < 4; ++j) acc[i][j] = (f32x4){0.f, 0.f, 0.f, 0.f};
  mm_tile_lds(Ah, Al, Wh, Wl, m0, n0, kH, 0, kH, kV - 1, acc,
              sAh, sAl, sBh, sBl);
  int lane = threadIdx.x & 63, wid = threadIdx.x >> 6;
  int wm = (wid >> 1) * 64, wn = (wid & 1) * 64;
  int r16 = lane & 15, kq = lane >> 4;
  #pragma unroll
  for (int i = 0; i < 4; ++i)
    #pragma unroll
    for (int j = 0; j < 4; ++j)
      #pragma unroll
      for (int r = 0; r < 4; ++r) {
        int m = m0 + wm + i * 16 + kq * 4 + r;
        int n = n0 + wn + j * 16 + r16;
        if (n < kV) {
          int tt = m >> 8, b = m & 255;
          out[(size_t)b * (kNS * kV) + (size_t)tt * kV + n] = acc[i][j][r] + bc[n];
        }
      }
}

}  // namespace

extern "C" void kernel_launch(void* const* d_in, const int* in_sizes, int n_in,
                              void* d_out, int out_size, void* d_ws,
                              size_t ws_size, hipStream_t stream) {
  (void)in_sizes; (void)n_in; (void)out_size; (void)ws_size;
  const float* word_embs = (const float*)d_in[0];
  const float* t_feat    = (const float*)d_in[1];
  const float* c_feats   = (const float*)d_in[2];
  const float* W_td1 = (const float*)d_in[4];
  const float* W_td2 = (const float*)d_in[5];
  const float* W_td3 = (const float*)d_in[6];
  const float* W_td  = (const float*)d_in[7];
  const float* W1_ih = (const float*)d_in[8];
  const float* W1_hh = (const float*)d_in[9];
  const float* b1_ih = (const float*)d_in[10];
  const float* b1_hh = (const float*)d_in[11];
  const float* W_feat = (const float*)d_in[12];
  const float* W_hidd = (const float*)d_in[13];
  const float* W_att  = (const float*)d_in[14];
  const float* W_l1 = (const float*)d_in[15];
  const float* W_l2 = (const float*)d_in[16];
  const float* W_l  = (const float*)d_in[17];
  const float* W2_ih = (const float*)d_in[18];
  const float* W2_hh = (const float*)d_in[19];
  const float* b2_ih = (const float*)d_in[20];
  const float* b2_hh = (const float*)d_in[21];
  const float* W_cls = (const float*)d_in[22];
  const float* b_cls = (const float*)d_in[23];

  float* lang = (float*)d_out;
  float* attn_out = lang + (size_t)kB * kNS * kV;
  // feat_proj (bf16, 64MB) lives in the lang_cap region of d_out — dead by
  // the time k_cls (the only writer of lang_cap) runs.
  unsigned short* fp = (unsigned short*)d_out;

  float* p = (float*)d_ws;
  float* h1 = p;      p += kB * kH;
  float* h2 = p;      p += kB * kH;
  float* td = p;      p += kB * kC;
  float* gx1 = p;     p += (size_t)kB * kG;
  float* gh1 = p;     p += (size_t)2 * kB * kG;   // 2 K-split partials
  float* gh2 = p;     p += (size_t)2 * kB * kG;
  float* mask_ws = p; p += (size_t)kNS * kB * kP;
  float* xw = p;      p += (size_t)kNS * kB * kC;
  float* td3t = p;    p += kE * 128;
  float* td1t = p;    p += kH * 128;
  float* tdt  = p;    p += 128 * 128;
  float* l1t  = p;    p += 128 * 128;
  float* l2t  = p;    p += kH * 128;
  float* lt   = p;    p += 128 * 128;
  float* iht1 = p;    p += 128 * kG;
  float* iht2 = p;    p += 128 * kG;
  float* whd_t = p;   p += kH * kH;

  unsigned short* u = (unsigned short*)p;
  unsigned short* h1h = u;     u += kB * kH;
  unsigned short* h1l = u;     u += kB * kH;
  unsigned short* h2h = u;     u += kB * kH;
  unsigned short* h2l = u;     u += kB * kH;
  unsigned short* w1hh_h = u;  u += (size_t)kG * kH;
  unsigned short* w1hh_l = u;  u += (size_t)kG * kH;
  unsigned short* w2hh_h = u;  u += (size_t)kG * kH;
  unsigned short* w2hh_l = u;  u += (size_t)kG * kH;
  unsigned short* wc_h = u;    u += (size_t)kV * kH;
  unsigned short* wc_l = u;    u += (size_t)kV * kH;
  unsigned short* wf_h = u;    u += (size_t)kH * kC;
  unsigned short* wf_l = u;    u += (size_t)kH * kC;
  unsigned short* h2all_h = u; u += (size_t)kNS * kB * kH;
  unsigned short* h2all_l = u; u += (size_t)kNS * kB * kH;
  unsigned short* l1bt = u;    u += kC * kC;
  unsigned short* l2bt = u;    u += (size_t)kH * kC;
  unsigned short* lbt = u;     u += kC * kC;
  unsigned short* iht2b = u;   u += (size_t)kC * kG;
  unsigned short* whdbT = u;   u += (size_t)kH * kH;
  unsigned short* td1bt = u;   u += (size_t)kH * kC;
  unsigned short* tdbt = u;    u += kC * kC;
  unsigned short* iht1b = u;   u += (size_t)kC * kG;

  k_transpose<<<dim3(64, 9), 256, 0, stream>>>(
      W_td3, W_td1, W_td, W_l1, W_l2, W_l, W1_ih, W2_ih, W_hidd,
      td3t, td1t, tdt, l1t, l2t, lt, iht1, iht2, whd_t);
  k_tobf16<<<dim3(96, 8), 256, 0, stream>>>(
      l1t, l2t, lt, iht2, whd_t, td1t, tdt, iht1,
      l1bt, l2bt, lbt, iht2b, whdbT, td1bt, tdbt, iht1b);
  k_split<<<dim3(256, 4), 256, 0, stream>>>(
      W1_hh, W2_hh, W_cls, W_feat,
      w1hh_h, w1hh_l, w2hh_h, w2hh_l, wc_h, wc_l, wf_h, wf_l);
  k_init<<<128, 256, 0, stream>>>(t_feat, W_td2, td, h1, h2,
                                  h1h, h1l, h2h, h2l);
  k_featproj<<<dim3(512, 4), 256, 0, stream>>>(c_feats, wf_h, wf_l, fp);
  k_xw<<<dim3(64, kNS), 256, 0, stream>>>(word_embs, td3t, td, xw);
  k_prestep<<<256, 256, 0, stream>>>(xw, tdbt, iht1b, b1_ih, gx1);

  for (int t = 0; t < kNS; ++t) {
    k_gh<<<96, 256, 0, stream>>>(h1h, h1l, h2h, h2l,
                                 w1hh_h, w1hh_l, w2hh_h, w2hh_l,
                                 b1_hh, b2_hh, gh1, gh2);
    k_step2<<<256, 1024, 0, stream>>>(gx1, gh1, gh2, h1, h2,
                                      h1h, h1l, h2h, h2l, whdbT, W_att, fp,
                                      c_feats, l1bt, l2bt, lbt, iht2b, b2_ih,
                                      td1bt, tdbt, iht1b, b1_ih, xw,
                                      h2all_h, h2all_l, mask_ws, t);
  }
  k_atrans<<<256, 256, 0, stream>>>(mask_ws, attn_out);
  k_cls<<<dim3(62, 27), 256, 0, stream>>>(h2all_h, h2all_l, wc_h, wc_l,
                                          b_cls, lang);
}

// Round 9
// 2224.421 us; speedup vs baseline: 18.3241x; 1.0014x over previous
//
#include <hip/hip_runtime.h>
#include <hip/hip_bf16.h>

namespace {

constexpr int kB  = 256;   // batch
constexpr int kP  = 256;   // proposals
constexpr int kT  = 32;    // words
constexpr int kNS = 31;    // steps = T-1
constexpr int kV  = 3433;  // vocab
constexpr int kH  = 512;   // hidden
constexpr int kE  = 300;   // embed
constexpr int kC  = 128;   // feat dim
constexpr int kG  = 1536;  // 3H
constexpr int kLdsStride = 40;   // shorts per LDS tile row (80B: 2-way max)

typedef __bf16 bf16x8 __attribute__((ext_vector_type(8)));
typedef float f32x4 __attribute__((ext_vector_type(4)));

__device__ __forceinline__ float fexp2(float x) {
  float r; asm("v_exp_f32 %0, %1" : "=v"(r) : "v"(x)); return r;
}
__device__ __forceinline__ float frcp(float x) {
  float r; asm("v_rcp_f32 %0, %1" : "=v"(r) : "v"(x)); return r;
}
__device__ __forceinline__ float ftanh(float x) {
  float e = fexp2(x * 2.8853900817779268f);   // e^(2x)
  return 1.0f - 2.0f * frcp(e + 1.0f);
}
__device__ __forceinline__ float fsigm(float x) {
  return frcp(1.0f + fexp2(x * -1.4426950408889634f));
}
__device__ __forceinline__ unsigned short f2bf(float f) {   // RNE bf16
  unsigned u = __float_as_uint(f);
  u += 0x7FFFu + ((u >> 16) & 1u);
  return (unsigned short)(u >> 16);
}
__device__ __forceinline__ float bf2f(unsigned short s) {
  return __uint_as_float((unsigned)s << 16);
}
__device__ __forceinline__ bf16x8 bload(const unsigned short* p) {
  union { uint4 u; bf16x8 v; } x;
  x.u = *(const uint4*)p;
  return x.v;
}

// ---------------- one-time weight transposes (W[r][k] -> Wt[k*R + r]) -------
__global__ void k_transpose(const float* s0, const float* s1, const float* s2,
                            const float* s3, const float* s4, const float* s5,
                            const float* s6, const float* s7, const float* s8,
                            float* d0, float* d1, float* d2, float* d3,
                            float* d4, float* d5, float* d6, float* d7,
                            float* d8) {
  const float* src; float* dst; int R, Cd;
  switch (blockIdx.y) {
    case 0:  src = s0; dst = d0; R = 128;  Cd = 300; break;  // W_td3
    case 1:  src = s1; dst = d1; R = 128;  Cd = 512; break;  // W_td1
    case 2:  src = s2; dst = d2; R = 128;  Cd = 128; break;  // W_td
    case 3:  src = s3; dst = d3; R = 128;  Cd = 128; break;  // W_l1
    case 4:  src = s4; dst = d4; R = 128;  Cd = 512; break;  // W_l2
    case 5:  src = s5; dst = d5; R = 128;  Cd = 128; break;  // W_l
    case 6:  src = s6; dst = d6; R = 1536; Cd = 128; break;  // W1_ih
    case 7:  src = s7; dst = d7; R = 1536; Cd = 128; break;  // W2_ih
    default: src = s8; dst = d8; R = 512;  Cd = 512; break;  // W_hidd
  }
  int n = R * Cd;
  for (int i = blockIdx.x * blockDim.x + threadIdx.x; i < n;
       i += gridDim.x * blockDim.x) {
    int k = i / R, r = i - k * R;
    dst[i] = src[r * Cd + k];    // dst[k*R + r]
  }
}

// ---------------- bf16 copies of the loop-local transposed weights -----------
__global__ void k_tobf16(const float* s0, const float* s1, const float* s2,
                         const float* s3, const float* s4, const float* s5,
                         const float* s6, const float* s7,
                         unsigned short* d0, unsigned short* d1,
                         unsigned short* d2, unsigned short* d3,
                         unsigned short* d4, unsigned short* d5,
                         unsigned short* d6, unsigned short* d7) {
  const float* s; unsigned short* d; int n;
  switch (blockIdx.y) {
    case 0:  s = s0; d = d0; n = kC * kC; break;   // l1t
    case 1:  s = s1; d = d1; n = kH * kC; break;   // l2t
    case 2:  s = s2; d = d2; n = kC * kC; break;   // lt
    case 3:  s = s3; d = d3; n = kC * kG; break;   // iht2
    case 4:  s = s4; d = d4; n = kH * kH; break;   // whd_t
    case 5:  s = s5; d = d5; n = kH * kC; break;   // td1t
    case 6:  s = s6; d = d6; n = kC * kC; break;   // tdt
    default: s = s7; d = d7; n = kC * kG; break;   // iht1
  }
  for (int i = blockIdx.x * blockDim.x + threadIdx.x; i < n;
       i += gridDim.x * blockDim.x)
    d[i] = f2bf(s[i]);
}

// ---------------- one-time weight hi/lo bf16 splits --------------------------
__global__ void k_split(const float* s0, const float* s1, const float* s2,
                        const float* s3,
                        unsigned short* h0, unsigned short* l0,
                        unsigned short* h1, unsigned short* l1,
                        unsigned short* h2, unsigned short* l2,
                        unsigned short* h3, unsigned short* l3) {
  const float* s; unsigned short* h; unsigned short* l; int n;
  switch (blockIdx.y) {
    case 0:  s = s0; h = h0; l = l0; n = kG * kH; break;   // W1_hh
    case 1:  s = s1; h = h1; l = l1; n = kG * kH; break;   // W2_hh
    case 2:  s = s2; h = h2; l = l2; n = kV * kH; break;   // W_cls
    default: s = s3; h = h3; l = l3; n = kH * kC; break;   // W_feat
  }
  for (int i = blockIdx.x * blockDim.x + threadIdx.x; i < n;
       i += gridDim.x * blockDim.x) {
    float v = s[i];
    unsigned short hb = f2bf(v);
    h[i] = hb;
    l[i] = f2bf(v - bf2f(hb));
  }
}

// ---------------- init: td = t_feat @ W_td2^T ; zero h states ----------------
__global__ void k_init(const float* __restrict__ t_feat,
                       const float* __restrict__ W_td2,
                       float* __restrict__ td, float* __restrict__ h1,
                       float* __restrict__ h2,
                       unsigned short* __restrict__ h1h,
                       unsigned short* __restrict__ h1l,
                       unsigned short* __restrict__ h2h,
                       unsigned short* __restrict__ h2l) {
  int tid = blockIdx.x * 256 + threadIdx.x;  // 32768 threads
  int b = tid >> 7, c = tid & 127;
  const float* tf = t_feat + b * kC;
  const float* w  = W_td2 + c * kC;
  float acc = 0.f;
  for (int k = 0; k < kC; ++k) acc = fmaf(tf[k], w[k], acc);
  td[tid] = acc;
  for (int i = tid; i < kB * kH; i += (1 << 15)) {
    h1[i] = 0.f; h2[i] = 0.f;
    h1h[i] = 0; h1l[i] = 0; h2h[i] = 0; h2l[i] = 0;
  }
}

// ---------------- xw[t][b][:] = x_t @ W_td3^T + td ---------------------------
__global__ __launch_bounds__(256) void k_xw(
    const float* __restrict__ word_embs, const float* __restrict__ td3t,
    const float* __restrict__ td, float* __restrict__ xw) {
  __shared__ float xl[4 * 300];
  __shared__ float tdl[512];
  int t = blockIdx.y, b0 = blockIdx.x * 4, tid = threadIdx.x;
  #pragma unroll
  for (int r = 0; r < 4; ++r) {
    const float* xs = word_embs + (size_t)(b0 + r) * (kT * kE) + (size_t)t * kE;
    for (int e = tid; e < kE; e += 256) xl[r * kE + e] = xs[e];
  }
  for (int i = tid; i < 512; i += 256) tdl[i] = td[(size_t)b0 * kC + i];
  __syncthreads();
  #pragma unroll
  for (int q = 0; q < 2; ++q) {
    int idx = tid + q * 256;
    int r = idx >> 7, c = idx & 127;
    float acc = tdl[idx];
    const float* xr = xl + r * kE;
    const float* w3 = td3t + c;
    for (int e = 0; e < kE; ++e) acc = fmaf(xr[e], w3[(size_t)e * 128], acc);
    xw[((size_t)t * kB + b0 + r) * kC + c] = acc;
  }
}

// ---------------- prestep: s(0), gx1(0) from xw[0] (h2 = 0) ------------------
__global__ __launch_bounds__(256) void k_prestep(
    const float* __restrict__ xw, const unsigned short* __restrict__ tdbt,
    const unsigned short* __restrict__ iht1b, const float* __restrict__ b1_ih,
    float* __restrict__ gx1) {
  __shared__ float s1l[128];
  __shared__ float s2l[128];
  __shared__ float part[256];
  int b = blockIdx.x, tid = threadIdx.x;
  if (tid < 128) s1l[tid] = ftanh(xw[(size_t)b * kC + tid]);
  __syncthreads();
  {
    int c = tid & 127, g = tid >> 7;
    float s = 0.f;
    const unsigned short* w = tdbt + (size_t)(g * 64) * kC + c;
    for (int k = 0; k < 64; ++k)
      s = fmaf(s1l[g * 64 + k], bf2f(w[(size_t)k * kC]), s);
    part[g * 128 + c] = s;
  }
  __syncthreads();
  if (tid < 128) s2l[tid] = fmaxf(part[tid] + part[128 + tid], 0.f);
  __syncthreads();
  #pragma unroll
  for (int q = 0; q < 6; ++q) {
    int j = q * 256 + tid;
    float acc = b1_ih[j];
    const unsigned short* w = iht1b + j;
    for (int k = 0; k < kC; ++k)
      acc = fmaf(s2l[k], bf2f(w[(size_t)k * kG]), acc);
    gx1[(size_t)b * kG + j] = acc;
  }
}

// ---------------- LDS-staged split-bf16 MFMA 128x128 tile (3-term) -----------
// 256 threads. Stages Ah/Al/Bh/Bl 128x32 bf16 tiles in LDS (stride 40 shorts:
// rows map to 8 distinct bank quads -> max 2-way conflict, which is free).
__device__ __forceinline__ void mm_tile_lds(
    const unsigned short* __restrict__ Ah, const unsigned short* __restrict__ Al,
    const unsigned short* __restrict__ Bh, const unsigned short* __restrict__ Bl,
    int m0, int n0, int K, int kbeg, int kend, int nMax, f32x4 acc[4][4],
    unsigned short* sAh, unsigned short* sAl,
    unsigned short* sBh, unsigned short* sBl) {
  int tid = threadIdx.x;
  int lane = tid & 63, wid = tid >> 6;
  int wm = (wid >> 1) * 64, wn = (wid & 1) * 64;
  int r16 = lane & 15, kq = lane >> 4;
  int rA = tid >> 2, cA = (tid & 3) * 8;   // rows rA and rA+64, col-chunk cA
  int brow0 = n0 + rA;       if (brow0 > nMax) brow0 = nMax;
  int brow1 = n0 + rA + 64;  if (brow1 > nMax) brow1 = nMax;
  for (int k0 = kbeg; k0 < kend; k0 += 32) {
    uint4 va0 = *(const uint4*)(Ah + (size_t)(m0 + rA) * K + k0 + cA);
    uint4 va1 = *(const uint4*)(Ah + (size_t)(m0 + rA + 64) * K + k0 + cA);
    uint4 vb0 = *(const uint4*)(Al + (size_t)(m0 + rA) * K + k0 + cA);
    uint4 vb1 = *(const uint4*)(Al + (size_t)(m0 + rA + 64) * K + k0 + cA);
    uint4 vc0 = *(const uint4*)(Bh + (size_t)brow0 * K + k0 + cA);
    uint4 vc1 = *(const uint4*)(Bh + (size_t)brow1 * K + k0 + cA);
    uint4 vd0 = *(const uint4*)(Bl + (size_t)brow0 * K + k0 + cA);
    uint4 vd1 = *(const uint4*)(Bl + (size_t)brow1 * K + k0 + cA);
    __syncthreads();   // previous chunk's reads complete
    *(uint4*)&sAh[rA * kLdsStride + cA] = va0;
    *(uint4*)&sAh[(rA + 64) * kLdsStride + cA] = va1;
    *(uint4*)&sAl[rA * kLdsStride + cA] = vb0;
    *(uint4*)&sAl[(rA + 64) * kLdsStride + cA] = vb1;
    *(uint4*)&sBh[rA * kLdsStride + cA] = vc0;
    *(uint4*)&sBh[(rA + 64) * kLdsStride + cA] = vc1;
    *(uint4*)&sBl[rA * kLdsStride + cA] = vd0;
    *(uint4*)&sBl[(rA + 64) * kLdsStride + cA] = vd1;
    __syncthreads();
    bf16x8 ah[4], al[4], bh[4], bl[4];
    #pragma unroll
    for (int i = 0; i < 4; ++i) {
      int ar = (wm + i * 16 + r16) * kLdsStride + kq * 8;
      int br = (wn + i * 16 + r16) * kLdsStride + kq * 8;
      ah[i] = *(const bf16x8*)&sAh[ar];
      al[i] = *(const bf16x8*)&sAl[ar];
      bh[i] = *(const bf16x8*)&sBh[br];
      bl[i] = *(const bf16x8*)&sBl[br];
    }
    #pragma unroll
    for (int i = 0; i < 4; ++i)
      #pragma unroll
      for (int j = 0; j < 4; ++j) {
        acc[i][j] = __builtin_amdgcn_mfma_f32_16x16x32_bf16(ah[i], bh[j], acc[i][j], 0, 0, 0);
        acc[i][j] = __builtin_amdgcn_mfma_f32_16x16x32_bf16(ah[i], bl[j], acc[i][j], 0, 0, 0);
        acc[i][j] = __builtin_amdgcn_mfma_f32_16x16x32_bf16(al[i], bh[j], acc[i][j], 0, 0, 0);
      }
  }
}

// ---------------- feat_proj = c_feats @ W_feat^T -> bf16 (MFMA) --------------
__global__ __launch_bounds__(256) void k_featproj(
    const float* __restrict__ A, const unsigned short* __restrict__ Wh,
    const unsigned short* __restrict__ Wl, unsigned short* __restrict__ out) {
  int lane = threadIdx.x & 63, wid = threadIdx.x >> 6;
  int wm = (wid >> 1) * 64, wn = (wid & 1) * 64;
  int r16 = lane & 15, kq = lane >> 4;
  int m0 = blockIdx.x * 128, n0 = blockIdx.y * 128;
  f32x4 acc[4][4];
  #pragma unroll
  for (int i = 0; i < 4; ++i)
    #pragma unroll
    for (int j = 0; j < 4; ++j) acc[i][j] = (f32x4){0.f, 0.f, 0.f, 0.f};
  for (int k0 = 0; k0 < kC; k0 += 32) {
    int kk = k0 + kq * 8;
    bf16x8 ah[4], al[4], bh[4], bl[4];
    #pragma unroll
    for (int i = 0; i < 4; ++i) {
      const float* pa = A + (size_t)(m0 + wm + i * 16 + r16) * kC + kk;
      float4 v0 = *(const float4*)pa;
      float4 v1 = *(const float4*)(pa + 4);
      float vv[8] = {v0.x, v0.y, v0.z, v0.w, v1.x, v1.y, v1.z, v1.w};
      union { unsigned short s[8]; bf16x8 v; } uh, ul;
      #pragma unroll
      for (int q = 0; q < 8; ++q) {
        unsigned short hb = f2bf(vv[q]);
        uh.s[q] = hb;
        ul.s[q] = f2bf(vv[q] - bf2f(hb));
      }
      ah[i] = uh.v; al[i] = ul.v;
      const unsigned short* pb = Wh + (size_t)(n0 + wn + i * 16 + r16) * kC + kk;
      const unsigned short* pl = Wl + (size_t)(n0 + wn + i * 16 + r16) * kC + kk;
      bh[i] = bload(pb); bl[i] = bload(pl);
    }
    #pragma unroll
    for (int i = 0; i < 4; ++i)
      #pragma unroll
      for (int j = 0; j < 4; ++j) {
        acc[i][j] = __builtin_amdgcn_mfma_f32_16x16x32_bf16(ah[i], bh[j], acc[i][j], 0, 0, 0);
        acc[i][j] = __builtin_amdgcn_mfma_f32_16x16x32_bf16(ah[i], bl[j], acc[i][j], 0, 0, 0);
        acc[i][j] = __builtin_amdgcn_mfma_f32_16x16x32_bf16(al[i], bh[j], acc[i][j], 0, 0, 0);
      }
  }
  #pragma unroll
  for (int i = 0; i < 4; ++i)
    #pragma unroll
    for (int j = 0; j < 4; ++j)
      #pragma unroll
      for (int r = 0; r < 4; ++r) {
        int m = m0 + wm + i * 16 + kq * 4 + r;
        int n = n0 + wn + j * 16 + r16;
        out[(size_t)m * kH + n] = f2bf(acc[i][j][r]);
      }
}

// ---------------- per-step kernel 1: gh1/gh2 MFMA, K-split x2 (96 blocks) ----
// Block g2: g = g2>>1 selects (gru, m-tile, n-tile); half = g2&1 selects
// K in [half*256, half*256+256). Output goes to partial buffer `half`;
// bias added only in half 0. step2 phases A/H sum both partials.
__global__ __launch_bounds__(256) void k_gh(
    const unsigned short* __restrict__ h1h, const unsigned short* __restrict__ h1l,
    const unsigned short* __restrict__ h2h, const unsigned short* __restrict__ h2l,
    const unsigned short* __restrict__ w1hh_h, const unsigned short* __restrict__ w1hh_l,
    const unsigned short* __restrict__ w2hh_h, const unsigned short* __restrict__ w2hh_l,
    const float* __restrict__ b1_hh, const float* __restrict__ b2_hh,
    float* __restrict__ gh1, float* __restrict__ gh2) {
  __shared__ __align__(16) unsigned short sAh[128 * kLdsStride];
  __shared__ __align__(16) unsigned short sAl[128 * kLdsStride];
  __shared__ __align__(16) unsigned short sBh[128 * kLdsStride];
  __shared__ __align__(16) unsigned short sBl[128 * kLdsStride];
  int g2 = blockIdx.x;          // 0..95
  int half = g2 & 1, g = g2 >> 1;   // g 0..47
  const unsigned short *Ah, *Al, *Wh, *Wl; const float* bias; float* out;
  if (g < 24) { Ah = h1h; Al = h1l; Wh = w1hh_h; Wl = w1hh_l;
                bias = b1_hh; out = gh1; }
  else { g -= 24; Ah = h2h; Al = h2l; Wh = w2hh_h; Wl = w2hh_l;
         bias = b2_hh; out = gh2; }
  out += (size_t)half * (kB * kG);
  int m0 = (g / 12) * 128, n0 = (g % 12) * 128;
  f32x4 acc[4][4];
  #pragma unroll
  for (int i = 0; i < 4; ++i)
    #pragma unroll
    for (int j = 0; j < 4; ++j) acc[i][j] = (f32x4){0.f, 0.f, 0.f, 0.f};
  mm_tile_lds(Ah, Al, Wh, Wl, m0, n0, kH, half * 256, half * 256 + 256,
              kG - 1, acc, sAh, sAl, sBh, sBl);
  int tid = threadIdx.x;
  int lane = tid & 63, wid = tid >> 6;
  int wm = (wid >> 1) * 64, wn = (wid & 1) * 64;
  int r16 = lane & 15, kq = lane >> 4;
  #pragma unroll
  for (int i = 0; i < 4; ++i)
    #pragma unroll
    for (int j = 0; j < 4; ++j)
      #pragma unroll
      for (int r = 0; r < 4; ++r) {
        int m = m0 + wm + i * 16 + kq * 4 + r;
        int n = n0 + wn + j * 16 + r16;
        float v = acc[i][j][r];
        if (half == 0) v += bias[n];
        out[(size_t)m * kG + n] = v;
      }
}

// ---------------- per-step kernel 2: one batch row per block, 1024 threads ---
__global__ __launch_bounds__(1024, 4) void k_step2(
    float* __restrict__ gx1, const float* __restrict__ gh1,
    const float* __restrict__ gh2,
    float* __restrict__ h1, float* __restrict__ h2,
    unsigned short* __restrict__ h1h, unsigned short* __restrict__ h1l,
    unsigned short* __restrict__ h2h, unsigned short* __restrict__ h2l,
    const unsigned short* __restrict__ whdbT, const float* __restrict__ W_att,
    const unsigned short* __restrict__ fp, const float* __restrict__ c_feats,
    const unsigned short* __restrict__ l1bt, const unsigned short* __restrict__ l2bt,
    const unsigned short* __restrict__ lbt, const unsigned short* __restrict__ iht2b,
    const float* __restrict__ b2_ih,
    const unsigned short* __restrict__ td1bt, const unsigned short* __restrict__ tdbt,
    const unsigned short* __restrict__ iht1b, const float* __restrict__ b1_ih,
    const float* __restrict__ xw,
    unsigned short* __restrict__ h2all_h, unsigned short* __restrict__ h2all_l,
    float* __restrict__ mask_ws, int t) {
  __shared__ float partbuf[8192];     // 32 KB, reused across phases
  __shared__ float h1p[512];
  __shared__ float h2p[512];
  __shared__ float hqs[512];
  __shared__ float scs[256];
  __shared__ float red[16];
  __shared__ float red2[16];
  __shared__ float attl[128];
  __shared__ float lt1[128];
  __shared__ float llv[128];
  __shared__ float s1l[128];
  __shared__ float s2l[128];
  __shared__ float gx2l[1536];
  const int b = blockIdx.x;
  const int tid = threadIdx.x;
  const int lane = tid & 63, wv = tid >> 6;   // 16 waves
  const size_t GPART = (size_t)kB * kG;       // gh k-split partial offset

  // ---- A: GRU1 combine -> h1' ----
  if (tid < 512) {
    int c = tid;
    float gr = gx1[(size_t)b * kG + c];
    float gz = gx1[(size_t)b * kG + 512 + c];
    float gn = gx1[(size_t)b * kG + 1024 + c];
    float hr = gh1[(size_t)b * kG + c] + gh1[GPART + (size_t)b * kG + c];
    float hz = gh1[(size_t)b * kG + 512 + c] + gh1[GPART + (size_t)b * kG + 512 + c];
    float hnv = gh1[(size_t)b * kG + 1024 + c] + gh1[GPART + (size_t)b * kG + 1024 + c];
    float rr = fsigm(gr + hr);
    float zz = fsigm(gz + hz);
    float nn = ftanh(gn + rr * hnv);
    float ho = h1[(size_t)b * kH + c];
    float hn = (1.f - zz) * nn + zz * ho;
    h1[(size_t)b * kH + c] = hn;
    h1p[c] = hn;
    unsigned short hb = f2bf(hn);
    h1h[(size_t)b * kH + c] = hb;
    h1l[(size_t)b * kH + c] = f2bf(hn - bf2f(hb));
  }
  __syncthreads();

  // ---- B: hq = h1' @ W_hidd^T. 64 col-groups(8) x 16 k-groups(32) ----
  {
    int cg = tid & 63, kg = tid >> 6;   // kg 0..15
    int c0 = cg * 8;
    const unsigned short* w = whdbT + (size_t)(kg * 32) * kH + c0;
    float acc[8] = {};
    #pragma unroll 4
    for (int k = 0; k < 32; ++k) {
      union { uint4 u; unsigned short s[8]; } wu;
      wu.u = *(const uint4*)(w + (size_t)k * kH);
      float h = h1p[kg * 32 + k];
      #pragma unroll
      for (int j = 0; j < 8; ++j) acc[j] = fmaf(h, bf2f(wu.s[j]), acc[j]);
    }
    float* pp = &partbuf[kg * 512 + c0];
    #pragma unroll
    for (int j = 0; j < 8; ++j) pp[j] = acc[j];
  }
  __syncthreads();
  if (tid < 512) {
    float s = 0.f;
    #pragma unroll
    for (int g = 0; g < 16; ++g) s += partbuf[g * 512 + tid];
    hqs[tid] = s;
  }
  __syncthreads();

  // ---- C: attention scores (exp-tanh), 16 waves x 16 proposals ----
  {
    float hq8[8], aw[8];
    #pragma unroll
    for (int j = 0; j < 8; ++j) hq8[j] = hqs[lane * 8 + j];
    {
      float4 a0 = *(const float4*)(W_att + lane * 8);
      float4 a1 = *(const float4*)(W_att + lane * 8 + 4);
      aw[0] = a0.x; aw[1] = a0.y; aw[2] = a0.z; aw[3] = a0.w;
      aw[4] = a1.x; aw[5] = a1.y; aw[6] = a1.z; aw[7] = a1.w;
    }
    const unsigned short* fpb = fp + (size_t)b * kP * kH;
    int p0 = wv * 16;
    uint4 rv = *(const uint4*)(fpb + (size_t)p0 * kH + lane * 8);
    for (int p = p0; p < p0 + 16; ++p) {
      union { uint4 v; unsigned short s[8]; } u; u.v = rv;
      if (p + 1 < p0 + 16)
        rv = *(const uint4*)(fpb + (size_t)(p + 1) * kH + lane * 8);
      float sc = 0.f;
      #pragma unroll
      for (int j = 0; j < 8; ++j) {
        float f = __uint_as_float((unsigned)u.s[j] << 16);
        sc += aw[j] * ftanh(f + hq8[j]);
      }
      #pragma unroll
      for (int m = 32; m; m >>= 1) sc += __shfl_xor(sc, m, 64);
      if (lane == 0) scs[p] = sc;
    }
  }
  __syncthreads();

  // ---- D: softmax over 256 proposals ----
  {
    float sv = (tid < 256) ? scs[tid] : -1e30f;
    float mx = sv;
    #pragma unroll
    for (int m = 32; m; m >>= 1) mx = fmaxf(mx, __shfl_xor(mx, m, 64));
    if (lane == 0) red[wv] = mx;
    __syncthreads();
    float bm = red[0];
    #pragma unroll
    for (int i = 1; i < 16; ++i) bm = fmaxf(bm, red[i]);
    float ev = (tid < 256) ? fexp2((sv - bm) * 1.4426950408889634f) : 0.f;
    float sm = ev;
    #pragma unroll
    for (int m = 32; m; m >>= 1) sm += __shfl_xor(sm, m, 64);
    if (lane == 0) red2[wv] = sm;
    __syncthreads();
    float tot = 0.f;
    #pragma unroll
    for (int i = 0; i < 16; ++i) tot += red2[i];
    if (tid < 256) {
      float mk = ev * frcp(tot);
      scs[tid] = mk;
      mask_ws[(size_t)t * (kB * kP) + (size_t)b * kP + tid] = mk;
    }
  }
  __syncthreads();

  // ---- E: attended = mask @ c_feats, 8 proposal-groups x 32 ----
  {
    int c = tid & 127, q = tid >> 7;
    const float* cf = c_feats + ((size_t)b * kP + q * 32) * kC + c;
    const float* ms = scs + q * 32;
    float acc = 0.f;
    for (int p = 0; p < 32; ++p) acc = fmaf(ms[p], cf[(size_t)p * kC], acc);
    partbuf[q * 128 + c] = acc;
  }
  __syncthreads();
  if (tid < 128) {
    float s = 0.f;
    #pragma unroll
    for (int q = 0; q < 8; ++q) s += partbuf[q * 128 + tid];
    attl[tid] = s;
  }
  __syncthreads();

  // ---- F: lt1 = tanh(att@W_l1^T + h1'@W_l2^T) ----
  {
    if (tid < 512) {
      int cg = tid & 15, kg = tid >> 4;
      int c0 = cg * 8;
      const unsigned short* w = l2bt + (size_t)(kg * 16) * kC + c0;
      float acc[8] = {};
      for (int k = 0; k < 16; ++k) {
        union { uint4 u; unsigned short s[8]; } wu;
        wu.u = *(const uint4*)(w + (size_t)k * kC);
        float h = h1p[kg * 16 + k];
        #pragma unroll
        for (int j = 0; j < 8; ++j) acc[j] = fmaf(h, bf2f(wu.s[j]), acc[j]);
      }
      float* pp = &partbuf[kg * 128 + c0];
      #pragma unroll
      for (int j = 0; j < 8; ++j) pp[j] = acc[j];
    } else if (tid < 768) {
      int tt = tid - 512;
      int cg = tt & 15, kg = tt >> 4;
      int c0 = cg * 8;
      const unsigned short* w = l1bt + (size_t)(kg * 8) * kC + c0;
      float acc[8] = {};
      for (int k = 0; k < 8; ++k) {
        union { uint4 u; unsigned short s[8]; } wu;
        wu.u = *(const uint4*)(w + (size_t)k * kC);
        float a = attl[kg * 8 + k];
        #pragma unroll
        for (int j = 0; j < 8; ++j) acc[j] = fmaf(a, bf2f(wu.s[j]), acc[j]);
      }
      float* pp = &partbuf[4096 + kg * 128 + c0];
      #pragma unroll
      for (int j = 0; j < 8; ++j) pp[j] = acc[j];
    }
  }
  __syncthreads();
  if (tid < 128) {
    float s = 0.f;
    #pragma unroll
    for (int g = 0; g < 32; ++g) s += partbuf[g * 128 + tid];
    #pragma unroll
    for (int g = 0; g < 16; ++g) s += partbuf[4096 + g * 128 + tid];
    lt1[tid] = ftanh(s);
  }
  __syncthreads();

  // ---- G: llv = relu(lt1 @ W_l^T), 16 cg x 16 kg (k=8) ----
  if (tid < 256) {
    int cg = tid & 15, kg = tid >> 4;
    int c0 = cg * 8;
    const unsigned short* w = lbt + (size_t)(kg * 8) * kC + c0;
    float acc[8] = {};
    for (int k = 0; k < 8; ++k) {
      union { uint4 u; unsigned short s[8]; } wu;
      wu.u = *(const uint4*)(w + (size_t)k * kC);
      float l = lt1[kg * 8 + k];
      #pragma unroll
      for (int j = 0; j < 8; ++j) acc[j] = fmaf(l, bf2f(wu.s[j]), acc[j]);
    }
    float* pp = &partbuf[kg * 128 + c0];
    #pragma unroll
    for (int j = 0; j < 8; ++j) pp[j] = acc[j];
  }
  __syncthreads();
  if (tid < 128) {
    float s = 0.f;
    #pragma unroll
    for (int g = 0; g < 16; ++g) s += partbuf[g * 128 + tid];
    llv[tid] = fmaxf(s, 0.f);
  }
  __syncthreads();

  // ---- H: gx2 = llv @ W2_ih^T + b2. 192 cg(8) x 4 kg(32) ----
  if (tid < 768) {
    int cg = tid % 192, kg = tid / 192;
    int c0 = cg * 8;
    const unsigned short* w = iht2b + (size_t)(kg * 32) * kG + c0;
    float acc[8] = {};
    #pragma unroll 4
    for (int k = 0; k < 32; ++k) {
      union { uint4 u; unsigned short s[8]; } wu;
      wu.u = *(const uint4*)(w + (size_t)k * kG);
      float l = llv[kg * 32 + k];
      #pragma unroll
      for (int j = 0; j < 8; ++j) acc[j] = fmaf(l, bf2f(wu.s[j]), acc[j]);
    }
    float* pp = &partbuf[kg * 1536 + c0];
    #pragma unroll
    for (int j = 0; j < 8; ++j) pp[j] = acc[j];
  }
  __syncthreads();
  for (int c = tid; c < kG; c += 1024) {
    float s = b2_ih[c];
    #pragma unroll
    for (int g = 0; g < 4; ++g) s += partbuf[g * 1536 + c];
    gx2l[c] = s;
  }
  __syncthreads();
  if (tid < 512) {
    int c = tid;
    float ghr = gh2[(size_t)b * kG + c] + gh2[GPART + (size_t)b * kG + c];
    float ghz = gh2[(size_t)b * kG + 512 + c] + gh2[GPART + (size_t)b * kG + 512 + c];
    float ghn = gh2[(size_t)b * kG + 1024 + c] + gh2[GPART + (size_t)b * kG + 1024 + c];
    float rr = fsigm(gx2l[c] + ghr);
    float zz = fsigm(gx2l[512 + c] + ghz);
    float nn = ftanh(gx2l[1024 + c] + rr * ghn);
    float ho = h2[(size_t)b * kH + c];
    float hn = (1.f - zz) * nn + zz * ho;
    h2[(size_t)b * kH + c] = hn;
    h2p[c] = hn;
    unsigned short hb = f2bf(hn);
    unsigned short lb = f2bf(hn - bf2f(hb));
    h2h[(size_t)b * kH + c] = hb;
    h2l[(size_t)b * kH + c] = lb;
    size_t o = ((size_t)t * kB + b) * kH + c;
    h2all_h[o] = hb;
    h2all_l[o] = lb;
  }
  __syncthreads();

  // ---- I: next step's s-chain + gx1 ----
  if (t + 1 < kNS) {
    // I1: s1 = tanh(xw[t+1] + h2'@W_td1^T), 16 cg x 32 kg (k=16)
    if (tid < 512) {
      int cg = tid & 15, kg = tid >> 4;
      int c0 = cg * 8;
      const unsigned short* w = td1bt + (size_t)(kg * 16) * kC + c0;
      float acc[8] = {};
      for (int k = 0; k < 16; ++k) {
        union { uint4 u; unsigned short s[8]; } wu;
        wu.u = *(const uint4*)(w + (size_t)k * kC);
        float h = h2p[kg * 16 + k];
        #pragma unroll
        for (int j = 0; j < 8; ++j) acc[j] = fmaf(h, bf2f(wu.s[j]), acc[j]);
      }
      float* pp = &partbuf[kg * 128 + c0];
      #pragma unroll
      for (int j = 0; j < 8; ++j) pp[j] = acc[j];
    }
    __syncthreads();
    if (tid < 128) {
      float s = xw[((size_t)(t + 1) * kB + b) * kC + tid];
      #pragma unroll
      for (int g = 0; g < 32; ++g) s += partbuf[g * 128 + tid];
      s1l[tid] = ftanh(s);
    }
    __syncthreads();
    // I2: s2 = relu(s1 @ W_td^T), 16 cg x 16 kg (k=8)
    if (tid < 256) {
      int cg = tid & 15, kg = tid >> 4;
      int c0 = cg * 8;
      const unsigned short* w = tdbt + (size_t)(kg * 8) * kC + c0;
      float acc[8] = {};
      for (int k = 0; k < 8; ++k) {
        union { uint4 u; unsigned short s[8]; } wu;
        wu.u = *(const uint4*)(w + (size_t)k * kC);
        float sv = s1l[kg * 8 + k];
        #pragma unroll
        for (int j = 0; j < 8; ++j) acc[j] = fmaf(sv, bf2f(wu.s[j]), acc[j]);
      }
      float* pp = &partbuf[kg * 128 + c0];
      #pragma unroll
      for (int j = 0; j < 8; ++j) pp[j] = acc[j];
    }
    __syncthreads();
    if (tid < 128) {
      float s = 0.f;
      #pragma unroll
      for (int g = 0; g < 16; ++g) s += partbuf[g * 128 + tid];
      s2l[tid] = fmaxf(s, 0.f);
    }
    __syncthreads();
    // I3: gx1(t+1) = s2 @ W1_ih^T + b1. 192 cg(8) x 4 kg(32)
    if (tid < 768) {
      int cg = tid % 192, kg = tid / 192;
      int c0 = cg * 8;
      const unsigned short* w = iht1b + (size_t)(kg * 32) * kG + c0;
      float acc[8] = {};
      #pragma unroll 4
      for (int k = 0; k < 32; ++k) {
        union { uint4 u; unsigned short s[8]; } wu;
        wu.u = *(const uint4*)(w + (size_t)k * kG);
        float sv = s2l[kg * 32 + k];
        #pragma unroll
        for (int j = 0; j < 8; ++j) acc[j] = fmaf(sv, bf2f(wu.s[j]), acc[j]);
      }
      float* pp = &partbuf[kg * 1536 + c0];
      #pragma unroll
      for (int j = 0; j < 8; ++j) pp[j] = acc[j];
    }
    __syncthreads();
    for (int c = tid; c < kG; c += 1024) {
      float s = b1_ih[c];
      #pragma unroll
      for (int g = 0; g < 4; ++g) s += partbuf[g * 1536 + c];
      gx1[(size_t)b * kG + c] = s;
    }
  }
}

// ---------------- mask transpose via LDS: [t][b][p] -> out[b][p][t] ----------
__global__ __launch_bounds__(256) void k_atrans(
    const float* __restrict__ mws, float* __restrict__ attn_out) {
  __shared__ float tile[256][33];   // +1 pad: bank = (pair+t)%32
  int pair0 = blockIdx.x * 256;     // 256 blocks cover 65536 (b,p) pairs
  int tid = threadIdx.x;
  #pragma unroll
  for (int t = 0; t < kNS; ++t)
    tile[tid][t] = mws[(size_t)t * (kB * kP) + pair0 + tid];
  __syncthreads();
  float* outb = attn_out + (size_t)pair0 * kNS;
  #pragma unroll
  for (int i = 0; i < kNS; ++i) {
    int g = i * 256 + tid;           // 0..7935 contiguous output floats
    int pr = g / 31, tt = g - pr * 31;
    outb[g] = tile[pr][tt];
  }
}

// ---------------- classifier: lang = h2_all @ W_cls^T + b_cls (MFMA, LDS) ----
__global__ __launch_bounds__(256) void k_cls(
    const unsigned short* __restrict__ Ah, const unsigned short* __restrict__ Al,
    const unsigned short* __restrict__ Wh, const unsigned short* __restrict__ Wl,
    const float* __restrict__ bc, float* __restrict__ out) {
  __shared__ __align__(16) unsigned short sAh[128 * kLdsStride];
  __shared__ __align__(16) unsigned short sAl[128 * kLdsStride];
  __shared__ __align__(16) unsigned short sBh[128 * kLdsStride];
  __shared__ __align__(16) unsigned short sBl[128 * kLdsStride];
  int m0 = blockIdx.x * 128, n0 = blockIdx.y * 128;
  f32x4 acc[4][4];
  #pragma unroll
  for (int i = 0; i < 4; ++i)
    #pragma unroll
    for (int j = 0; j < 4; ++j) acc[i][j] = (f32x4){0.f, 0.f, 0.f, 0.f};
  mm_tile_lds(Ah, Al, Wh, Wl, m0, n0, kH, 0, kH, kV - 1, acc,
              sAh, sAl, sBh, sBl);
  int lane = threadIdx.x & 63, wid = threadIdx.x >> 6;
  int wm = (wid >> 1) * 64, wn = (wid & 1) * 64;
  int r16 = lane & 15, kq = lane >> 4;
  #pragma unroll
  for (int i = 0; i < 4; ++i)
    #pragma unroll
    for (int j = 0; j < 4; ++j)
      #pragma unroll
      for (int r = 0; r < 4; ++r) {
        int m = m0 + wm + i * 16 + kq * 4 + r;
        int n = n0 + wn + j * 16 + r16;
        if (n < kV) {
          int tt = m >> 8, b = m & 255;
          out[(size_t)b * (kNS * kV) + (size_t)tt * kV + n] = acc[i][j][r] + bc[n];
        }
      }
}

}  // namespace

extern "C" void kernel_launch(void* const* d_in, const int* in_sizes, int n_in,
                              void* d_out, int out_size, void* d_ws,
                              size_t ws_size, hipStream_t stream) {
  (void)in_sizes; (void)n_in; (void)out_size; (void)ws_size;
  const float* word_embs = (const float*)d_in[0];
  const float* t_feat    = (const float*)d_in[1];
  const float* c_feats   = (const float*)d_in[2];
  const float* W_td1 = (const float*)d_in[4];
  const float* W_td2 = (const float*)d_in[5];
  const float* W_td3 = (const float*)d_in[6];
  const float* W_td  = (const float*)d_in[7];
  const float* W1_ih = (const float*)d_in[8];
  const float* W1_hh = (const float*)d_in[9];
  const float* b1_ih = (const float*)d_in[10];
  const float* b1_hh = (const float*)d_in[11];
  const float* W_feat = (const float*)d_in[12];
  const float* W_hidd = (const float*)d_in[13];
  const float* W_att  = (const float*)d_in[14];
  const float* W_l1 = (const float*)d_in[15];
  const float* W_l2 = (const float*)d_in[16];
  const float* W_l  = (const float*)d_in[17];
  const float* W2_ih = (const float*)d_in[18];
  const float* W2_hh = (const float*)d_in[19];
  const float* b2_ih = (const float*)d_in[20];
  const float* b2_hh = (const float*)d_in[21];
  const float* W_cls = (const float*)d_in[22];
  const float* b_cls = (const float*)d_in[23];

  float* lang = (float*)d_out;
  float* attn_out = lang + (size_t)kB * kNS * kV;
  // feat_proj (bf16, 64MB) lives in the lang_cap region of d_out — dead by
  // the time k_cls (the only writer of lang_cap) runs.
  unsigned short* fp = (unsigned short*)d_out;

  float* p = (float*)d_ws;
  float* h1 = p;      p += kB * kH;
  float* h2 = p;      p += kB * kH;
  float* td = p;      p += kB * kC;
  float* gx1 = p;     p += (size_t)kB * kG;
  float* gh1 = p;     p += (size_t)2 * kB * kG;   // 2 K-split partials
  float* gh2 = p;     p += (size_t)2 * kB * kG;
  float* mask_ws = p; p += (size_t)kNS * kB * kP;
  float* xw = p;      p += (size_t)kNS * kB * kC;
  float* td3t = p;    p += kE * 128;
  float* td1t = p;    p += kH * 128;
  float* tdt  = p;    p += 128 * 128;
  float* l1t  = p;    p += 128 * 128;
  float* l2t  = p;    p += kH * 128;
  float* lt   = p;    p += 128 * 128;
  float* iht1 = p;    p += 128 * kG;
  float* iht2 = p;    p += 128 * kG;
  float* whd_t = p;   p += kH * kH;

  unsigned short* u = (unsigned short*)p;
  unsigned short* h1h = u;     u += kB * kH;
  unsigned short* h1l = u;     u += kB * kH;
  unsigned short* h2h = u;     u += kB * kH;
  unsigned short* h2l = u;     u += kB * kH;
  unsigned short* w1hh_h = u;  u += (size_t)kG * kH;
  unsigned short* w1hh_l = u;  u += (size_t)kG * kH;
  unsigned short* w2hh_h = u;  u += (size_t)kG * kH;
  unsigned short* w2hh_l = u;  u += (size_t)kG * kH;
  unsigned short* wc_h = u;    u += (size_t)kV * kH;
  unsigned short* wc_l = u;    u += (size_t)kV * kH;
  unsigned short* wf_h = u;    u += (size_t)kH * kC;
  unsigned short* wf_l = u;    u += (size_t)kH * kC;
  unsigned short* h2all_h = u; u += (size_t)kNS * kB * kH;
  unsigned short* h2all_l = u; u += (size_t)kNS * kB * kH;
  unsigned short* l1bt = u;    u += kC * kC;
  unsigned short* l2bt = u;    u += (size_t)kH * kC;
  unsigned short* lbt = u;     u += kC * kC;
  unsigned short* iht2b = u;   u += (size_t)kC * kG;
  unsigned short* whdbT = u;   u += (size_t)kH * kH;
  unsigned short* td1bt = u;   u += (size_t)kH * kC;
  unsigned short* tdbt = u;    u += kC * kC;
  unsigned short* iht1b = u;   u += (size_t)kC * kG;

  k_transpose<<<dim3(64, 9), 256, 0, stream>>>(
      W_td3, W_td1, W_td, W_l1, W_l2, W_l, W1_ih, W2_ih, W_hidd,
      td3t, td1t, tdt, l1t, l2t, lt, iht1, iht2, whd_t);
  k_tobf16<<<dim3(96, 8), 256, 0, stream>>>(
      l1t, l2t, lt, iht2, whd_t, td1t, tdt, iht1,
      l1bt, l2bt, lbt, iht2b, whdbT, td1bt, tdbt, iht1b);
  k_split<<<dim3(256, 4), 256, 0, stream>>>(
      W1_hh, W2_hh, W_cls, W_feat,
      w1hh_h, w1hh_l, w2hh_h, w2hh_l, wc_h, wc_l, wf_h, wf_l);
  k_init<<<128, 256, 0, stream>>>(t_feat, W_td2, td, h1, h2,
                                  h1h, h1l, h2h, h2l);
  k_featproj<<<dim3(512, 4), 256, 0, stream>>>(c_feats, wf_h, wf_l, fp);
  k_xw<<<dim3(64, kNS), 256, 0, stream>>>(word_embs, td3t, td, xw);
  k_prestep<<<256, 256, 0, stream>>>(xw, tdbt, iht1b, b1_ih, gx1);

  for (int t = 0; t < kNS; ++t) {
    k_gh<<<96, 256, 0, stream>>>(h1h, h1l, h2h, h2l,
                                 w1hh_h, w1hh_l, w2hh_h, w2hh_l,
                                 b1_hh, b2_hh, gh1, gh2);
    k_step2<<<256, 1024, 0, stream>>>(gx1, gh1, gh2, h1, h2,
                                      h1h, h1l, h2h, h2l, whdbT, W_att, fp,
                                      c_feats, l1bt, l2bt, lbt, iht2b, b2_ih,
                                      td1bt, tdbt, iht1b, b1_ih, xw,
                                      h2all_h, h2all_l, mask_ws, t);
  }
  k_atrans<<<256, 256, 0, stream>>>(mask_ws, attn_out);
  k_cls<<<dim3(62, 27), 256, 0, stream>>>(h2all_h, h2all_l, wc_h, wc_l,
                                          b_cls, lang);
}